// Round 1
// 213.750 us; speedup vs baseline: 1.2828x; 1.2828x over previous
//
#include <hip/hip_runtime.h>

// B(derived), IN_DIM=784, NUM_NETS=30, N_NODES=20, NUM_OUT=10, DIM_OUT=16, NUM_ITER=3
// Validated: size-based binding; dtype detect; k1m MFMA; k2s; k2p priors GEMM.
// R15: k3r (106us, DS-pipe bound: ~350 DS ops/thread -- 90 P-broadcast reads + 240
// reduce shuffles) -> k3t: lane (o,j) holds pri[n=2j,2j+1][k=0..15] IN REGISTERS.
// k-contraction (logits) is now in-register (0 shuffles); n-contraction (s) is one
// 15-shuffle transpose-reduce + 16-shuffle allgather; P reads 30/iter -> 2/iter;
// iter0 softmax(0)=0.1 hardcoded. ~90 DS ops/thread. Fallback k2s+k3y2 unchanged.

typedef unsigned short bfu;
typedef unsigned int u32;
typedef __attribute__((ext_vector_type(8))) short short8;
typedef __attribute__((ext_vector_type(4))) float floatx4;

__device__ __forceinline__ float bf2f(bfu u) { union { u32 i; float f; } v; v.i = ((u32)u) << 16; return v.f; }
__device__ __forceinline__ float lo2f(u32 w) { union { u32 i; float f; } v; v.i = w << 16; return v.f; }
__device__ __forceinline__ float hi2f(u32 w) { union { u32 i; float f; } v; v.i = w & 0xffff0000u; return v.f; }
__device__ __forceinline__ float ldf(const void* p, int idx, bool b16) {
    return b16 ? bf2f(((const bfu*)p)[idx]) : ((const float*)p)[idx];
}
__device__ __forceinline__ bfu f2bf(float f) {   // RNE
    u32 u = __float_as_uint(f);
    return (bfu)((u + 0x7FFFu + ((u >> 16) & 1u)) >> 16);
}
__device__ __forceinline__ void unpack8(uint4 q, float* dst) {
    dst[0] = lo2f(q.x); dst[1] = hi2f(q.x);
    dst[2] = lo2f(q.y); dst[3] = hi2f(q.y);
    dst[4] = lo2f(q.z); dst[5] = hi2f(q.z);
    dst[6] = lo2f(q.w); dst[7] = hi2f(q.w);
}

// ---- dtype detector (validated) ----
__global__ void detect_dtype(const u32* x, const u32* W1, const u32* b1,
                             const u32* W2, const u32* b2, const u32* rw,
                             u32* flags) {
    int t = threadIdx.x;
    if (t >= 6) return;
    const u32* p = (t == 0) ? x : (t == 1) ? W1 : (t == 2) ? b1
                 : (t == 3) ? W2 : (t == 4) ? b2 : rw;
    int c = 0;
    for (int i = 0; i < 64; i++) {
        u32 e = (p[i] >> 7) & 0xFF;
        c += (e >= 64 && e <= 140) ? 1 : 0;
    }
    flags[t] = (c >= 48) ? 1u : 0u;
}

// ---- prep_all: xb | Wt | rwb | b1f (+ rwn if mode==0), index-partitioned ----
__global__ void prep_all(const void* x, const void* W1, const void* b1, const void* rw,
                         bfu* __restrict__ xb, bfu* __restrict__ Wt,
                         float* __restrict__ b1f, bfu* __restrict__ rwb,
                         bfu* __restrict__ rwn,
                         const u32* flags, int B, int mode) {
    const int idx = blockIdx.x * 256 + threadIdx.x;
    const int nxb = B * 800;
    if (idx < nxb) {                                   // xb[B][800] bf16
        const bool b16 = flags[0] != 0;
        int b = idx / 800, kk = idx - b * 800;
        bfu v = 0;
        if (kk < 784) {
            int src = b * 784 + kk;
            v = b16 ? ((const bfu*)x)[src] : f2bf(((const float*)x)[src]);
        }
        xb[idx] = v;
        return;
    }
    int i2 = idx - nxb;
    if (i2 < 640 * 800) {                              // Wt[c][k] bf16
        const bool wb = flags[1] != 0;
        int c = i2 / 800, k = i2 - c * 800;
        bfu v = 0;
        if (c < 600 && k < 784) {
            int nn = c / 20, o = c - nn * 20;
            int src = nn * 15680 + k * 20 + o;
            v = wb ? ((const bfu*)W1)[src] : f2bf(((const float*)W1)[src]);
        }
        Wt[i2] = v;
        return;
    }
    i2 -= 640 * 800;
    if (i2 < 96000) {                                  // rwb[o][n][k][d] bf16 (fallback k3y2)
        const bool rb = flags[5] != 0;
        int d = i2 % 20;
        int k = (i2 / 20) % 16;
        int n = (i2 / 320) % 30;
        int o = i2 / 9600;
        int src = o * 9600 + n * 320 + d * 16 + k;
        rwb[i2] = rb ? ((const bfu*)rw)[src] : f2bf(((const float*)rw)[src]);
        return;
    }
    i2 -= 96000;
    if (i2 < 640) {                                    // b1f fp32
        b1f[i2] = (i2 < 600) ? ldf(b1, i2, flags[2] != 0) : 0.f;
        return;
    }
    i2 -= 640;
    if (mode == 0 && i2 < 153600) {                    // rwn[n][col=o*16+k][dd<32] bf16, K-pad
        const bool rb = flags[5] != 0;
        int dd = i2 % 32;
        int col = (i2 / 32) % 160;
        int n = i2 / 5120;
        bfu v = 0;
        if (dd < 20) {
            int o = col / 16, kk = col % 16;
            int src = o * 9600 + n * 320 + dd * 16 + kk;
            v = rb ? ((const bfu*)rw)[src] : f2bf(((const float*)rw)[src]);
        }
        rwn[i2] = v;
    }
}

// ---------------- K1m: h1 = relu(xb @ Wt^T + b1), bf16 MFMA (validated) ----------------
__global__ __launch_bounds__(256, 4) void k1m(const bfu* __restrict__ xb, const bfu* __restrict__ Wt,
                                              const float* __restrict__ b1f,
                                              float* __restrict__ h1, int Btot) {
    __shared__ short As[128 * 40];
    __shared__ short Bs[64 * 40];
    const int tid = threadIdx.x;
    const int w = tid >> 6, lane = tid & 63;
    const int quad = lane >> 4, fl = lane & 15;
    const int m0 = blockIdx.x * 128, n0 = blockIdx.y * 64;

    floatx4 acc[2][4];
    #pragma unroll
    for (int mi = 0; mi < 2; mi++)
        #pragma unroll
        for (int ni = 0; ni < 4; ni++) acc[mi][ni] = (floatx4){0.f, 0.f, 0.f, 0.f};

    const int arow = tid >> 1, aseg = tid & 1;
    const int brow = tid >> 2, bseg = tid & 3;
    int agrow = m0 + arow; if (agrow >= Btot) agrow = Btot - 1;
    const bfu* abase = xb + (size_t)agrow * 800 + aseg * 16;
    const bfu* bbase = Wt + (size_t)(n0 + brow) * 800 + bseg * 8;

    for (int k0 = 0; k0 < 800; k0 += 32) {
        uint4 qa0 = *(const uint4*)(abase + k0);
        uint4 qa1 = *(const uint4*)(abase + k0 + 8);
        uint4 qb  = *(const uint4*)(bbase + k0);

        __syncthreads();
        *(uint4*)&As[arow * 40 + aseg * 16 + 0] = qa0;
        *(uint4*)&As[arow * 40 + aseg * 16 + 8] = qa1;
        *(uint4*)&Bs[brow * 40 + bseg * 8] = qb;
        __syncthreads();

        short8 af[2], bfr[4];
        #pragma unroll
        for (int mi = 0; mi < 2; mi++)
            af[mi] = *(const short8*)&As[(w * 32 + mi * 16 + fl) * 40 + quad * 8];
        #pragma unroll
        for (int ni = 0; ni < 4; ni++)
            bfr[ni] = *(const short8*)&Bs[(ni * 16 + fl) * 40 + quad * 8];
        #pragma unroll
        for (int mi = 0; mi < 2; mi++)
            #pragma unroll
            for (int ni = 0; ni < 4; ni++)
                acc[mi][ni] = __builtin_amdgcn_mfma_f32_16x16x32_bf16(af[mi], bfr[ni], acc[mi][ni], 0, 0, 0);
    }

    #pragma unroll
    for (int mi = 0; mi < 2; mi++) {
        #pragma unroll
        for (int ni = 0; ni < 4; ni++) {
            const int c = n0 + ni * 16 + fl;
            #pragma unroll
            for (int r = 0; r < 4; r++) {
                const int m = m0 + w * 32 + mi * 16 + quad * 4 + r;
                if (c < 600 && m < Btot)
                    h1[(size_t)m * 600 + c] = fmaxf(acc[mi][ni][r] + b1f[c], 0.f);
            }
        }
    }
}

// ---------------- K2 core (validated math) ----------------
__device__ __forceinline__ void k2_core(const float* hp, const float* wn, const float* bn,
                                        float* o, float& sc) {
    float h[20];
    #pragma unroll
    for (int d4 = 0; d4 < 20; d4 += 4) {
        float4 v = *(const float4*)(hp + d4);
        h[d4] = v.x; h[d4 + 1] = v.y; h[d4 + 2] = v.z; h[d4 + 3] = v.w;
    }
    float sq = 0.f;
    #pragma unroll
    for (int e = 0; e < 20; e++) {
        float acc = bn[e];
        #pragma unroll
        for (int d = 0; d < 20; d++) acc += h[d] * wn[d * 20 + e];
        acc = fmaxf(acc, 0.f);
        o[e] = acc;
        sq += acc * acc;
    }
    sc = (sq > 0.f) ? sqrtf(sq) / (1.f + sq) : 0.f;
}

// K2b (main): u -> ub32[b][n][32] bf16, zero-padded
__global__ __launch_bounds__(256) void k2b(const float* h1, const void* W2, const void* b2,
                                           bfu* __restrict__ ub32, const u32* flags, int total) {
    __shared__ float W2s[12000];
    __shared__ float b2s[600];
    const bool wb = flags[3] != 0, bb = flags[4] != 0;
    const int tid = threadIdx.x;
    for (int i = tid; i < 12000; i += 256) W2s[i] = ldf(W2, i, wb);
    for (int i = tid; i < 600; i += 256) b2s[i] = ldf(b2, i, bb);
    __syncthreads();

    int t = blockIdx.x * 256 + tid;
    if (t >= total) return;          // t = b*30 + n
    const int b = t / 30, n = t - b * 30;
    float o[20], sc;
    k2_core(h1 + (size_t)b * 600 + n * 20, &W2s[n * 400], &b2s[n * 20], o, sc);

    u32 wbuf[16];
    #pragma unroll
    for (int j = 0; j < 10; j++)
        wbuf[j] = (u32)f2bf(o[2 * j] * sc) | ((u32)f2bf(o[2 * j + 1] * sc) << 16);
    #pragma unroll
    for (int j = 10; j < 16; j++) wbuf[j] = 0;
    uint4* dst = (uint4*)(ub32 + ((size_t)b * 30 + n) * 32);
    dst[0] = *(uint4*)&wbuf[0];
    dst[1] = *(uint4*)&wbuf[4];
    dst[2] = *(uint4*)&wbuf[8];
    dst[3] = *(uint4*)&wbuf[12];
}

// K2s (fallback, validated): u fp32 in place
__global__ __launch_bounds__(256) void k2s(const float* h1, const void* W2, const void* b2,
                                           float* u, const u32* flags, int total) {
    __shared__ float W2s[12000];
    __shared__ float b2s[600];
    const bool wb = flags[3] != 0, bb = flags[4] != 0;
    const int tid = threadIdx.x;
    for (int i = tid; i < 12000; i += 256) W2s[i] = ldf(W2, i, wb);
    for (int i = tid; i < 600; i += 256) b2s[i] = ldf(b2, i, bb);
    __syncthreads();

    int t = blockIdx.x * 256 + tid;
    if (t >= total) return;
    const int b = t / 30, n = t - b * 30;
    float o[20], sc;
    k2_core(h1 + (size_t)b * 600 + n * 20, &W2s[n * 400], &b2s[n * 20], o, sc);
    float* up = u + (size_t)b * 600 + n * 20;
    #pragma unroll
    for (int e4 = 0; e4 < 20; e4 += 4) {
        float4 v;
        v.x = o[e4] * sc; v.y = o[e4 + 1] * sc; v.z = o[e4 + 2] * sc; v.w = o[e4 + 3] * sc;
        *(float4*)(up + e4) = v;
    }
}

// ---------------- K2p: priors GEMM via MFMA (main, validated) ----------------
// grid (ceil(B/128), 30); block 256 = 4 waves. pri[b][n*160 + o*16+k] bf16.
__global__ __launch_bounds__(256) void k2p(const bfu* __restrict__ ub32,
                                           const bfu* __restrict__ rwn,
                                           bfu* __restrict__ pri, int Btot) {
    const int tid = threadIdx.x;
    const int w = tid >> 6, lane = tid & 63;
    const int quad = lane >> 4, fl = lane & 15;
    const int n = blockIdx.y;
    const int b0 = blockIdx.x * 128;

    short8 bfr[10];
    #pragma unroll
    for (int nj = 0; nj < 10; nj++)
        bfr[nj] = *(const short8*)(rwn + ((size_t)n * 160 + nj * 16 + fl) * 32 + quad * 8);

    #pragma unroll
    for (int mi = 0; mi < 2; mi++) {
        int m = b0 + w * 32 + mi * 16 + fl;
        int mc = (m < Btot) ? m : Btot - 1;
        short8 af = *(const short8*)(ub32 + ((size_t)mc * 30 + n) * 32 + quad * 8);
        #pragma unroll
        for (int nj = 0; nj < 10; nj++) {
            floatx4 acc = (floatx4){0.f, 0.f, 0.f, 0.f};
            acc = __builtin_amdgcn_mfma_f32_16x16x32_bf16(af, bfr[nj], acc, 0, 0, 0);
            #pragma unroll
            for (int r = 0; r < 4; r++) {
                int mr = b0 + w * 32 + mi * 16 + quad * 4 + r;
                if (mr < Btot)
                    pri[(size_t)mr * 4800 + n * 160 + nj * 16 + fl] = f2bf(acc[r]);
            }
        }
    }
}

// ---------------- K3t: routing with k-in-register layout (main, R15) ----------------
// 640 thr = 4 rows/block; per row 160 threads (o=r>>4, j=r&15).
// Lane (o,j) holds pri[n=2j][o][0..15] and pri[n=2j+1][o][0..15] in fp32 regs
// (j==15 -> n=30,31 pads, zero). Per iteration:
//   s[o,k] = sum_n P[n,o]*pri[n,o,k]:  per-lane 16-vec partial, then 15-shuffle
//            transpose-reduce leaving s[k=j] on lane j.
//   allgather s (16 shfl) -> q, squash scale, and v-vector all in-register.
//   L[n,o] += dot_k(pri, v): in-register (0 shuffles), unique owner lane -> LDS store.
//   softmax over o: 30 dedicated threads/row (unchanged, validated pattern).
// iter0: softmax(0) == 0.1 hardcoded (exact). DS ops/thread ~90 vs k3r's ~350.
__global__ __launch_bounds__(640, 2) void k3t(const bfu* __restrict__ pri_buf,
                                              float* __restrict__ out, int Btot) {
    __shared__ float L[4][300];
    __shared__ float P[4][300];
    const int tid = threadIdx.x;
    const int g = tid / 160, r = tid - g * 160;
    const int o = r >> 4, j = r & 15;
    const int b0 = blockIdx.x * 4;
    int bb = b0 + g; if (bb >= Btot) bb = Btot - 1;

    const int n0 = 2 * j, n1 = n0 + 1;
    float p0[16], p1[16];
    if (j < 15) {
        const bfu* pb = pri_buf + (size_t)bb * 4800 + (size_t)o * 16;
        uint4 q0 = *(const uint4*)(pb + n0 * 160);
        uint4 q1 = *(const uint4*)(pb + n0 * 160 + 8);
        uint4 q2 = *(const uint4*)(pb + n1 * 160);
        uint4 q3 = *(const uint4*)(pb + n1 * 160 + 8);
        unpack8(q0, p0); unpack8(q1, p0 + 8);
        unpack8(q2, p1); unpack8(q3, p1 + 8);
    } else {
        #pragma unroll
        for (int i = 0; i < 16; i++) { p0[i] = 0.f; p1[i] = 0.f; }
    }

    float L0 = 0.f, L1 = 0.f;
    float v = 0.f;
    #pragma unroll
    for (int it = 0; it < 3; it++) {
        float P0, P1;
        if (it == 0) {
            P0 = 0.1f; P1 = 0.1f;              // softmax(zeros) over 10 outputs
        } else {
            if (r < 30) {                       // dedicated softmax over o for row n=r
                float l[10];
                #pragma unroll
                for (int oo = 0; oo < 10; oo++) l[oo] = L[g][r * 10 + oo];
                float mx = l[0];
                #pragma unroll
                for (int oo = 1; oo < 10; oo++) mx = fmaxf(mx, l[oo]);
                float den = 0.f;
                #pragma unroll
                for (int oo = 0; oo < 10; oo++) { l[oo] = __expf(l[oo] - mx); den += l[oo]; }
                float inv = 1.f / den;
                #pragma unroll
                for (int oo = 0; oo < 10; oo++) P[g][r * 10 + oo] = l[oo] * inv;
            }
            __syncthreads();
            P0 = (j < 15) ? P[g][n0 * 10 + o] : 0.f;
            P1 = (j < 15) ? P[g][n1 * 10 + o] : 0.f;
        }

        // per-lane partial s-vector over this lane's two nets
        float t[16];
        #pragma unroll
        for (int i = 0; i < 16; i++) t[i] = P0 * p0[i] + P1 * p1[i];

        // 16-lane transpose-reduce: lane j ends with s[k=j] (15 shuffles)
        #pragma unroll
        for (int i = 0; i < 8; i++) {
            float send = (j & 8) ? t[i] : t[i + 8];
            float recv = __shfl_xor(send, 8, 16);
            t[i] = ((j & 8) ? t[i + 8] : t[i]) + recv;
        }
        #pragma unroll
        for (int i = 0; i < 4; i++) {
            float send = (j & 4) ? t[i] : t[i + 4];
            float recv = __shfl_xor(send, 4, 16);
            t[i] = ((j & 4) ? t[i + 4] : t[i]) + recv;
        }
        #pragma unroll
        for (int i = 0; i < 2; i++) {
            float send = (j & 2) ? t[i] : t[i + 2];
            float recv = __shfl_xor(send, 2, 16);
            t[i] = ((j & 2) ? t[i + 2] : t[i]) + recv;
        }
        {
            float send = (j & 1) ? t[0] : t[1];
            float recv = __shfl_xor(send, 1, 16);
            t[0] = ((j & 1) ? t[1] : t[0]) + recv;
        }
        float s = t[0];                         // s[o, k=j]

        if (it < 2) {
            // allgather s across the 16-lane group: gives q, scale, and v-vector
            float sf[16];
            #pragma unroll
            for (int k = 0; k < 16; k++) sf[k] = __shfl(s, k, 16);
            float q = 0.f;
            #pragma unroll
            for (int k = 0; k < 16; k++) q += sf[k] * sf[k];
            float scale = sqrtf(q) / (1.f + q);
            v = s * scale;
            // logits update: fully in-register dot over k
            float d0 = 0.f, d1 = 0.f;
            #pragma unroll
            for (int k = 0; k < 16; k++) {
                float vk = sf[k] * scale;
                d0 += p0[k] * vk;
                d1 += p1[k] * vk;
            }
            L0 += d0; L1 += d1;
            if (j < 15) {
                L[g][n0 * 10 + o] = L0;
                L[g][n1 * 10 + o] = L1;
            }
            __syncthreads();
        } else {
            float q = s * s;
            q += __shfl_xor(q, 1, 16);
            q += __shfl_xor(q, 2, 16);
            q += __shfl_xor(q, 4, 16);
            q += __shfl_xor(q, 8, 16);
            v = s * sqrtf(q) / (1.f + q);
        }
    }
    if ((b0 + g) < Btot) out[(size_t)(b0 + g) * 160 + r] = v;
}

// ---------------- K3y2 (fallback, validated @202us) ----------------
__global__ __launch_bounds__(640, 2) void k3y2(const float* __restrict__ u,
                                               const bfu* __restrict__ rwb,
                                               float* __restrict__ out, int Btot) {
    __shared__ float US[4][600];
    __shared__ float L[4][300];
    __shared__ float P[4][300];
    const int tid = threadIdx.x;
    const int g = tid / 160, r = tid - g * 160;
    const int o = r >> 4, k = r & 15;
    const int b0 = blockIdx.x * 4;

    {
        const int nf4 = 150;
        for (int i = tid; i < 4 * nf4; i += 640) {
            int gg = i / nf4, j = i - gg * nf4;
            int bb = b0 + gg; if (bb >= Btot) bb = Btot - 1;
            *(float4*)&US[gg][j * 4] = *(const float4*)(u + (size_t)bb * 600 + j * 4);
        }
        for (int i = tid; i < 1200; i += 640) L[i / 300][i % 300] = 0.f;
    }
    __syncthreads();

    float pri[30];
    const bfu* rp = rwb + o * 9600 + k * 20;
    #pragma unroll 2
    for (int n = 0; n < 30; n++) {
        const uint2* rq = (const uint2*)(rp + n * 320);
        float a = 0.f;
        #pragma unroll
        for (int jj = 0; jj < 5; jj++) {
            uint2 w = rq[jj];
            float4 uu = *(const float4*)&US[g][n * 20 + jj * 4];
            a += lo2f(w.x) * uu.x + hi2f(w.x) * uu.y + lo2f(w.y) * uu.z + hi2f(w.y) * uu.w;
        }
        pri[n] = a;
    }

    float v = 0.f;
    for (int it = 0; it < 3; it++) {
        if (r < 30) {
            const int n = r;
            float mx = L[g][n * 10];
            #pragma unroll
            for (int oo = 1; oo < 10; oo++) mx = fmaxf(mx, L[g][n * 10 + oo]);
            float e[10], den = 0.f;
            #pragma unroll
            for (int oo = 0; oo < 10; oo++) { e[oo] = __expf(L[g][n * 10 + oo] - mx); den += e[oo]; }
            float inv = 1.f / den;
            #pragma unroll
            for (int oo = 0; oo < 10; oo++) P[g][n * 10 + oo] = e[oo] * inv;
        }
        __syncthreads();
        float s = 0.f;
        #pragma unroll
        for (int n = 0; n < 30; n++) s += P[g][n * 10 + o] * pri[n];
        float q = s * s;
        q += __shfl_xor(q, 1, 16);
        q += __shfl_xor(q, 2, 16);
        q += __shfl_xor(q, 4, 16);
        q += __shfl_xor(q, 8, 16);
        v = s * sqrtf(q) / (1.f + q);
        if (it < 2) {
            #pragma unroll 5
            for (int n = 0; n < 30; n++) {
                float t = pri[n] * v;
                t += __shfl_xor(t, 1, 16);
                t += __shfl_xor(t, 2, 16);
                t += __shfl_xor(t, 4, 16);
                t += __shfl_xor(t, 8, 16);
                if (k == 0) L[g][n * 10 + o] += t;
            }
            __syncthreads();
        }
    }
    if ((b0 + g) < Btot) out[(size_t)(b0 + g) * 160 + r] = v;
}

extern "C" void kernel_launch(void* const* d_in, const int* in_sizes, int n_in,
                              void* d_out, int out_size, void* d_ws, size_t ws_size,
                              hipStream_t stream) {
    // ---- size-based input matching (validated) ----
    int ix = -1, iw1 = -1, ib1 = -1, iw2 = -1, ib2 = -1, irw = -1;
    for (int i = 0; i < n_in; i++) {
        int s = in_sizes[i];
        if (s == 470400 && iw1 < 0) iw1 = i;
        else if (s == 12000 && iw2 < 0) iw2 = i;
        else if (s == 96000 && irw < 0) irw = i;
        else if (s == 600) { if (ib1 < 0) ib1 = i; else if (ib2 < 0) ib2 = i; }
    }
    long bestsz = -1;
    for (int i = 0; i < n_in; i++) {
        if (i == iw1 || i == iw2 || i == irw || i == ib1 || i == ib2) continue;
        if ((long)in_sizes[i] > bestsz) { bestsz = in_sizes[i]; ix = i; }
    }
    if (ix < 0 || iw1 < 0 || ib1 < 0 || iw2 < 0 || ib2 < 0 || irw < 0) {
        ix = 0; iw1 = 1; ib1 = 2; iw2 = 3; ib2 = 4; irw = 5;
    }
    const void* x  = d_in[ix];
    const void* W1 = d_in[iw1];
    const void* b1 = d_in[ib1];
    const void* W2 = d_in[iw2];
    const void* b2 = d_in[ib2];
    const void* rw = d_in[irw];
    const int B = in_sizes[ix] / 784;
    float* out = (float*)d_out;

    // ---- ws layout (byte offsets, all 16B-aligned) ----
    char* base = (char*)d_ws;
    size_t off = 0;
    float* h1u  = (float*)(base + off); off += (size_t)B * 2400;       // B*600 f32
    float* b1f  = (float*)(base + off); off += 2560;                   // 640 f32
    u32*  flags = (u32*)(base + off);   off += 32;                     // 8 u32
    bfu*   Wt   = (bfu*)(base + off);   off += 1024000;                // 640*800 bf16
    bfu*   xb   = (bfu*)(base + off);   off += (size_t)B * 1600;       // B*800 bf16
    bfu*   rwb  = (bfu*)(base + off);   off += 192000;                 // 96000 bf16
    size_t fb_bytes = off;
    bfu*   rwn  = (bfu*)(base + off);   off += 307200;                 // 30*160*32 bf16
    bfu*   ub32 = (bfu*)(base + off);   off += (size_t)B * 1920;       // B*30*32 bf16
    bfu*   pri  = (bfu*)(base + off);   off += (size_t)B * 9600;       // B*4800 bf16
    size_t main_bytes = off;

    const int mode = (ws_size >= main_bytes) ? 0 : 1;   // fixed per-call -> graph-safe
    const int prep_total = B * 800 + 640 * 800 + 96000 + 640 + (mode == 0 ? 153600 : 0);

    detect_dtype<<<1, 64, 0, stream>>>((const u32*)x, (const u32*)W1, (const u32*)b1,
                                       (const u32*)W2, (const u32*)b2, (const u32*)rw, flags);
    prep_all<<<(prep_total + 255) / 256, 256, 0, stream>>>(x, W1, b1, rw, xb, Wt, b1f,
                                                           rwb, rwn, flags, B, mode);
    k1m<<<dim3((B + 127) / 128, 10), 256, 0, stream>>>(xb, Wt, b1f, h1u, B);
    if (mode == 0) {
        k2b<<<(B * 30 + 255) / 256, 256, 0, stream>>>(h1u, W2, b2, ub32, flags, B * 30);
        k2p<<<dim3((B + 127) / 128, 30), 256, 0, stream>>>(ub32, rwn, pri, B);
        k3t<<<(B + 3) / 4, 640, 0, stream>>>(pri, out, B);
    } else {
        (void)fb_bytes;
        k2s<<<(B * 30 + 255) / 256, 256, 0, stream>>>(h1u, W2, b2, h1u, flags, B * 30);
        k3y2<<<(B + 3) / 4, 640, 0, stream>>>(h1u, rwb, out, B);
    }
}

// Round 2
// 191.374 us; speedup vs baseline: 1.4328x; 1.1169x over previous
//
#include <hip/hip_runtime.h>

// B(derived), IN_DIM=784, NUM_NETS=30, N_NODES=20, NUM_OUT=10, DIM_OUT=16, NUM_ITER=3
// Validated: size-based binding; dtype detect; k1m MFMA; k2p priors GEMM; k3t routing
// (41us). R16: k2b (44.8us, 5.08M LDS bank-conflict cycles: lanes differ only by n and
// n*400 mod 32banks hits 2 banks -> ~30-way conflict on 400 ds_reads/thread) -> k2n:
// blockIdx.y = n, W2 read via block-UNIFORM global loads from prepped fp32 W2t (s_load,
// zero DS), h1 stored [n][b][20] in mode 0 so the h-load is a contiguous 5120B/wave.
// Fallback k2s+k3y2 unchanged (k1m tr=0 keeps b-major h1).

typedef unsigned short bfu;
typedef unsigned int u32;
typedef __attribute__((ext_vector_type(8))) short short8;
typedef __attribute__((ext_vector_type(4))) float floatx4;

__device__ __forceinline__ float bf2f(bfu u) { union { u32 i; float f; } v; v.i = ((u32)u) << 16; return v.f; }
__device__ __forceinline__ float lo2f(u32 w) { union { u32 i; float f; } v; v.i = w << 16; return v.f; }
__device__ __forceinline__ float hi2f(u32 w) { union { u32 i; float f; } v; v.i = w & 0xffff0000u; return v.f; }
__device__ __forceinline__ float ldf(const void* p, int idx, bool b16) {
    return b16 ? bf2f(((const bfu*)p)[idx]) : ((const float*)p)[idx];
}
__device__ __forceinline__ bfu f2bf(float f) {   // RNE
    u32 u = __float_as_uint(f);
    return (bfu)((u + 0x7FFFu + ((u >> 16) & 1u)) >> 16);
}
__device__ __forceinline__ void unpack8(uint4 q, float* dst) {
    dst[0] = lo2f(q.x); dst[1] = hi2f(q.x);
    dst[2] = lo2f(q.y); dst[3] = hi2f(q.y);
    dst[4] = lo2f(q.z); dst[5] = hi2f(q.z);
    dst[6] = lo2f(q.w); dst[7] = hi2f(q.w);
}

// ---- dtype detector (validated) ----
__global__ void detect_dtype(const u32* x, const u32* W1, const u32* b1,
                             const u32* W2, const u32* b2, const u32* rw,
                             u32* flags) {
    int t = threadIdx.x;
    if (t >= 6) return;
    const u32* p = (t == 0) ? x : (t == 1) ? W1 : (t == 2) ? b1
                 : (t == 3) ? W2 : (t == 4) ? b2 : rw;
    int c = 0;
    for (int i = 0; i < 64; i++) {
        u32 e = (p[i] >> 7) & 0xFF;
        c += (e >= 64 && e <= 140) ? 1 : 0;
    }
    flags[t] = (c >= 48) ? 1u : 0u;
}

// ---- prep_all: xb | Wt | rwb | b1f (+ rwn | W2t | b2f if mode==0) ----
__global__ void prep_all(const void* x, const void* W1, const void* b1,
                         const void* W2, const void* b2, const void* rw,
                         bfu* __restrict__ xb, bfu* __restrict__ Wt,
                         float* __restrict__ b1f, bfu* __restrict__ rwb,
                         bfu* __restrict__ rwn, float* __restrict__ W2t,
                         float* __restrict__ b2f,
                         const u32* flags, int B, int mode) {
    const int idx = blockIdx.x * 256 + threadIdx.x;
    const int nxb = B * 800;
    if (idx < nxb) {                                   // xb[B][800] bf16
        const bool b16 = flags[0] != 0;
        int b = idx / 800, kk = idx - b * 800;
        bfu v = 0;
        if (kk < 784) {
            int src = b * 784 + kk;
            v = b16 ? ((const bfu*)x)[src] : f2bf(((const float*)x)[src]);
        }
        xb[idx] = v;
        return;
    }
    int i2 = idx - nxb;
    if (i2 < 640 * 800) {                              // Wt[c][k] bf16
        const bool wb = flags[1] != 0;
        int c = i2 / 800, k = i2 - c * 800;
        bfu v = 0;
        if (c < 600 && k < 784) {
            int nn = c / 20, o = c - nn * 20;
            int src = nn * 15680 + k * 20 + o;
            v = wb ? ((const bfu*)W1)[src] : f2bf(((const float*)W1)[src]);
        }
        Wt[i2] = v;
        return;
    }
    i2 -= 640 * 800;
    if (i2 < 96000) {                                  // rwb[o][n][k][d] bf16 (fallback k3y2)
        const bool rb = flags[5] != 0;
        int d = i2 % 20;
        int k = (i2 / 20) % 16;
        int n = (i2 / 320) % 30;
        int o = i2 / 9600;
        int src = o * 9600 + n * 320 + d * 16 + k;
        rwb[i2] = rb ? ((const bfu*)rw)[src] : f2bf(((const float*)rw)[src]);
        return;
    }
    i2 -= 96000;
    if (i2 < 640) {                                    // b1f fp32
        b1f[i2] = (i2 < 600) ? ldf(b1, i2, flags[2] != 0) : 0.f;
        return;
    }
    i2 -= 640;
    if (mode != 0) return;
    if (i2 < 153600) {                                 // rwn[n][col=o*16+k][dd<32] bf16, K-pad
        const bool rb = flags[5] != 0;
        int dd = i2 % 32;
        int col = (i2 / 32) % 160;
        int n = i2 / 5120;
        bfu v = 0;
        if (dd < 20) {
            int o = col / 16, kk = col % 16;
            int src = o * 9600 + n * 320 + dd * 16 + kk;
            v = rb ? ((const bfu*)rw)[src] : f2bf(((const float*)rw)[src]);
        }
        rwn[i2] = v;
        return;
    }
    i2 -= 153600;
    if (i2 < 12000) {                                  // W2t[n][e][d] fp32 = W2[n][d][e]
        int d = i2 % 20;
        int e = (i2 / 20) % 20;
        int n = i2 / 400;
        W2t[i2] = ldf(W2, n * 400 + d * 20 + e, flags[3] != 0);
        return;
    }
    i2 -= 12000;
    if (i2 < 640) {                                    // b2f fp32
        b2f[i2] = (i2 < 600) ? ldf(b2, i2, flags[4] != 0) : 0.f;
    }
}

// ---------------- K1m: h1 = relu(xb @ Wt^T + b1), bf16 MFMA (validated) ----------------
// tr==1 (mode 0): store h1 as [n][b][20] (coalesced reads for k2n). tr==0: [b][600].
__global__ __launch_bounds__(256, 4) void k1m(const bfu* __restrict__ xb, const bfu* __restrict__ Wt,
                                              const float* __restrict__ b1f,
                                              float* __restrict__ h1, int Btot, int tr) {
    __shared__ short As[128 * 40];
    __shared__ short Bs[64 * 40];
    const int tid = threadIdx.x;
    const int w = tid >> 6, lane = tid & 63;
    const int quad = lane >> 4, fl = lane & 15;
    const int m0 = blockIdx.x * 128, n0 = blockIdx.y * 64;

    floatx4 acc[2][4];
    #pragma unroll
    for (int mi = 0; mi < 2; mi++)
        #pragma unroll
        for (int ni = 0; ni < 4; ni++) acc[mi][ni] = (floatx4){0.f, 0.f, 0.f, 0.f};

    const int arow = tid >> 1, aseg = tid & 1;
    const int brow = tid >> 2, bseg = tid & 3;
    int agrow = m0 + arow; if (agrow >= Btot) agrow = Btot - 1;
    const bfu* abase = xb + (size_t)agrow * 800 + aseg * 16;
    const bfu* bbase = Wt + (size_t)(n0 + brow) * 800 + bseg * 8;

    for (int k0 = 0; k0 < 800; k0 += 32) {
        uint4 qa0 = *(const uint4*)(abase + k0);
        uint4 qa1 = *(const uint4*)(abase + k0 + 8);
        uint4 qb  = *(const uint4*)(bbase + k0);

        __syncthreads();
        *(uint4*)&As[arow * 40 + aseg * 16 + 0] = qa0;
        *(uint4*)&As[arow * 40 + aseg * 16 + 8] = qa1;
        *(uint4*)&Bs[brow * 40 + bseg * 8] = qb;
        __syncthreads();

        short8 af[2], bfr[4];
        #pragma unroll
        for (int mi = 0; mi < 2; mi++)
            af[mi] = *(const short8*)&As[(w * 32 + mi * 16 + fl) * 40 + quad * 8];
        #pragma unroll
        for (int ni = 0; ni < 4; ni++)
            bfr[ni] = *(const short8*)&Bs[(ni * 16 + fl) * 40 + quad * 8];
        #pragma unroll
        for (int mi = 0; mi < 2; mi++)
            #pragma unroll
            for (int ni = 0; ni < 4; ni++)
                acc[mi][ni] = __builtin_amdgcn_mfma_f32_16x16x32_bf16(af[mi], bfr[ni], acc[mi][ni], 0, 0, 0);
    }

    #pragma unroll
    for (int mi = 0; mi < 2; mi++) {
        #pragma unroll
        for (int ni = 0; ni < 4; ni++) {
            const int c = n0 + ni * 16 + fl;
            const int cn = c / 20, ce = c - cn * 20;
            #pragma unroll
            for (int r = 0; r < 4; r++) {
                const int m = m0 + w * 32 + mi * 16 + quad * 4 + r;
                if (c < 600 && m < Btot) {
                    size_t di = tr ? (((size_t)cn * Btot + m) * 20 + ce)
                                   : ((size_t)m * 600 + c);
                    h1[di] = fmaxf(acc[mi][ni][r] + b1f[c], 0.f);
                }
            }
        }
    }
}

// ---------------- K2n (main): per-net block, uniform W2 -> s_load, no LDS ----------------
// grid (ceil(B/256), 30). h1n[n][b][20] coalesced; W2t/b2f block-uniform fp32.
__global__ __launch_bounds__(256) void k2n(const float* __restrict__ h1n,
                                           const float* __restrict__ W2t,
                                           const float* __restrict__ b2f,
                                           bfu* __restrict__ ub32, int Btot) {
    const int n = blockIdx.y;
    int b = blockIdx.x * 256 + threadIdx.x;
    if (b >= Btot) b = Btot - 1;          // clamp (duplicate same-value write, benign)

    float h[20];
    const float* hp = h1n + ((size_t)n * Btot + b) * 20;
    #pragma unroll
    for (int d4 = 0; d4 < 20; d4 += 4) {
        float4 v = *(const float4*)(hp + d4);
        h[d4] = v.x; h[d4 + 1] = v.y; h[d4 + 2] = v.z; h[d4 + 3] = v.w;
    }

    const float* wn = W2t + n * 400;      // block-uniform
    const float* bn = b2f + n * 20;       // block-uniform
    float o[20], sq = 0.f;
    #pragma unroll
    for (int e = 0; e < 20; e++) {
        float acc = bn[e];
        #pragma unroll
        for (int d = 0; d < 20; d++) acc += h[d] * wn[e * 20 + d];
        acc = fmaxf(acc, 0.f);
        o[e] = acc;
        sq += acc * acc;
    }
    float sc = (sq > 0.f) ? sqrtf(sq) / (1.f + sq) : 0.f;

    u32 wbuf[16];
    #pragma unroll
    for (int j = 0; j < 10; j++)
        wbuf[j] = (u32)f2bf(o[2 * j] * sc) | ((u32)f2bf(o[2 * j + 1] * sc) << 16);
    #pragma unroll
    for (int j = 10; j < 16; j++) wbuf[j] = 0;
    uint4* dst = (uint4*)(ub32 + ((size_t)b * 30 + n) * 32);
    dst[0] = *(uint4*)&wbuf[0];
    dst[1] = *(uint4*)&wbuf[4];
    dst[2] = *(uint4*)&wbuf[8];
    dst[3] = *(uint4*)&wbuf[12];
}

// ---------------- K2 core (fallback path, validated math) ----------------
__device__ __forceinline__ void k2_core(const float* hp, const float* wn, const float* bn,
                                        float* o, float& sc) {
    float h[20];
    #pragma unroll
    for (int d4 = 0; d4 < 20; d4 += 4) {
        float4 v = *(const float4*)(hp + d4);
        h[d4] = v.x; h[d4 + 1] = v.y; h[d4 + 2] = v.z; h[d4 + 3] = v.w;
    }
    float sq = 0.f;
    #pragma unroll
    for (int e = 0; e < 20; e++) {
        float acc = bn[e];
        #pragma unroll
        for (int d = 0; d < 20; d++) acc += h[d] * wn[d * 20 + e];
        acc = fmaxf(acc, 0.f);
        o[e] = acc;
        sq += acc * acc;
    }
    sc = (sq > 0.f) ? sqrtf(sq) / (1.f + sq) : 0.f;
}

// K2s (fallback, validated): u fp32 in place
__global__ __launch_bounds__(256) void k2s(const float* h1, const void* W2, const void* b2,
                                           float* u, const u32* flags, int total) {
    __shared__ float W2s[12000];
    __shared__ float b2s[600];
    const bool wb = flags[3] != 0, bb = flags[4] != 0;
    const int tid = threadIdx.x;
    for (int i = tid; i < 12000; i += 256) W2s[i] = ldf(W2, i, wb);
    for (int i = tid; i < 600; i += 256) b2s[i] = ldf(b2, i, bb);
    __syncthreads();

    int t = blockIdx.x * 256 + tid;
    if (t >= total) return;
    const int b = t / 30, n = t - b * 30;
    float o[20], sc;
    k2_core(h1 + (size_t)b * 600 + n * 20, &W2s[n * 400], &b2s[n * 20], o, sc);
    float* up = u + (size_t)b * 600 + n * 20;
    #pragma unroll
    for (int e4 = 0; e4 < 20; e4 += 4) {
        float4 v;
        v.x = o[e4] * sc; v.y = o[e4 + 1] * sc; v.z = o[e4 + 2] * sc; v.w = o[e4 + 3] * sc;
        *(float4*)(up + e4) = v;
    }
}

// ---------------- K2p: priors GEMM via MFMA (main, validated) ----------------
// grid (ceil(B/128), 30); block 256 = 4 waves. pri[b][n*160 + o*16+k] bf16.
__global__ __launch_bounds__(256) void k2p(const bfu* __restrict__ ub32,
                                           const bfu* __restrict__ rwn,
                                           bfu* __restrict__ pri, int Btot) {
    const int tid = threadIdx.x;
    const int w = tid >> 6, lane = tid & 63;
    const int quad = lane >> 4, fl = lane & 15;
    const int n = blockIdx.y;
    const int b0 = blockIdx.x * 128;

    short8 bfr[10];
    #pragma unroll
    for (int nj = 0; nj < 10; nj++)
        bfr[nj] = *(const short8*)(rwn + ((size_t)n * 160 + nj * 16 + fl) * 32 + quad * 8);

    #pragma unroll
    for (int mi = 0; mi < 2; mi++) {
        int m = b0 + w * 32 + mi * 16 + fl;
        int mc = (m < Btot) ? m : Btot - 1;
        short8 af = *(const short8*)(ub32 + ((size_t)mc * 30 + n) * 32 + quad * 8);
        #pragma unroll
        for (int nj = 0; nj < 10; nj++) {
            floatx4 acc = (floatx4){0.f, 0.f, 0.f, 0.f};
            acc = __builtin_amdgcn_mfma_f32_16x16x32_bf16(af, bfr[nj], acc, 0, 0, 0);
            #pragma unroll
            for (int r = 0; r < 4; r++) {
                int mr = b0 + w * 32 + mi * 16 + quad * 4 + r;
                if (mr < Btot)
                    pri[(size_t)mr * 4800 + n * 160 + nj * 16 + fl] = f2bf(acc[r]);
            }
        }
    }
}

// ---------------- K3t: routing with k-in-register layout (main, validated @41us) ----------------
__global__ __launch_bounds__(640, 2) void k3t(const bfu* __restrict__ pri_buf,
                                              float* __restrict__ out, int Btot) {
    __shared__ float L[4][300];
    __shared__ float P[4][300];
    const int tid = threadIdx.x;
    const int g = tid / 160, r = tid - g * 160;
    const int o = r >> 4, j = r & 15;
    const int b0 = blockIdx.x * 4;
    int bb = b0 + g; if (bb >= Btot) bb = Btot - 1;

    const int n0 = 2 * j, n1 = n0 + 1;
    float p0[16], p1[16];
    if (j < 15) {
        const bfu* pb = pri_buf + (size_t)bb * 4800 + (size_t)o * 16;
        uint4 q0 = *(const uint4*)(pb + n0 * 160);
        uint4 q1 = *(const uint4*)(pb + n0 * 160 + 8);
        uint4 q2 = *(const uint4*)(pb + n1 * 160);
        uint4 q3 = *(const uint4*)(pb + n1 * 160 + 8);
        unpack8(q0, p0); unpack8(q1, p0 + 8);
        unpack8(q2, p1); unpack8(q3, p1 + 8);
    } else {
        #pragma unroll
        for (int i = 0; i < 16; i++) { p0[i] = 0.f; p1[i] = 0.f; }
    }

    float L0 = 0.f, L1 = 0.f;
    float v = 0.f;
    #pragma unroll
    for (int it = 0; it < 3; it++) {
        float P0, P1;
        if (it == 0) {
            P0 = 0.1f; P1 = 0.1f;              // softmax(zeros) over 10 outputs
        } else {
            if (r < 30) {                       // dedicated softmax over o for row n=r
                float l[10];
                #pragma unroll
                for (int oo = 0; oo < 10; oo++) l[oo] = L[g][r * 10 + oo];
                float mx = l[0];
                #pragma unroll
                for (int oo = 1; oo < 10; oo++) mx = fmaxf(mx, l[oo]);
                float den = 0.f;
                #pragma unroll
                for (int oo = 0; oo < 10; oo++) { l[oo] = __expf(l[oo] - mx); den += l[oo]; }
                float inv = 1.f / den;
                #pragma unroll
                for (int oo = 0; oo < 10; oo++) P[g][r * 10 + oo] = l[oo] * inv;
            }
            __syncthreads();
            P0 = (j < 15) ? P[g][n0 * 10 + o] : 0.f;
            P1 = (j < 15) ? P[g][n1 * 10 + o] : 0.f;
        }

        float t[16];
        #pragma unroll
        for (int i = 0; i < 16; i++) t[i] = P0 * p0[i] + P1 * p1[i];

        // 16-lane transpose-reduce: lane j ends with s[k=j] (15 shuffles)
        #pragma unroll
        for (int i = 0; i < 8; i++) {
            float send = (j & 8) ? t[i] : t[i + 8];
            float recv = __shfl_xor(send, 8, 16);
            t[i] = ((j & 8) ? t[i + 8] : t[i]) + recv;
        }
        #pragma unroll
        for (int i = 0; i < 4; i++) {
            float send = (j & 4) ? t[i] : t[i + 4];
            float recv = __shfl_xor(send, 4, 16);
            t[i] = ((j & 4) ? t[i + 4] : t[i]) + recv;
        }
        #pragma unroll
        for (int i = 0; i < 2; i++) {
            float send = (j & 2) ? t[i] : t[i + 2];
            float recv = __shfl_xor(send, 2, 16);
            t[i] = ((j & 2) ? t[i + 2] : t[i]) + recv;
        }
        {
            float send = (j & 1) ? t[0] : t[1];
            float recv = __shfl_xor(send, 1, 16);
            t[0] = ((j & 1) ? t[1] : t[0]) + recv;
        }
        float s = t[0];                         // s[o, k=j]

        if (it < 2) {
            float sf[16];
            #pragma unroll
            for (int k = 0; k < 16; k++) sf[k] = __shfl(s, k, 16);
            float q = 0.f;
            #pragma unroll
            for (int k = 0; k < 16; k++) q += sf[k] * sf[k];
            float scale = sqrtf(q) / (1.f + q);
            v = s * scale;
            float d0 = 0.f, d1 = 0.f;
            #pragma unroll
            for (int k = 0; k < 16; k++) {
                float vk = sf[k] * scale;
                d0 += p0[k] * vk;
                d1 += p1[k] * vk;
            }
            L0 += d0; L1 += d1;
            if (j < 15) {
                L[g][n0 * 10 + o] = L0;
                L[g][n1 * 10 + o] = L1;
            }
            __syncthreads();
        } else {
            float q = s * s;
            q += __shfl_xor(q, 1, 16);
            q += __shfl_xor(q, 2, 16);
            q += __shfl_xor(q, 4, 16);
            q += __shfl_xor(q, 8, 16);
            v = s * sqrtf(q) / (1.f + q);
        }
    }
    if ((b0 + g) < Btot) out[(size_t)(b0 + g) * 160 + r] = v;
}

// ---------------- K3y2 (fallback, validated @202us) ----------------
__global__ __launch_bounds__(640, 2) void k3y2(const float* __restrict__ u,
                                               const bfu* __restrict__ rwb,
                                               float* __restrict__ out, int Btot) {
    __shared__ float US[4][600];
    __shared__ float L[4][300];
    __shared__ float P[4][300];
    const int tid = threadIdx.x;
    const int g = tid / 160, r = tid - g * 160;
    const int o = r >> 4, k = r & 15;
    const int b0 = blockIdx.x * 4;

    {
        const int nf4 = 150;
        for (int i = tid; i < 4 * nf4; i += 640) {
            int gg = i / nf4, j = i - gg * nf4;
            int bb = b0 + gg; if (bb >= Btot) bb = Btot - 1;
            *(float4*)&US[gg][j * 4] = *(const float4*)(u + (size_t)bb * 600 + j * 4);
        }
        for (int i = tid; i < 1200; i += 640) L[i / 300][i % 300] = 0.f;
    }
    __syncthreads();

    float pri[30];
    const bfu* rp = rwb + o * 9600 + k * 20;
    #pragma unroll 2
    for (int n = 0; n < 30; n++) {
        const uint2* rq = (const uint2*)(rp + n * 320);
        float a = 0.f;
        #pragma unroll
        for (int jj = 0; jj < 5; jj++) {
            uint2 w = rq[jj];
            float4 uu = *(const float4*)&US[g][n * 20 + jj * 4];
            a += lo2f(w.x) * uu.x + hi2f(w.x) * uu.y + lo2f(w.y) * uu.z + hi2f(w.y) * uu.w;
        }
        pri[n] = a;
    }

    float v = 0.f;
    for (int it = 0; it < 3; it++) {
        if (r < 30) {
            const int n = r;
            float mx = L[g][n * 10];
            #pragma unroll
            for (int oo = 1; oo < 10; oo++) mx = fmaxf(mx, L[g][n * 10 + oo]);
            float e[10], den = 0.f;
            #pragma unroll
            for (int oo = 0; oo < 10; oo++) { e[oo] = __expf(L[g][n * 10 + oo] - mx); den += e[oo]; }
            float inv = 1.f / den;
            #pragma unroll
            for (int oo = 0; oo < 10; oo++) P[g][n * 10 + oo] = e[oo] * inv;
        }
        __syncthreads();
        float s = 0.f;
        #pragma unroll
        for (int n = 0; n < 30; n++) s += P[g][n * 10 + o] * pri[n];
        float q = s * s;
        q += __shfl_xor(q, 1, 16);
        q += __shfl_xor(q, 2, 16);
        q += __shfl_xor(q, 4, 16);
        q += __shfl_xor(q, 8, 16);
        v = s * sqrtf(q) / (1.f + q);
        if (it < 2) {
            #pragma unroll 5
            for (int n = 0; n < 30; n++) {
                float t = pri[n] * v;
                t += __shfl_xor(t, 1, 16);
                t += __shfl_xor(t, 2, 16);
                t += __shfl_xor(t, 4, 16);
                t += __shfl_xor(t, 8, 16);
                if (k == 0) L[g][n * 10 + o] += t;
            }
            __syncthreads();
        }
    }
    if ((b0 + g) < Btot) out[(size_t)(b0 + g) * 160 + r] = v;
}

extern "C" void kernel_launch(void* const* d_in, const int* in_sizes, int n_in,
                              void* d_out, int out_size, void* d_ws, size_t ws_size,
                              hipStream_t stream) {
    // ---- size-based input matching (validated) ----
    int ix = -1, iw1 = -1, ib1 = -1, iw2 = -1, ib2 = -1, irw = -1;
    for (int i = 0; i < n_in; i++) {
        int s = in_sizes[i];
        if (s == 470400 && iw1 < 0) iw1 = i;
        else if (s == 12000 && iw2 < 0) iw2 = i;
        else if (s == 96000 && irw < 0) irw = i;
        else if (s == 600) { if (ib1 < 0) ib1 = i; else if (ib2 < 0) ib2 = i; }
    }
    long bestsz = -1;
    for (int i = 0; i < n_in; i++) {
        if (i == iw1 || i == iw2 || i == irw || i == ib1 || i == ib2) continue;
        if ((long)in_sizes[i] > bestsz) { bestsz = in_sizes[i]; ix = i; }
    }
    if (ix < 0 || iw1 < 0 || ib1 < 0 || iw2 < 0 || ib2 < 0 || irw < 0) {
        ix = 0; iw1 = 1; ib1 = 2; iw2 = 3; ib2 = 4; irw = 5;
    }
    const void* x  = d_in[ix];
    const void* W1 = d_in[iw1];
    const void* b1 = d_in[ib1];
    const void* W2 = d_in[iw2];
    const void* b2 = d_in[ib2];
    const void* rw = d_in[irw];
    const int B = in_sizes[ix] / 784;
    float* out = (float*)d_out;

    // ---- ws layout (byte offsets, all 16B-aligned) ----
    char* base = (char*)d_ws;
    size_t off = 0;
    float* h1u  = (float*)(base + off); off += (size_t)B * 2400;       // B*600 f32
    float* b1f  = (float*)(base + off); off += 2560;                   // 640 f32
    u32*  flags = (u32*)(base + off);   off += 32;                     // 8 u32
    bfu*   Wt   = (bfu*)(base + off);   off += 1024000;                // 640*800 bf16
    bfu*   xb   = (bfu*)(base + off);   off += (size_t)B * 1600;       // B*800 bf16
    bfu*   rwb  = (bfu*)(base + off);   off += 192000;                 // 96000 bf16
    size_t fb_bytes = off;
    bfu*   rwn  = (bfu*)(base + off);   off += 307200;                 // 30*160*32 bf16
    float* W2t  = (float*)(base + off); off += 48000;                  // 30*20*20 f32
    float* b2f  = (float*)(base + off); off += 2560;                   // 640 f32
    bfu*   ub32 = (bfu*)(base + off);   off += (size_t)B * 1920;       // B*30*32 bf16
    bfu*   pri  = (bfu*)(base + off);   off += (size_t)B * 9600;       // B*4800 bf16
    size_t main_bytes = off;

    const int mode = (ws_size >= main_bytes) ? 0 : 1;   // fixed per-call -> graph-safe
    const int prep_total = B * 800 + 640 * 800 + 96000 + 640
                         + (mode == 0 ? (153600 + 12000 + 640) : 0);

    detect_dtype<<<1, 64, 0, stream>>>((const u32*)x, (const u32*)W1, (const u32*)b1,
                                       (const u32*)W2, (const u32*)b2, (const u32*)rw, flags);
    prep_all<<<(prep_total + 255) / 256, 256, 0, stream>>>(x, W1, b1, W2, b2, rw,
                                                           xb, Wt, b1f, rwb, rwn,
                                                           W2t, b2f, flags, B, mode);
    k1m<<<dim3((B + 127) / 128, 10), 256, 0, stream>>>(xb, Wt, b1f, h1u, B, mode == 0 ? 1 : 0);
    if (mode == 0) {
        k2n<<<dim3((B + 255) / 256, 30), 256, 0, stream>>>(h1u, W2t, b2f, ub32, B);
        k2p<<<dim3((B + 127) / 128, 30), 256, 0, stream>>>(ub32, rwn, pri, B);
        k3t<<<(B + 3) / 4, 640, 0, stream>>>(pri, out, B);
    } else {
        (void)fb_bytes;
        k2s<<<(B * 30 + 255) / 256, 256, 0, stream>>>(h1u, W2, b2, h1u, flags, B * 30);
        k3y2<<<(B + 3) / 4, 640, 0, stream>>>(h1u, rwb, out, B);
    }
}

// Round 3
// 191.088 us; speedup vs baseline: 1.4349x; 1.0015x over previous
//
#include <hip/hip_runtime.h>

// B(derived), IN_DIM=784, NUM_NETS=30, N_NODES=20, NUM_OUT=10, DIM_OUT=16, NUM_ITER=3
// Validated: size-based binding; dtype detect; k1m MFMA; k2n uniform-W2; k2p priors GEMM.
// R17: k3t (40.8us, DS+VALU bound: ~91 DS ops/lane x 20K waves ~= 18us DS pipe) -> k3u:
// 80 threads/row (4 nets/lane, p[4][16] regs). Same per-lane DS count but HALF the
// waves -> DS total halves; tree selects halve; FMA total constant. pri re-laid o-major
// [b][o][n][k] (free index change in k2p) so each lane loads 128B contiguous.
// Fallback k2s+k3y2 unchanged (b-major h1, rwb layout).

typedef unsigned short bfu;
typedef unsigned int u32;
typedef __attribute__((ext_vector_type(8))) short short8;
typedef __attribute__((ext_vector_type(4))) float floatx4;

__device__ __forceinline__ float bf2f(bfu u) { union { u32 i; float f; } v; v.i = ((u32)u) << 16; return v.f; }
__device__ __forceinline__ float lo2f(u32 w) { union { u32 i; float f; } v; v.i = w << 16; return v.f; }
__device__ __forceinline__ float hi2f(u32 w) { union { u32 i; float f; } v; v.i = w & 0xffff0000u; return v.f; }
__device__ __forceinline__ float ldf(const void* p, int idx, bool b16) {
    return b16 ? bf2f(((const bfu*)p)[idx]) : ((const float*)p)[idx];
}
__device__ __forceinline__ bfu f2bf(float f) {   // RNE
    u32 u = __float_as_uint(f);
    return (bfu)((u + 0x7FFFu + ((u >> 16) & 1u)) >> 16);
}
__device__ __forceinline__ void unpack8(uint4 q, float* dst) {
    dst[0] = lo2f(q.x); dst[1] = hi2f(q.x);
    dst[2] = lo2f(q.y); dst[3] = hi2f(q.y);
    dst[4] = lo2f(q.z); dst[5] = hi2f(q.z);
    dst[6] = lo2f(q.w); dst[7] = hi2f(q.w);
}

// ---- dtype detector (validated) ----
__global__ void detect_dtype(const u32* x, const u32* W1, const u32* b1,
                             const u32* W2, const u32* b2, const u32* rw,
                             u32* flags) {
    int t = threadIdx.x;
    if (t >= 6) return;
    const u32* p = (t == 0) ? x : (t == 1) ? W1 : (t == 2) ? b1
                 : (t == 3) ? W2 : (t == 4) ? b2 : rw;
    int c = 0;
    for (int i = 0; i < 64; i++) {
        u32 e = (p[i] >> 7) & 0xFF;
        c += (e >= 64 && e <= 140) ? 1 : 0;
    }
    flags[t] = (c >= 48) ? 1u : 0u;
}

// ---- prep_all: xb | Wt | rwb | b1f (+ rwn | W2t | b2f if mode==0) ----
__global__ void prep_all(const void* x, const void* W1, const void* b1,
                         const void* W2, const void* b2, const void* rw,
                         bfu* __restrict__ xb, bfu* __restrict__ Wt,
                         float* __restrict__ b1f, bfu* __restrict__ rwb,
                         bfu* __restrict__ rwn, float* __restrict__ W2t,
                         float* __restrict__ b2f,
                         const u32* flags, int B, int mode) {
    const int idx = blockIdx.x * 256 + threadIdx.x;
    const int nxb = B * 800;
    if (idx < nxb) {                                   // xb[B][800] bf16
        const bool b16 = flags[0] != 0;
        int b = idx / 800, kk = idx - b * 800;
        bfu v = 0;
        if (kk < 784) {
            int src = b * 784 + kk;
            v = b16 ? ((const bfu*)x)[src] : f2bf(((const float*)x)[src]);
        }
        xb[idx] = v;
        return;
    }
    int i2 = idx - nxb;
    if (i2 < 640 * 800) {                              // Wt[c][k] bf16
        const bool wb = flags[1] != 0;
        int c = i2 / 800, k = i2 - c * 800;
        bfu v = 0;
        if (c < 600 && k < 784) {
            int nn = c / 20, o = c - nn * 20;
            int src = nn * 15680 + k * 20 + o;
            v = wb ? ((const bfu*)W1)[src] : f2bf(((const float*)W1)[src]);
        }
        Wt[i2] = v;
        return;
    }
    i2 -= 640 * 800;
    if (i2 < 96000) {                                  // rwb[o][n][k][d] bf16 (fallback k3y2)
        const bool rb = flags[5] != 0;
        int d = i2 % 20;
        int k = (i2 / 20) % 16;
        int n = (i2 / 320) % 30;
        int o = i2 / 9600;
        int src = o * 9600 + n * 320 + d * 16 + k;
        rwb[i2] = rb ? ((const bfu*)rw)[src] : f2bf(((const float*)rw)[src]);
        return;
    }
    i2 -= 96000;
    if (i2 < 640) {                                    // b1f fp32
        b1f[i2] = (i2 < 600) ? ldf(b1, i2, flags[2] != 0) : 0.f;
        return;
    }
    i2 -= 640;
    if (mode != 0) return;
    if (i2 < 153600) {                                 // rwn[n][col=o*16+k][dd<32] bf16, K-pad
        const bool rb = flags[5] != 0;
        int dd = i2 % 32;
        int col = (i2 / 32) % 160;
        int n = i2 / 5120;
        bfu v = 0;
        if (dd < 20) {
            int o = col / 16, kk = col % 16;
            int src = o * 9600 + n * 320 + dd * 16 + kk;
            v = rb ? ((const bfu*)rw)[src] : f2bf(((const float*)rw)[src]);
        }
        rwn[i2] = v;
        return;
    }
    i2 -= 153600;
    if (i2 < 12000) {                                  // W2t[n][e][d] fp32 = W2[n][d][e]
        int d = i2 % 20;
        int e = (i2 / 20) % 20;
        int n = i2 / 400;
        W2t[i2] = ldf(W2, n * 400 + d * 20 + e, flags[3] != 0);
        return;
    }
    i2 -= 12000;
    if (i2 < 640) {                                    // b2f fp32
        b2f[i2] = (i2 < 600) ? ldf(b2, i2, flags[4] != 0) : 0.f;
    }
}

// ---------------- K1m: h1 = relu(xb @ Wt^T + b1), bf16 MFMA (validated) ----------------
// tr==1 (mode 0): store h1 as [n][b][20] (coalesced reads for k2n). tr==0: [b][600].
__global__ __launch_bounds__(256, 4) void k1m(const bfu* __restrict__ xb, const bfu* __restrict__ Wt,
                                              const float* __restrict__ b1f,
                                              float* __restrict__ h1, int Btot, int tr) {
    __shared__ short As[128 * 40];
    __shared__ short Bs[64 * 40];
    const int tid = threadIdx.x;
    const int w = tid >> 6, lane = tid & 63;
    const int quad = lane >> 4, fl = lane & 15;
    const int m0 = blockIdx.x * 128, n0 = blockIdx.y * 64;

    floatx4 acc[2][4];
    #pragma unroll
    for (int mi = 0; mi < 2; mi++)
        #pragma unroll
        for (int ni = 0; ni < 4; ni++) acc[mi][ni] = (floatx4){0.f, 0.f, 0.f, 0.f};

    const int arow = tid >> 1, aseg = tid & 1;
    const int brow = tid >> 2, bseg = tid & 3;
    int agrow = m0 + arow; if (agrow >= Btot) agrow = Btot - 1;
    const bfu* abase = xb + (size_t)agrow * 800 + aseg * 16;
    const bfu* bbase = Wt + (size_t)(n0 + brow) * 800 + bseg * 8;

    for (int k0 = 0; k0 < 800; k0 += 32) {
        uint4 qa0 = *(const uint4*)(abase + k0);
        uint4 qa1 = *(const uint4*)(abase + k0 + 8);
        uint4 qb  = *(const uint4*)(bbase + k0);

        __syncthreads();
        *(uint4*)&As[arow * 40 + aseg * 16 + 0] = qa0;
        *(uint4*)&As[arow * 40 + aseg * 16 + 8] = qa1;
        *(uint4*)&Bs[brow * 40 + bseg * 8] = qb;
        __syncthreads();

        short8 af[2], bfr[4];
        #pragma unroll
        for (int mi = 0; mi < 2; mi++)
            af[mi] = *(const short8*)&As[(w * 32 + mi * 16 + fl) * 40 + quad * 8];
        #pragma unroll
        for (int ni = 0; ni < 4; ni++)
            bfr[ni] = *(const short8*)&Bs[(ni * 16 + fl) * 40 + quad * 8];
        #pragma unroll
        for (int mi = 0; mi < 2; mi++)
            #pragma unroll
            for (int ni = 0; ni < 4; ni++)
                acc[mi][ni] = __builtin_amdgcn_mfma_f32_16x16x32_bf16(af[mi], bfr[ni], acc[mi][ni], 0, 0, 0);
    }

    #pragma unroll
    for (int mi = 0; mi < 2; mi++) {
        #pragma unroll
        for (int ni = 0; ni < 4; ni++) {
            const int c = n0 + ni * 16 + fl;
            const int cn = c / 20, ce = c - cn * 20;
            #pragma unroll
            for (int r = 0; r < 4; r++) {
                const int m = m0 + w * 32 + mi * 16 + quad * 4 + r;
                if (c < 600 && m < Btot) {
                    size_t di = tr ? (((size_t)cn * Btot + m) * 20 + ce)
                                   : ((size_t)m * 600 + c);
                    h1[di] = fmaxf(acc[mi][ni][r] + b1f[c], 0.f);
                }
            }
        }
    }
}

// ---------------- K2n (main): per-net block, uniform W2 -> s_load, no LDS ----------------
__global__ __launch_bounds__(256) void k2n(const float* __restrict__ h1n,
                                           const float* __restrict__ W2t,
                                           const float* __restrict__ b2f,
                                           bfu* __restrict__ ub32, int Btot) {
    const int n = blockIdx.y;
    int b = blockIdx.x * 256 + threadIdx.x;
    if (b >= Btot) b = Btot - 1;          // clamp (duplicate same-value write, benign)

    float h[20];
    const float* hp = h1n + ((size_t)n * Btot + b) * 20;
    #pragma unroll
    for (int d4 = 0; d4 < 20; d4 += 4) {
        float4 v = *(const float4*)(hp + d4);
        h[d4] = v.x; h[d4 + 1] = v.y; h[d4 + 2] = v.z; h[d4 + 3] = v.w;
    }

    const float* wn = W2t + n * 400;      // block-uniform
    const float* bn = b2f + n * 20;       // block-uniform
    float o[20], sq = 0.f;
    #pragma unroll
    for (int e = 0; e < 20; e++) {
        float acc = bn[e];
        #pragma unroll
        for (int d = 0; d < 20; d++) acc += h[d] * wn[e * 20 + d];
        acc = fmaxf(acc, 0.f);
        o[e] = acc;
        sq += acc * acc;
    }
    float sc = (sq > 0.f) ? sqrtf(sq) / (1.f + sq) : 0.f;

    u32 wbuf[16];
    #pragma unroll
    for (int j = 0; j < 10; j++)
        wbuf[j] = (u32)f2bf(o[2 * j] * sc) | ((u32)f2bf(o[2 * j + 1] * sc) << 16);
    #pragma unroll
    for (int j = 10; j < 16; j++) wbuf[j] = 0;
    uint4* dst = (uint4*)(ub32 + ((size_t)b * 30 + n) * 32);
    dst[0] = *(uint4*)&wbuf[0];
    dst[1] = *(uint4*)&wbuf[4];
    dst[2] = *(uint4*)&wbuf[8];
    dst[3] = *(uint4*)&wbuf[12];
}

// ---------------- K2 core (fallback path, validated math) ----------------
__device__ __forceinline__ void k2_core(const float* hp, const float* wn, const float* bn,
                                        float* o, float& sc) {
    float h[20];
    #pragma unroll
    for (int d4 = 0; d4 < 20; d4 += 4) {
        float4 v = *(const float4*)(hp + d4);
        h[d4] = v.x; h[d4 + 1] = v.y; h[d4 + 2] = v.z; h[d4 + 3] = v.w;
    }
    float sq = 0.f;
    #pragma unroll
    for (int e = 0; e < 20; e++) {
        float acc = bn[e];
        #pragma unroll
        for (int d = 0; d < 20; d++) acc += h[d] * wn[d * 20 + e];
        acc = fmaxf(acc, 0.f);
        o[e] = acc;
        sq += acc * acc;
    }
    sc = (sq > 0.f) ? sqrtf(sq) / (1.f + sq) : 0.f;
}

// K2s (fallback, validated): u fp32 in place
__global__ __launch_bounds__(256) void k2s(const float* h1, const void* W2, const void* b2,
                                           float* u, const u32* flags, int total) {
    __shared__ float W2s[12000];
    __shared__ float b2s[600];
    const bool wb = flags[3] != 0, bb = flags[4] != 0;
    const int tid = threadIdx.x;
    for (int i = tid; i < 12000; i += 256) W2s[i] = ldf(W2, i, wb);
    for (int i = tid; i < 600; i += 256) b2s[i] = ldf(b2, i, bb);
    __syncthreads();

    int t = blockIdx.x * 256 + tid;
    if (t >= total) return;
    const int b = t / 30, n = t - b * 30;
    float o[20], sc;
    k2_core(h1 + (size_t)b * 600 + n * 20, &W2s[n * 400], &b2s[n * 20], o, sc);
    float* up = u + (size_t)b * 600 + n * 20;
    #pragma unroll
    for (int e4 = 0; e4 < 20; e4 += 4) {
        float4 v;
        v.x = o[e4] * sc; v.y = o[e4 + 1] * sc; v.z = o[e4 + 2] * sc; v.w = o[e4 + 3] * sc;
        *(float4*)(up + e4) = v;
    }
}

// ---------------- K2p: priors GEMM via MFMA (main, validated math) ----------------
// grid (ceil(B/128), 30); block 256 = 4 waves. R17: o-major store pri[b][o*480+n*16+k].
__global__ __launch_bounds__(256) void k2p(const bfu* __restrict__ ub32,
                                           const bfu* __restrict__ rwn,
                                           bfu* __restrict__ pri, int Btot) {
    const int tid = threadIdx.x;
    const int w = tid >> 6, lane = tid & 63;
    const int quad = lane >> 4, fl = lane & 15;
    const int n = blockIdx.y;
    const int b0 = blockIdx.x * 128;

    short8 bfr[10];
    #pragma unroll
    for (int nj = 0; nj < 10; nj++)
        bfr[nj] = *(const short8*)(rwn + ((size_t)n * 160 + nj * 16 + fl) * 32 + quad * 8);

    #pragma unroll
    for (int mi = 0; mi < 2; mi++) {
        int m = b0 + w * 32 + mi * 16 + fl;
        int mc = (m < Btot) ? m : Btot - 1;
        short8 af = *(const short8*)(ub32 + ((size_t)mc * 30 + n) * 32 + quad * 8);
        #pragma unroll
        for (int nj = 0; nj < 10; nj++) {
            floatx4 acc = (floatx4){0.f, 0.f, 0.f, 0.f};
            acc = __builtin_amdgcn_mfma_f32_16x16x32_bf16(af, bfr[nj], acc, 0, 0, 0);
            #pragma unroll
            for (int r = 0; r < 4; r++) {
                int mr = b0 + w * 32 + mi * 16 + quad * 4 + r;
                if (mr < Btot)
                    pri[(size_t)mr * 4800 + nj * 480 + n * 16 + fl] = f2bf(acc[r]);
            }
        }
    }
}

// ---------------- K3u: routing, 80 threads/row, 4 nets/lane (main, R17) ----------------
// 320 thr = 4 rows/block; per row 80 threads (o=r>>3, j=r&7). Lane (o,j) holds
// pri[n=4j..4j+3][o][0..15] in regs (n>=30 pads zero). Tree-reduce over 8 lanes
// (xor4/2/1, 14 shfl) leaves s[2j],s[2j+1]; allgather 16 shfl; logits dot in-register.
// iter0 softmax(0)=0.1 hardcoded. Half the waves of k3t -> DS total halves.
__global__ __launch_bounds__(320) void k3u(const bfu* __restrict__ pri_buf,
                                           float* __restrict__ out, int Btot) {
    __shared__ float L[4][300];
    __shared__ float P[4][300];
    const int tid = threadIdx.x;
    const int g = tid / 80, r = tid - g * 80;
    const int o = r >> 3, j = r & 7;
    const int b0 = blockIdx.x * 4;
    int bb = b0 + g; if (bb >= Btot) bb = Btot - 1;

    // load pri[bb][o][4j..4j+3][0..15]  (o-major layout, 128B contiguous per lane)
    float p[4][16];
    const bfu* pb = pri_buf + (size_t)bb * 4800 + (size_t)o * 480 + j * 64;
    #pragma unroll
    for (int nn = 0; nn < 4; nn++) {
        if (4 * j + nn < 30) {
            uint4 q0 = *(const uint4*)(pb + nn * 16);
            uint4 q1 = *(const uint4*)(pb + nn * 16 + 8);
            unpack8(q0, p[nn]); unpack8(q1, p[nn] + 8);
        } else {
            #pragma unroll
            for (int i = 0; i < 16; i++) p[nn][i] = 0.f;
        }
    }

    float Lr[4] = {0.f, 0.f, 0.f, 0.f};
    float v0 = 0.f, v1 = 0.f;
    #pragma unroll
    for (int it = 0; it < 3; it++) {
        float t[16];
        if (it == 0) {
            #pragma unroll
            for (int i = 0; i < 16; i++)
                t[i] = 0.1f * ((p[0][i] + p[1][i]) + (p[2][i] + p[3][i]));
        } else {
            if (r < 30) {                       // dedicated softmax over o for net r
                float l[10];
                #pragma unroll
                for (int oo = 0; oo < 10; oo++) l[oo] = L[g][r * 10 + oo];
                float mx = l[0];
                #pragma unroll
                for (int oo = 1; oo < 10; oo++) mx = fmaxf(mx, l[oo]);
                float den = 0.f;
                #pragma unroll
                for (int oo = 0; oo < 10; oo++) { l[oo] = __expf(l[oo] - mx); den += l[oo]; }
                float inv = 1.f / den;
                #pragma unroll
                for (int oo = 0; oo < 10; oo++) P[g][r * 10 + oo] = l[oo] * inv;
            }
            __syncthreads();
            float Pw[4];
            #pragma unroll
            for (int nn = 0; nn < 4; nn++)
                Pw[nn] = (4 * j + nn < 30) ? P[g][(4 * j + nn) * 10 + o] : 0.f;
            #pragma unroll
            for (int i = 0; i < 16; i++)
                t[i] = (Pw[0] * p[0][i] + Pw[1] * p[1][i])
                     + (Pw[2] * p[2][i] + Pw[3] * p[3][i]);
        }

        // tree reduce 16-vector over 8 lanes: end lane j holds s[2j], s[2j+1]
        #pragma unroll
        for (int i = 0; i < 8; i++) {
            float send = (j & 4) ? t[i] : t[i + 8];
            float recv = __shfl_xor(send, 4, 8);
            t[i] = ((j & 4) ? t[i + 8] : t[i]) + recv;
        }
        #pragma unroll
        for (int i = 0; i < 4; i++) {
            float send = (j & 2) ? t[i] : t[i + 4];
            float recv = __shfl_xor(send, 2, 8);
            t[i] = ((j & 2) ? t[i + 4] : t[i]) + recv;
        }
        #pragma unroll
        for (int i = 0; i < 2; i++) {
            float send = (j & 1) ? t[i] : t[i + 2];
            float recv = __shfl_xor(send, 1, 8);
            t[i] = ((j & 1) ? t[i + 2] : t[i]) + recv;
        }

        if (it < 2) {
            float sf[16];
            #pragma unroll
            for (int q8 = 0; q8 < 8; q8++) {
                sf[2 * q8]     = __shfl(t[0], q8, 8);
                sf[2 * q8 + 1] = __shfl(t[1], q8, 8);
            }
            float qq = 0.f;
            #pragma unroll
            for (int k = 0; k < 16; k++) qq += sf[k] * sf[k];
            float scale = sqrtf(qq) / (1.f + qq);
            float d[4] = {0.f, 0.f, 0.f, 0.f};
            #pragma unroll
            for (int k = 0; k < 16; k++) {
                float vk = sf[k] * scale;
                d[0] += p[0][k] * vk;
                d[1] += p[1][k] * vk;
                d[2] += p[2][k] * vk;
                d[3] += p[3][k] * vk;
            }
            #pragma unroll
            for (int nn = 0; nn < 4; nn++) {
                Lr[nn] += d[nn];
                if (4 * j + nn < 30) L[g][(4 * j + nn) * 10 + o] = Lr[nn];
            }
            __syncthreads();
        } else {
            float qq = t[0] * t[0] + t[1] * t[1];
            qq += __shfl_xor(qq, 1, 8);
            qq += __shfl_xor(qq, 2, 8);
            qq += __shfl_xor(qq, 4, 8);
            float scale = sqrtf(qq) / (1.f + qq);
            v0 = t[0] * scale;
            v1 = t[1] * scale;
        }
    }
    if ((b0 + g) < Btot) {
        float2 w; w.x = v0; w.y = v1;
        *(float2*)(out + (size_t)(b0 + g) * 160 + o * 16 + 2 * j) = w;
    }
}

// ---------------- K3y2 (fallback, validated @202us) ----------------
__global__ __launch_bounds__(640, 2) void k3y2(const float* __restrict__ u,
                                               const bfu* __restrict__ rwb,
                                               float* __restrict__ out, int Btot) {
    __shared__ float US[4][600];
    __shared__ float L[4][300];
    __shared__ float P[4][300];
    const int tid = threadIdx.x;
    const int g = tid / 160, r = tid - g * 160;
    const int o = r >> 4, k = r & 15;
    const int b0 = blockIdx.x * 4;

    {
        const int nf4 = 150;
        for (int i = tid; i < 4 * nf4; i += 640) {
            int gg = i / nf4, j = i - gg * nf4;
            int bb = b0 + gg; if (bb >= Btot) bb = Btot - 1;
            *(float4*)&US[gg][j * 4] = *(const float4*)(u + (size_t)bb * 600 + j * 4);
        }
        for (int i = tid; i < 1200; i += 640) L[i / 300][i % 300] = 0.f;
    }
    __syncthreads();

    float pri[30];
    const bfu* rp = rwb + o * 9600 + k * 20;
    #pragma unroll 2
    for (int n = 0; n < 30; n++) {
        const uint2* rq = (const uint2*)(rp + n * 320);
        float a = 0.f;
        #pragma unroll
        for (int jj = 0; jj < 5; jj++) {
            uint2 w = rq[jj];
            float4 uu = *(const float4*)&US[g][n * 20 + jj * 4];
            a += lo2f(w.x) * uu.x + hi2f(w.x) * uu.y + lo2f(w.y) * uu.z + hi2f(w.y) * uu.w;
        }
        pri[n] = a;
    }

    float v = 0.f;
    for (int it = 0; it < 3; it++) {
        if (r < 30) {
            const int n = r;
            float mx = L[g][n * 10];
            #pragma unroll
            for (int oo = 1; oo < 10; oo++) mx = fmaxf(mx, L[g][n * 10 + oo]);
            float e[10], den = 0.f;
            #pragma unroll
            for (int oo = 0; oo < 10; oo++) { e[oo] = __expf(L[g][n * 10 + oo] - mx); den += e[oo]; }
            float inv = 1.f / den;
            #pragma unroll
            for (int oo = 0; oo < 10; oo++) P[g][n * 10 + oo] = e[oo] * inv;
        }
        __syncthreads();
        float s = 0.f;
        #pragma unroll
        for (int n = 0; n < 30; n++) s += P[g][n * 10 + o] * pri[n];
        float q = s * s;
        q += __shfl_xor(q, 1, 16);
        q += __shfl_xor(q, 2, 16);
        q += __shfl_xor(q, 4, 16);
        q += __shfl_xor(q, 8, 16);
        v = s * sqrtf(q) / (1.f + q);
        if (it < 2) {
            #pragma unroll 5
            for (int n = 0; n < 30; n++) {
                float t = pri[n] * v;
                t += __shfl_xor(t, 1, 16);
                t += __shfl_xor(t, 2, 16);
                t += __shfl_xor(t, 4, 16);
                t += __shfl_xor(t, 8, 16);
                if (k == 0) L[g][n * 10 + o] += t;
            }
            __syncthreads();
        }
    }
    if ((b0 + g) < Btot) out[(size_t)(b0 + g) * 160 + r] = v;
}

extern "C" void kernel_launch(void* const* d_in, const int* in_sizes, int n_in,
                              void* d_out, int out_size, void* d_ws, size_t ws_size,
                              hipStream_t stream) {
    // ---- size-based input matching (validated) ----
    int ix = -1, iw1 = -1, ib1 = -1, iw2 = -1, ib2 = -1, irw = -1;
    for (int i = 0; i < n_in; i++) {
        int s = in_sizes[i];
        if (s == 470400 && iw1 < 0) iw1 = i;
        else if (s == 12000 && iw2 < 0) iw2 = i;
        else if (s == 96000 && irw < 0) irw = i;
        else if (s == 600) { if (ib1 < 0) ib1 = i; else if (ib2 < 0) ib2 = i; }
    }
    long bestsz = -1;
    for (int i = 0; i < n_in; i++) {
        if (i == iw1 || i == iw2 || i == irw || i == ib1 || i == ib2) continue;
        if ((long)in_sizes[i] > bestsz) { bestsz = in_sizes[i]; ix = i; }
    }
    if (ix < 0 || iw1 < 0 || ib1 < 0 || iw2 < 0 || ib2 < 0 || irw < 0) {
        ix = 0; iw1 = 1; ib1 = 2; iw2 = 3; ib2 = 4; irw = 5;
    }
    const void* x  = d_in[ix];
    const void* W1 = d_in[iw1];
    const void* b1 = d_in[ib1];
    const void* W2 = d_in[iw2];
    const void* b2 = d_in[ib2];
    const void* rw = d_in[irw];
    const int B = in_sizes[ix] / 784;
    float* out = (float*)d_out;

    // ---- ws layout (byte offsets, all 16B-aligned) ----
    char* base = (char*)d_ws;
    size_t off = 0;
    float* h1u  = (float*)(base + off); off += (size_t)B * 2400;       // B*600 f32
    float* b1f  = (float*)(base + off); off += 2560;                   // 640 f32
    u32*  flags = (u32*)(base + off);   off += 32;                     // 8 u32
    bfu*   Wt   = (bfu*)(base + off);   off += 1024000;                // 640*800 bf16
    bfu*   xb   = (bfu*)(base + off);   off += (size_t)B * 1600;       // B*800 bf16
    bfu*   rwb  = (bfu*)(base + off);   off += 192000;                 // 96000 bf16
    size_t fb_bytes = off;
    bfu*   rwn  = (bfu*)(base + off);   off += 307200;                 // 30*160*32 bf16
    float* W2t  = (float*)(base + off); off += 48000;                  // 30*20*20 f32
    float* b2f  = (float*)(base + off); off += 2560;                   // 640 f32
    bfu*   ub32 = (bfu*)(base + off);   off += (size_t)B * 1920;       // B*30*32 bf16
    bfu*   pri  = (bfu*)(base + off);   off += (size_t)B * 9600;       // B*4800 bf16
    size_t main_bytes = off;

    const int mode = (ws_size >= main_bytes) ? 0 : 1;   // fixed per-call -> graph-safe
    const int prep_total = B * 800 + 640 * 800 + 96000 + 640
                         + (mode == 0 ? (153600 + 12000 + 640) : 0);

    detect_dtype<<<1, 64, 0, stream>>>((const u32*)x, (const u32*)W1, (const u32*)b1,
                                       (const u32*)W2, (const u32*)b2, (const u32*)rw, flags);
    prep_all<<<(prep_total + 255) / 256, 256, 0, stream>>>(x, W1, b1, W2, b2, rw,
                                                           xb, Wt, b1f, rwb, rwn,
                                                           W2t, b2f, flags, B, mode);
    k1m<<<dim3((B + 127) / 128, 10), 256, 0, stream>>>(xb, Wt, b1f, h1u, B, mode == 0 ? 1 : 0);
    if (mode == 0) {
        k2n<<<dim3((B + 255) / 256, 30), 256, 0, stream>>>(h1u, W2t, b2f, ub32, B);
        k2p<<<dim3((B + 127) / 128, 30), 256, 0, stream>>>(ub32, rwn, pri, B);
        k3u<<<(B + 3) / 4, 320, 0, stream>>>(pri, out, B);
    } else {
        (void)fb_bytes;
        k2s<<<(B * 30 + 255) / 256, 256, 0, stream>>>(h1u, W2, b2, h1u, flags, B * 30);
        k3y2<<<(B + 3) / 4, 640, 0, stream>>>(h1u, rwb, out, B);
    }
}

// Round 4
// 188.904 us; speedup vs baseline: 1.4515x; 1.0116x over previous
//
#include <hip/hip_runtime.h>

// B(derived), IN_DIM=784, NUM_NETS=30, N_NODES=20, NUM_OUT=10, DIM_OUT=16, NUM_ITER=3
// Validated: size-based binding; dtype detect; k1m MFMA (tr=1: h1 [n][b][20]); k3t routing.
// R18: (a) R17 post-mortem: k3u (80thr/row) REGRESSED -- latency-bound, fewer waves hurt.
// Revert to k3t (proven 40.8us) but keep o-major pri [b][o][n][k]: lane (o,j) now loads
// nets 2j,2j+1 as ONE 64B contiguous run (was 4x16B scattered over 640B, ~2x fetch amp).
// (b) Fuse k2n+k2p -> k2q: u computed in-reg from h1n (2 thr/row, partner shuffle for
// ||u||^2), exchanged via 10KB LDS tile [128][40] (16B-aligned b128, 2-way alias = free),
// then k2p's MFMA + o-major store. Kills ub32 write+read (31MB) + one launch.
// Fallback k2s+k3y2 unchanged.

typedef unsigned short bfu;
typedef unsigned int u32;
typedef __attribute__((ext_vector_type(8))) short short8;
typedef __attribute__((ext_vector_type(4))) float floatx4;

__device__ __forceinline__ float bf2f(bfu u) { union { u32 i; float f; } v; v.i = ((u32)u) << 16; return v.f; }
__device__ __forceinline__ float lo2f(u32 w) { union { u32 i; float f; } v; v.i = w << 16; return v.f; }
__device__ __forceinline__ float hi2f(u32 w) { union { u32 i; float f; } v; v.i = w & 0xffff0000u; return v.f; }
__device__ __forceinline__ float ldf(const void* p, int idx, bool b16) {
    return b16 ? bf2f(((const bfu*)p)[idx]) : ((const float*)p)[idx];
}
__device__ __forceinline__ bfu f2bf(float f) {   // RNE
    u32 u = __float_as_uint(f);
    return (bfu)((u + 0x7FFFu + ((u >> 16) & 1u)) >> 16);
}
__device__ __forceinline__ void unpack8(uint4 q, float* dst) {
    dst[0] = lo2f(q.x); dst[1] = hi2f(q.x);
    dst[2] = lo2f(q.y); dst[3] = hi2f(q.y);
    dst[4] = lo2f(q.z); dst[5] = hi2f(q.z);
    dst[6] = lo2f(q.w); dst[7] = hi2f(q.w);
}

// ---- dtype detector (validated) ----
__global__ void detect_dtype(const u32* x, const u32* W1, const u32* b1,
                             const u32* W2, const u32* b2, const u32* rw,
                             u32* flags) {
    int t = threadIdx.x;
    if (t >= 6) return;
    const u32* p = (t == 0) ? x : (t == 1) ? W1 : (t == 2) ? b1
                 : (t == 3) ? W2 : (t == 4) ? b2 : rw;
    int c = 0;
    for (int i = 0; i < 64; i++) {
        u32 e = (p[i] >> 7) & 0xFF;
        c += (e >= 64 && e <= 140) ? 1 : 0;
    }
    flags[t] = (c >= 48) ? 1u : 0u;
}

// ---- prep_all: xb | Wt | rwb | b1f (+ rwn | W2t | b2f if mode==0) ----
__global__ void prep_all(const void* x, const void* W1, const void* b1,
                         const void* W2, const void* b2, const void* rw,
                         bfu* __restrict__ xb, bfu* __restrict__ Wt,
                         float* __restrict__ b1f, bfu* __restrict__ rwb,
                         bfu* __restrict__ rwn, float* __restrict__ W2t,
                         float* __restrict__ b2f,
                         const u32* flags, int B, int mode) {
    const int idx = blockIdx.x * 256 + threadIdx.x;
    const int nxb = B * 800;
    if (idx < nxb) {                                   // xb[B][800] bf16
        const bool b16 = flags[0] != 0;
        int b = idx / 800, kk = idx - b * 800;
        bfu v = 0;
        if (kk < 784) {
            int src = b * 784 + kk;
            v = b16 ? ((const bfu*)x)[src] : f2bf(((const float*)x)[src]);
        }
        xb[idx] = v;
        return;
    }
    int i2 = idx - nxb;
    if (i2 < 640 * 800) {                              // Wt[c][k] bf16
        const bool wb = flags[1] != 0;
        int c = i2 / 800, k = i2 - c * 800;
        bfu v = 0;
        if (c < 600 && k < 784) {
            int nn = c / 20, o = c - nn * 20;
            int src = nn * 15680 + k * 20 + o;
            v = wb ? ((const bfu*)W1)[src] : f2bf(((const float*)W1)[src]);
        }
        Wt[i2] = v;
        return;
    }
    i2 -= 640 * 800;
    if (i2 < 96000) {                                  // rwb[o][n][k][d] bf16 (fallback k3y2)
        const bool rb = flags[5] != 0;
        int d = i2 % 20;
        int k = (i2 / 20) % 16;
        int n = (i2 / 320) % 30;
        int o = i2 / 9600;
        int src = o * 9600 + n * 320 + d * 16 + k;
        rwb[i2] = rb ? ((const bfu*)rw)[src] : f2bf(((const float*)rw)[src]);
        return;
    }
    i2 -= 96000;
    if (i2 < 640) {                                    // b1f fp32
        b1f[i2] = (i2 < 600) ? ldf(b1, i2, flags[2] != 0) : 0.f;
        return;
    }
    i2 -= 640;
    if (mode != 0) return;
    if (i2 < 153600) {                                 // rwn[n][col=o*16+k][dd<32] bf16, K-pad
        const bool rb = flags[5] != 0;
        int dd = i2 % 32;
        int col = (i2 / 32) % 160;
        int n = i2 / 5120;
        bfu v = 0;
        if (dd < 20) {
            int o = col / 16, kk = col % 16;
            int src = o * 9600 + n * 320 + dd * 16 + kk;
            v = rb ? ((const bfu*)rw)[src] : f2bf(((const float*)rw)[src]);
        }
        rwn[i2] = v;
        return;
    }
    i2 -= 153600;
    if (i2 < 12000) {                                  // W2t[n][e][d] fp32 = W2[n][d][e]
        int d = i2 % 20;
        int e = (i2 / 20) % 20;
        int n = i2 / 400;
        W2t[i2] = ldf(W2, n * 400 + d * 20 + e, flags[3] != 0);
        return;
    }
    i2 -= 12000;
    if (i2 < 640) {                                    // b2f fp32
        b2f[i2] = (i2 < 600) ? ldf(b2, i2, flags[4] != 0) : 0.f;
    }
}

// ---------------- K1m: h1 = relu(xb @ Wt^T + b1), bf16 MFMA (validated) ----------------
// tr==1 (mode 0): store h1 as [n][b][20] (coalesced reads for k2q). tr==0: [b][600].
__global__ __launch_bounds__(256, 4) void k1m(const bfu* __restrict__ xb, const bfu* __restrict__ Wt,
                                              const float* __restrict__ b1f,
                                              float* __restrict__ h1, int Btot, int tr) {
    __shared__ short As[128 * 40];
    __shared__ short Bs[64 * 40];
    const int tid = threadIdx.x;
    const int w = tid >> 6, lane = tid & 63;
    const int quad = lane >> 4, fl = lane & 15;
    const int m0 = blockIdx.x * 128, n0 = blockIdx.y * 64;

    floatx4 acc[2][4];
    #pragma unroll
    for (int mi = 0; mi < 2; mi++)
        #pragma unroll
        for (int ni = 0; ni < 4; ni++) acc[mi][ni] = (floatx4){0.f, 0.f, 0.f, 0.f};

    const int arow = tid >> 1, aseg = tid & 1;
    const int brow = tid >> 2, bseg = tid & 3;
    int agrow = m0 + arow; if (agrow >= Btot) agrow = Btot - 1;
    const bfu* abase = xb + (size_t)agrow * 800 + aseg * 16;
    const bfu* bbase = Wt + (size_t)(n0 + brow) * 800 + bseg * 8;

    for (int k0 = 0; k0 < 800; k0 += 32) {
        uint4 qa0 = *(const uint4*)(abase + k0);
        uint4 qa1 = *(const uint4*)(abase + k0 + 8);
        uint4 qb  = *(const uint4*)(bbase + k0);

        __syncthreads();
        *(uint4*)&As[arow * 40 + aseg * 16 + 0] = qa0;
        *(uint4*)&As[arow * 40 + aseg * 16 + 8] = qa1;
        *(uint4*)&Bs[brow * 40 + bseg * 8] = qb;
        __syncthreads();

        short8 af[2], bfr[4];
        #pragma unroll
        for (int mi = 0; mi < 2; mi++)
            af[mi] = *(const short8*)&As[(w * 32 + mi * 16 + fl) * 40 + quad * 8];
        #pragma unroll
        for (int ni = 0; ni < 4; ni++)
            bfr[ni] = *(const short8*)&Bs[(ni * 16 + fl) * 40 + quad * 8];
        #pragma unroll
        for (int mi = 0; mi < 2; mi++)
            #pragma unroll
            for (int ni = 0; ni < 4; ni++)
                acc[mi][ni] = __builtin_amdgcn_mfma_f32_16x16x32_bf16(af[mi], bfr[ni], acc[mi][ni], 0, 0, 0);
    }

    #pragma unroll
    for (int mi = 0; mi < 2; mi++) {
        #pragma unroll
        for (int ni = 0; ni < 4; ni++) {
            const int c = n0 + ni * 16 + fl;
            const int cn = c / 20, ce = c - cn * 20;
            #pragma unroll
            for (int r = 0; r < 4; r++) {
                const int m = m0 + w * 32 + mi * 16 + quad * 4 + r;
                if (c < 600 && m < Btot) {
                    size_t di = tr ? (((size_t)cn * Btot + m) * 20 + ce)
                                   : ((size_t)m * 600 + c);
                    h1[di] = fmaxf(acc[mi][ni][r] + b1f[c], 0.f);
                }
            }
        }
    }
}

// ---------------- K2q (main, R18): fused u-compute + priors MFMA ----------------
// grid (ceil(B/128), 30); block 256. Phase 1: 2 thr/row compute u[row][e] (10 e each,
// partner __shfl_xor for ||u||^2), write bf16 to us[128][40] (k-padded to 32).
// Phase 2: k2p MFMA body, af from LDS; o-major store pri[b][o*480+n*16+k] bf16.
__global__ __launch_bounds__(256) void k2q(const float* __restrict__ h1n,
                                           const float* __restrict__ W2t,
                                           const float* __restrict__ b2f,
                                           const bfu* __restrict__ rwn,
                                           bfu* __restrict__ pri, int Btot) {
    __shared__ short us[128 * 40];
    const int tid = threadIdx.x;
    const int n = blockIdx.y;
    const int b0 = blockIdx.x * 128;

    // issue B-operand global loads early (rwn is small + L2-hot)
    const int w = tid >> 6, lane = tid & 63;
    const int quad = lane >> 4, fl = lane & 15;
    short8 bfr[10];
    #pragma unroll
    for (int nj = 0; nj < 10; nj++)
        bfr[nj] = *(const short8*)(rwn + ((size_t)n * 160 + nj * 16 + fl) * 32 + quad * 8);

    // ---- phase 1: u for rows b0..b0+127 ----
    {
        const int row = tid >> 1, half = tid & 1;
        int br = b0 + row; if (br >= Btot) br = Btot - 1;
        float h[20];
        const float* hp = h1n + ((size_t)n * Btot + br) * 20;
        #pragma unroll
        for (int d4 = 0; d4 < 20; d4 += 4) {
            float4 v = *(const float4*)(hp + d4);
            h[d4] = v.x; h[d4 + 1] = v.y; h[d4 + 2] = v.z; h[d4 + 3] = v.w;
        }
        const float* wn = W2t + n * 400;      // block-uniform
        const float* bn = b2f + n * 20;       // block-uniform
        float o[10], sq = 0.f;
        #pragma unroll
        for (int i = 0; i < 10; i++) {
            const int e = 2 * i + half;
            float acc = bn[e];
            #pragma unroll
            for (int d = 0; d < 20; d++) acc += h[d] * wn[e * 20 + d];
            acc = fmaxf(acc, 0.f);
            o[i] = acc;
            sq += acc * acc;
        }
        sq += __shfl_xor(sq, 1);              // partner (same row) -> full ||u||^2
        float sc = (sq > 0.f) ? sqrtf(sq) / (1.f + sq) : 0.f;
        #pragma unroll
        for (int i = 0; i < 10; i++)
            us[row * 40 + 2 * i + half] = (short)f2bf(o[i] * sc);
        #pragma unroll
        for (int i = 10; i < 16; i++)         // zero-pad k=20..31
            us[row * 40 + 2 * i + half] = 0;
    }
    __syncthreads();

    // ---- phase 2: priors MFMA (k2p body, af from LDS) ----
    #pragma unroll
    for (int mi = 0; mi < 2; mi++) {
        short8 af = *(const short8*)&us[(w * 32 + mi * 16 + fl) * 40 + quad * 8];
        #pragma unroll
        for (int nj = 0; nj < 10; nj++) {
            floatx4 acc = (floatx4){0.f, 0.f, 0.f, 0.f};
            acc = __builtin_amdgcn_mfma_f32_16x16x32_bf16(af, bfr[nj], acc, 0, 0, 0);
            #pragma unroll
            for (int r = 0; r < 4; r++) {
                int mr = b0 + w * 32 + mi * 16 + quad * 4 + r;
                if (mr < Btot)
                    pri[(size_t)mr * 4800 + nj * 480 + n * 16 + fl] = f2bf(acc[r]);
            }
        }
    }
}

// ---------------- K2 core (fallback path, validated math) ----------------
__device__ __forceinline__ void k2_core(const float* hp, const float* wn, const float* bn,
                                        float* o, float& sc) {
    float h[20];
    #pragma unroll
    for (int d4 = 0; d4 < 20; d4 += 4) {
        float4 v = *(const float4*)(hp + d4);
        h[d4] = v.x; h[d4 + 1] = v.y; h[d4 + 2] = v.z; h[d4 + 3] = v.w;
    }
    float sq = 0.f;
    #pragma unroll
    for (int e = 0; e < 20; e++) {
        float acc = bn[e];
        #pragma unroll
        for (int d = 0; d < 20; d++) acc += h[d] * wn[d * 20 + e];
        acc = fmaxf(acc, 0.f);
        o[e] = acc;
        sq += acc * acc;
    }
    sc = (sq > 0.f) ? sqrtf(sq) / (1.f + sq) : 0.f;
}

// K2s (fallback, validated): u fp32 in place
__global__ __launch_bounds__(256) void k2s(const float* h1, const void* W2, const void* b2,
                                           float* u, const u32* flags, int total) {
    __shared__ float W2s[12000];
    __shared__ float b2s[600];
    const bool wb = flags[3] != 0, bb = flags[4] != 0;
    const int tid = threadIdx.x;
    for (int i = tid; i < 12000; i += 256) W2s[i] = ldf(W2, i, wb);
    for (int i = tid; i < 600; i += 256) b2s[i] = ldf(b2, i, bb);
    __syncthreads();

    int t = blockIdx.x * 256 + tid;
    if (t >= total) return;
    const int b = t / 30, n = t - b * 30;
    float o[20], sc;
    k2_core(h1 + (size_t)b * 600 + n * 20, &W2s[n * 400], &b2s[n * 20], o, sc);
    float* up = u + (size_t)b * 600 + n * 20;
    #pragma unroll
    for (int e4 = 0; e4 < 20; e4 += 4) {
        float4 v;
        v.x = o[e4] * sc; v.y = o[e4 + 1] * sc; v.z = o[e4 + 2] * sc; v.w = o[e4 + 3] * sc;
        *(float4*)(up + e4) = v;
    }
}

// ---------------- K3t: routing, k-in-register (main, validated @40.8us) ----------------
// R18: o-major pri -> lane (o,j) loads nets 2j,2j+1 as one 64B contiguous run.
__global__ __launch_bounds__(640, 2) void k3t(const bfu* __restrict__ pri_buf,
                                              float* __restrict__ out, int Btot) {
    __shared__ float L[4][300];
    __shared__ float P[4][300];
    const int tid = threadIdx.x;
    const int g = tid / 160, r = tid - g * 160;
    const int o = r >> 4, j = r & 15;
    const int b0 = blockIdx.x * 4;
    int bb = b0 + g; if (bb >= Btot) bb = Btot - 1;

    const int n0 = 2 * j, n1 = n0 + 1;
    float p0[16], p1[16];
    if (j < 15) {
        const bfu* pb = pri_buf + (size_t)bb * 4800 + (size_t)o * 480 + j * 32;
        uint4 q0 = *(const uint4*)(pb);        // n0 k0..7
        uint4 q1 = *(const uint4*)(pb + 8);    // n0 k8..15
        uint4 q2 = *(const uint4*)(pb + 16);   // n1 k0..7
        uint4 q3 = *(const uint4*)(pb + 24);   // n1 k8..15
        unpack8(q0, p0); unpack8(q1, p0 + 8);
        unpack8(q2, p1); unpack8(q3, p1 + 8);
    } else {
        #pragma unroll
        for (int i = 0; i < 16; i++) { p0[i] = 0.f; p1[i] = 0.f; }
    }

    float L0 = 0.f, L1 = 0.f;
    float v = 0.f;
    #pragma unroll
    for (int it = 0; it < 3; it++) {
        float P0, P1;
        if (it == 0) {
            P0 = 0.1f; P1 = 0.1f;              // softmax(zeros) over 10 outputs
        } else {
            if (r < 30) {                       // dedicated softmax over o for net r
                float l[10];
                #pragma unroll
                for (int oo = 0; oo < 10; oo++) l[oo] = L[g][r * 10 + oo];
                float mx = l[0];
                #pragma unroll
                for (int oo = 1; oo < 10; oo++) mx = fmaxf(mx, l[oo]);
                float den = 0.f;
                #pragma unroll
                for (int oo = 0; oo < 10; oo++) { l[oo] = __expf(l[oo] - mx); den += l[oo]; }
                float inv = 1.f / den;
                #pragma unroll
                for (int oo = 0; oo < 10; oo++) P[g][r * 10 + oo] = l[oo] * inv;
            }
            __syncthreads();
            P0 = (j < 15) ? P[g][n0 * 10 + o] : 0.f;
            P1 = (j < 15) ? P[g][n1 * 10 + o] : 0.f;
        }

        float t[16];
        #pragma unroll
        for (int i = 0; i < 16; i++) t[i] = P0 * p0[i] + P1 * p1[i];

        // 16-lane transpose-reduce: lane j ends with s[k=j] (15 shuffles)
        #pragma unroll
        for (int i = 0; i < 8; i++) {
            float send = (j & 8) ? t[i] : t[i + 8];
            float recv = __shfl_xor(send, 8, 16);
            t[i] = ((j & 8) ? t[i + 8] : t[i]) + recv;
        }
        #pragma unroll
        for (int i = 0; i < 4; i++) {
            float send = (j & 4) ? t[i] : t[i + 4];
            float recv = __shfl_xor(send, 4, 16);
            t[i] = ((j & 4) ? t[i + 4] : t[i]) + recv;
        }
        #pragma unroll
        for (int i = 0; i < 2; i++) {
            float send = (j & 2) ? t[i] : t[i + 2];
            float recv = __shfl_xor(send, 2, 16);
            t[i] = ((j & 2) ? t[i + 2] : t[i]) + recv;
        }
        {
            float send = (j & 1) ? t[0] : t[1];
            float recv = __shfl_xor(send, 1, 16);
            t[0] = ((j & 1) ? t[1] : t[0]) + recv;
        }
        float s = t[0];                         // s[o, k=j]

        if (it < 2) {
            float sf[16];
            #pragma unroll
            for (int k = 0; k < 16; k++) sf[k] = __shfl(s, k, 16);
            float q = 0.f;
            #pragma unroll
            for (int k = 0; k < 16; k++) q += sf[k] * sf[k];
            float scale = sqrtf(q) / (1.f + q);
            v = s * scale;
            float d0 = 0.f, d1 = 0.f;
            #pragma unroll
            for (int k = 0; k < 16; k++) {
                float vk = sf[k] * scale;
                d0 += p0[k] * vk;
                d1 += p1[k] * vk;
            }
            L0 += d0; L1 += d1;
            if (j < 15) {
                L[g][n0 * 10 + o] = L0;
                L[g][n1 * 10 + o] = L1;
            }
            __syncthreads();
        } else {
            float q = s * s;
            q += __shfl_xor(q, 1, 16);
            q += __shfl_xor(q, 2, 16);
            q += __shfl_xor(q, 4, 16);
            q += __shfl_xor(q, 8, 16);
            v = s * sqrtf(q) / (1.f + q);
        }
    }
    if ((b0 + g) < Btot) out[(size_t)(b0 + g) * 160 + r] = v;
}

// ---------------- K3y2 (fallback, validated @202us) ----------------
__global__ __launch_bounds__(640, 2) void k3y2(const float* __restrict__ u,
                                               const bfu* __restrict__ rwb,
                                               float* __restrict__ out, int Btot) {
    __shared__ float US[4][600];
    __shared__ float L[4][300];
    __shared__ float P[4][300];
    const int tid = threadIdx.x;
    const int g = tid / 160, r = tid - g * 160;
    const int o = r >> 4, k = r & 15;
    const int b0 = blockIdx.x * 4;

    {
        const int nf4 = 150;
        for (int i = tid; i < 4 * nf4; i += 640) {
            int gg = i / nf4, j = i - gg * nf4;
            int bb = b0 + gg; if (bb >= Btot) bb = Btot - 1;
            *(float4*)&US[gg][j * 4] = *(const float4*)(u + (size_t)bb * 600 + j * 4);
        }
        for (int i = tid; i < 1200; i += 640) L[i / 300][i % 300] = 0.f;
    }
    __syncthreads();

    float pri[30];
    const bfu* rp = rwb + o * 9600 + k * 20;
    #pragma unroll 2
    for (int n = 0; n < 30; n++) {
        const uint2* rq = (const uint2*)(rp + n * 320);
        float a = 0.f;
        #pragma unroll
        for (int jj = 0; jj < 5; jj++) {
            uint2 w = rq[jj];
            float4 uu = *(const float4*)&US[g][n * 20 + jj * 4];
            a += lo2f(w.x) * uu.x + hi2f(w.x) * uu.y + lo2f(w.y) * uu.z + hi2f(w.y) * uu.w;
        }
        pri[n] = a;
    }

    float v = 0.f;
    for (int it = 0; it < 3; it++) {
        if (r < 30) {
            const int n = r;
            float mx = L[g][n * 10];
            #pragma unroll
            for (int oo = 1; oo < 10; oo++) mx = fmaxf(mx, L[g][n * 10 + oo]);
            float e[10], den = 0.f;
            #pragma unroll
            for (int oo = 0; oo < 10; oo++) { e[oo] = __expf(L[g][n * 10 + oo] - mx); den += e[oo]; }
            float inv = 1.f / den;
            #pragma unroll
            for (int oo = 0; oo < 10; oo++) P[g][n * 10 + oo] = e[oo] * inv;
        }
        __syncthreads();
        float s = 0.f;
        #pragma unroll
        for (int n = 0; n < 30; n++) s += P[g][n * 10 + o] * pri[n];
        float q = s * s;
        q += __shfl_xor(q, 1, 16);
        q += __shfl_xor(q, 2, 16);
        q += __shfl_xor(q, 4, 16);
        q += __shfl_xor(q, 8, 16);
        v = s * sqrtf(q) / (1.f + q);
        if (it < 2) {
            #pragma unroll 5
            for (int n = 0; n < 30; n++) {
                float t = pri[n] * v;
                t += __shfl_xor(t, 1, 16);
                t += __shfl_xor(t, 2, 16);
                t += __shfl_xor(t, 4, 16);
                t += __shfl_xor(t, 8, 16);
                if (k == 0) L[g][n * 10 + o] += t;
            }
            __syncthreads();
        }
    }
    if ((b0 + g) < Btot) out[(size_t)(b0 + g) * 160 + r] = v;
}

extern "C" void kernel_launch(void* const* d_in, const int* in_sizes, int n_in,
                              void* d_out, int out_size, void* d_ws, size_t ws_size,
                              hipStream_t stream) {
    // ---- size-based input matching (validated) ----
    int ix = -1, iw1 = -1, ib1 = -1, iw2 = -1, ib2 = -1, irw = -1;
    for (int i = 0; i < n_in; i++) {
        int s = in_sizes[i];
        if (s == 470400 && iw1 < 0) iw1 = i;
        else if (s == 12000 && iw2 < 0) iw2 = i;
        else if (s == 96000 && irw < 0) irw = i;
        else if (s == 600) { if (ib1 < 0) ib1 = i; else if (ib2 < 0) ib2 = i; }
    }
    long bestsz = -1;
    for (int i = 0; i < n_in; i++) {
        if (i == iw1 || i == iw2 || i == irw || i == ib1 || i == ib2) continue;
        if ((long)in_sizes[i] > bestsz) { bestsz = in_sizes[i]; ix = i; }
    }
    if (ix < 0 || iw1 < 0 || ib1 < 0 || iw2 < 0 || ib2 < 0 || irw < 0) {
        ix = 0; iw1 = 1; ib1 = 2; iw2 = 3; ib2 = 4; irw = 5;
    }
    const void* x  = d_in[ix];
    const void* W1 = d_in[iw1];
    const void* b1 = d_in[ib1];
    const void* W2 = d_in[iw2];
    const void* b2 = d_in[ib2];
    const void* rw = d_in[irw];
    const int B = in_sizes[ix] / 784;
    float* out = (float*)d_out;

    // ---- ws layout (byte offsets, all 16B-aligned) ----
    char* base = (char*)d_ws;
    size_t off = 0;
    float* h1u  = (float*)(base + off); off += (size_t)B * 2400;       // B*600 f32
    float* b1f  = (float*)(base + off); off += 2560;                   // 640 f32
    u32*  flags = (u32*)(base + off);   off += 32;                     // 8 u32
    bfu*   Wt   = (bfu*)(base + off);   off += 1024000;                // 640*800 bf16
    bfu*   xb   = (bfu*)(base + off);   off += (size_t)B * 1600;       // B*800 bf16
    bfu*   rwb  = (bfu*)(base + off);   off += 192000;                 // 96000 bf16
    size_t fb_bytes = off;
    bfu*   rwn  = (bfu*)(base + off);   off += 307200;                 // 30*160*32 bf16
    float* W2t  = (float*)(base + off); off += 48000;                  // 30*20*20 f32
    float* b2f  = (float*)(base + off); off += 2560;                   // 640 f32
    bfu*   pri  = (bfu*)(base + off);   off += (size_t)B * 9600;       // B*4800 bf16
    size_t main_bytes = off;

    const int mode = (ws_size >= main_bytes) ? 0 : 1;   // fixed per-call -> graph-safe
    const int prep_total = B * 800 + 640 * 800 + 96000 + 640
                         + (mode == 0 ? (153600 + 12000 + 640) : 0);

    detect_dtype<<<1, 64, 0, stream>>>((const u32*)x, (const u32*)W1, (const u32*)b1,
                                       (const u32*)W2, (const u32*)b2, (const u32*)rw, flags);
    prep_all<<<(prep_total + 255) / 256, 256, 0, stream>>>(x, W1, b1, W2, b2, rw,
                                                           xb, Wt, b1f, rwb, rwn,
                                                           W2t, b2f, flags, B, mode);
    k1m<<<dim3((B + 127) / 128, 10), 256, 0, stream>>>(xb, Wt, b1f, h1u, B, mode == 0 ? 1 : 0);
    if (mode == 0) {
        k2q<<<dim3((B + 127) / 128, 30), 256, 0, stream>>>(h1u, W2t, b2f, rwn, pri, B);
        k3t<<<(B + 3) / 4, 640, 0, stream>>>(pri, out, B);
    } else {
        (void)fb_bytes;
        k2s<<<(B * 30 + 255) / 256, 256, 0, stream>>>(h1u, W2, b2, h1u, flags, B * 30);
        k3y2<<<(B + 3) / 4, 640, 0, stream>>>(h1u, rwb, out, B);
    }
}

// Round 5
// 179.866 us; speedup vs baseline: 1.5244x; 1.0502x over previous
//
#include <hip/hip_runtime.h>

// B(derived), IN_DIM=784, NUM_NETS=30, N_NODES=20, NUM_OUT=10, DIM_OUT=16, NUM_ITER=3
// Validated: size-based binding; dtype detect; k2q fused u+priors MFMA; k3t routing math.
// R19: (a) k1m BK 32->64 (12x64 + 32-tail): barriers 50->26, 6 loads in flight, 12
// ds_read_b128 + 16 MFMA per step (same MFMA mapping/epilogue). LDS [128][72]+[64][72]
// = 27.6KB, 72-short stride -> 2-way bank alias (free). (b) k3t -> k3t2: 2 rows/block
// (320 thr), per-lane code IDENTICAL to validated k3t; 6 blocks/CU = 30 waves (was 20)
// on a latency-bound kernel + barriers sync 5 waves not 10. (R17 lesson: keep 160
// thr/row, add waves.) Fallback k2s+k3y2 unchanged.

typedef unsigned short bfu;
typedef unsigned int u32;
typedef __attribute__((ext_vector_type(8))) short short8;
typedef __attribute__((ext_vector_type(4))) float floatx4;

__device__ __forceinline__ float bf2f(bfu u) { union { u32 i; float f; } v; v.i = ((u32)u) << 16; return v.f; }
__device__ __forceinline__ float lo2f(u32 w) { union { u32 i; float f; } v; v.i = w << 16; return v.f; }
__device__ __forceinline__ float hi2f(u32 w) { union { u32 i; float f; } v; v.i = w & 0xffff0000u; return v.f; }
__device__ __forceinline__ float ldf(const void* p, int idx, bool b16) {
    return b16 ? bf2f(((const bfu*)p)[idx]) : ((const float*)p)[idx];
}
__device__ __forceinline__ bfu f2bf(float f) {   // RNE
    u32 u = __float_as_uint(f);
    return (bfu)((u + 0x7FFFu + ((u >> 16) & 1u)) >> 16);
}
__device__ __forceinline__ void unpack8(uint4 q, float* dst) {
    dst[0] = lo2f(q.x); dst[1] = hi2f(q.x);
    dst[2] = lo2f(q.y); dst[3] = hi2f(q.y);
    dst[4] = lo2f(q.z); dst[5] = hi2f(q.z);
    dst[6] = lo2f(q.w); dst[7] = hi2f(q.w);
}

// ---- dtype detector (validated) ----
__global__ void detect_dtype(const u32* x, const u32* W1, const u32* b1,
                             const u32* W2, const u32* b2, const u32* rw,
                             u32* flags) {
    int t = threadIdx.x;
    if (t >= 6) return;
    const u32* p = (t == 0) ? x : (t == 1) ? W1 : (t == 2) ? b1
                 : (t == 3) ? W2 : (t == 4) ? b2 : rw;
    int c = 0;
    for (int i = 0; i < 64; i++) {
        u32 e = (p[i] >> 7) & 0xFF;
        c += (e >= 64 && e <= 140) ? 1 : 0;
    }
    flags[t] = (c >= 48) ? 1u : 0u;
}

// ---- prep_all: xb | Wt | rwb | b1f (+ rwn | W2t | b2f if mode==0) ----
__global__ void prep_all(const void* x, const void* W1, const void* b1,
                         const void* W2, const void* b2, const void* rw,
                         bfu* __restrict__ xb, bfu* __restrict__ Wt,
                         float* __restrict__ b1f, bfu* __restrict__ rwb,
                         bfu* __restrict__ rwn, float* __restrict__ W2t,
                         float* __restrict__ b2f,
                         const u32* flags, int B, int mode) {
    const int idx = blockIdx.x * 256 + threadIdx.x;
    const int nxb = B * 800;
    if (idx < nxb) {                                   // xb[B][800] bf16
        const bool b16 = flags[0] != 0;
        int b = idx / 800, kk = idx - b * 800;
        bfu v = 0;
        if (kk < 784) {
            int src = b * 784 + kk;
            v = b16 ? ((const bfu*)x)[src] : f2bf(((const float*)x)[src]);
        }
        xb[idx] = v;
        return;
    }
    int i2 = idx - nxb;
    if (i2 < 640 * 800) {                              // Wt[c][k] bf16
        const bool wb = flags[1] != 0;
        int c = i2 / 800, k = i2 - c * 800;
        bfu v = 0;
        if (c < 600 && k < 784) {
            int nn = c / 20, o = c - nn * 20;
            int src = nn * 15680 + k * 20 + o;
            v = wb ? ((const bfu*)W1)[src] : f2bf(((const float*)W1)[src]);
        }
        Wt[i2] = v;
        return;
    }
    i2 -= 640 * 800;
    if (i2 < 96000) {                                  // rwb[o][n][k][d] bf16 (fallback k3y2)
        const bool rb = flags[5] != 0;
        int d = i2 % 20;
        int k = (i2 / 20) % 16;
        int n = (i2 / 320) % 30;
        int o = i2 / 9600;
        int src = o * 9600 + n * 320 + d * 16 + k;
        rwb[i2] = rb ? ((const bfu*)rw)[src] : f2bf(((const float*)rw)[src]);
        return;
    }
    i2 -= 96000;
    if (i2 < 640) {                                    // b1f fp32
        b1f[i2] = (i2 < 600) ? ldf(b1, i2, flags[2] != 0) : 0.f;
        return;
    }
    i2 -= 640;
    if (mode != 0) return;
    if (i2 < 153600) {                                 // rwn[n][col=o*16+k][dd<32] bf16, K-pad
        const bool rb = flags[5] != 0;
        int dd = i2 % 32;
        int col = (i2 / 32) % 160;
        int n = i2 / 5120;
        bfu v = 0;
        if (dd < 20) {
            int o = col / 16, kk = col % 16;
            int src = o * 9600 + n * 320 + dd * 16 + kk;
            v = rb ? ((const bfu*)rw)[src] : f2bf(((const float*)rw)[src]);
        }
        rwn[i2] = v;
        return;
    }
    i2 -= 153600;
    if (i2 < 12000) {                                  // W2t[n][e][d] fp32 = W2[n][d][e]
        int d = i2 % 20;
        int e = (i2 / 20) % 20;
        int n = i2 / 400;
        W2t[i2] = ldf(W2, n * 400 + d * 20 + e, flags[3] != 0);
        return;
    }
    i2 -= 12000;
    if (i2 < 640) {                                    // b2f fp32
        b2f[i2] = (i2 < 600) ? ldf(b2, i2, flags[4] != 0) : 0.f;
    }
}

// ---------------- K1m: h1 = relu(xb @ Wt^T + b1), bf16 MFMA (R19: BK=64) ----------------
// tr==1 (mode 0): store h1 as [n][b][20] (coalesced reads for k2q). tr==0: [b][600].
__global__ __launch_bounds__(256, 4) void k1m(const bfu* __restrict__ xb, const bfu* __restrict__ Wt,
                                              const float* __restrict__ b1f,
                                              float* __restrict__ h1, int Btot, int tr) {
    __shared__ short As[128 * 72];     // [row][64+8pad]
    __shared__ short Bs[64 * 72];
    const int tid = threadIdx.x;
    const int w = tid >> 6, lane = tid & 63;
    const int quad = lane >> 4, fl = lane & 15;
    const int m0 = blockIdx.x * 128, n0 = blockIdx.y * 64;

    floatx4 acc[2][4];
    #pragma unroll
    for (int mi = 0; mi < 2; mi++)
        #pragma unroll
        for (int ni = 0; ni < 4; ni++) acc[mi][ni] = (floatx4){0.f, 0.f, 0.f, 0.f};

    const int arow = tid >> 1, aseg = tid & 1;    // 2 thr/row, 64B each
    const int brow = tid >> 2, bseg = tid & 3;    // 4 thr/row, 32B each
    int agrow = m0 + arow; if (agrow >= Btot) agrow = Btot - 1;
    const bfu* abase = xb + (size_t)agrow * 800 + aseg * 32;
    const bfu* bbase = Wt + (size_t)(n0 + brow) * 800 + bseg * 16;

    // 12 steps of BK=64
    for (int k0 = 0; k0 < 768; k0 += 64) {
        uint4 qa0 = *(const uint4*)(abase + k0);
        uint4 qa1 = *(const uint4*)(abase + k0 + 8);
        uint4 qa2 = *(const uint4*)(abase + k0 + 16);
        uint4 qa3 = *(const uint4*)(abase + k0 + 24);
        uint4 qb0 = *(const uint4*)(bbase + k0);
        uint4 qb1 = *(const uint4*)(bbase + k0 + 8);

        __syncthreads();
        *(uint4*)&As[arow * 72 + aseg * 32 + 0]  = qa0;
        *(uint4*)&As[arow * 72 + aseg * 32 + 8]  = qa1;
        *(uint4*)&As[arow * 72 + aseg * 32 + 16] = qa2;
        *(uint4*)&As[arow * 72 + aseg * 32 + 24] = qa3;
        *(uint4*)&Bs[brow * 72 + bseg * 16 + 0]  = qb0;
        *(uint4*)&Bs[brow * 72 + bseg * 16 + 8]  = qb1;
        __syncthreads();

        short8 af[2][2], bfr[4][2];
        #pragma unroll
        for (int mi = 0; mi < 2; mi++)
            #pragma unroll
            for (int kk = 0; kk < 2; kk++)
                af[mi][kk] = *(const short8*)&As[(w * 32 + mi * 16 + fl) * 72 + kk * 32 + quad * 8];
        #pragma unroll
        for (int ni = 0; ni < 4; ni++)
            #pragma unroll
            for (int kk = 0; kk < 2; kk++)
                bfr[ni][kk] = *(const short8*)&Bs[(ni * 16 + fl) * 72 + kk * 32 + quad * 8];
        #pragma unroll
        for (int kk = 0; kk < 2; kk++)
            #pragma unroll
            for (int mi = 0; mi < 2; mi++)
                #pragma unroll
                for (int ni = 0; ni < 4; ni++)
                    acc[mi][ni] = __builtin_amdgcn_mfma_f32_16x16x32_bf16(af[mi][kk], bfr[ni][kk], acc[mi][ni], 0, 0, 0);
    }

    // tail step: k0=768, 32 wide
    {
        const bfu* at = xb + (size_t)agrow * 800 + 768 + aseg * 16;
        const bfu* bt = Wt + (size_t)(n0 + brow) * 800 + 768 + bseg * 8;
        uint4 qa0 = *(const uint4*)(at);
        uint4 qa1 = *(const uint4*)(at + 8);
        uint4 qb0 = *(const uint4*)(bt);

        __syncthreads();
        *(uint4*)&As[arow * 72 + aseg * 16 + 0] = qa0;
        *(uint4*)&As[arow * 72 + aseg * 16 + 8] = qa1;
        *(uint4*)&Bs[brow * 72 + bseg * 8] = qb0;
        __syncthreads();

        short8 af[2], bfr[4];
        #pragma unroll
        for (int mi = 0; mi < 2; mi++)
            af[mi] = *(const short8*)&As[(w * 32 + mi * 16 + fl) * 72 + quad * 8];
        #pragma unroll
        for (int ni = 0; ni < 4; ni++)
            bfr[ni] = *(const short8*)&Bs[(ni * 16 + fl) * 72 + quad * 8];
        #pragma unroll
        for (int mi = 0; mi < 2; mi++)
            #pragma unroll
            for (int ni = 0; ni < 4; ni++)
                acc[mi][ni] = __builtin_amdgcn_mfma_f32_16x16x32_bf16(af[mi], bfr[ni], acc[mi][ni], 0, 0, 0);
    }

    #pragma unroll
    for (int mi = 0; mi < 2; mi++) {
        #pragma unroll
        for (int ni = 0; ni < 4; ni++) {
            const int c = n0 + ni * 16 + fl;
            const int cn = c / 20, ce = c - cn * 20;
            #pragma unroll
            for (int r = 0; r < 4; r++) {
                const int m = m0 + w * 32 + mi * 16 + quad * 4 + r;
                if (c < 600 && m < Btot) {
                    size_t di = tr ? (((size_t)cn * Btot + m) * 20 + ce)
                                   : ((size_t)m * 600 + c);
                    h1[di] = fmaxf(acc[mi][ni][r] + b1f[c], 0.f);
                }
            }
        }
    }
}

// ---------------- K2q (main, validated R18): fused u-compute + priors MFMA ----------------
__global__ __launch_bounds__(256) void k2q(const float* __restrict__ h1n,
                                           const float* __restrict__ W2t,
                                           const float* __restrict__ b2f,
                                           const bfu* __restrict__ rwn,
                                           bfu* __restrict__ pri, int Btot) {
    __shared__ short us[128 * 40];
    const int tid = threadIdx.x;
    const int n = blockIdx.y;
    const int b0 = blockIdx.x * 128;

    const int w = tid >> 6, lane = tid & 63;
    const int quad = lane >> 4, fl = lane & 15;
    short8 bfr[10];
    #pragma unroll
    for (int nj = 0; nj < 10; nj++)
        bfr[nj] = *(const short8*)(rwn + ((size_t)n * 160 + nj * 16 + fl) * 32 + quad * 8);

    {
        const int row = tid >> 1, half = tid & 1;
        int br = b0 + row; if (br >= Btot) br = Btot - 1;
        float h[20];
        const float* hp = h1n + ((size_t)n * Btot + br) * 20;
        #pragma unroll
        for (int d4 = 0; d4 < 20; d4 += 4) {
            float4 v = *(const float4*)(hp + d4);
            h[d4] = v.x; h[d4 + 1] = v.y; h[d4 + 2] = v.z; h[d4 + 3] = v.w;
        }
        const float* wn = W2t + n * 400;
        const float* bn = b2f + n * 20;
        float o[10], sq = 0.f;
        #pragma unroll
        for (int i = 0; i < 10; i++) {
            const int e = 2 * i + half;
            float acc = bn[e];
            #pragma unroll
            for (int d = 0; d < 20; d++) acc += h[d] * wn[e * 20 + d];
            acc = fmaxf(acc, 0.f);
            o[i] = acc;
            sq += acc * acc;
        }
        sq += __shfl_xor(sq, 1);
        float sc = (sq > 0.f) ? sqrtf(sq) / (1.f + sq) : 0.f;
        #pragma unroll
        for (int i = 0; i < 10; i++)
            us[row * 40 + 2 * i + half] = (short)f2bf(o[i] * sc);
        #pragma unroll
        for (int i = 10; i < 16; i++)
            us[row * 40 + 2 * i + half] = 0;
    }
    __syncthreads();

    #pragma unroll
    for (int mi = 0; mi < 2; mi++) {
        short8 af = *(const short8*)&us[(w * 32 + mi * 16 + fl) * 40 + quad * 8];
        #pragma unroll
        for (int nj = 0; nj < 10; nj++) {
            floatx4 acc = (floatx4){0.f, 0.f, 0.f, 0.f};
            acc = __builtin_amdgcn_mfma_f32_16x16x32_bf16(af, bfr[nj], acc, 0, 0, 0);
            #pragma unroll
            for (int r = 0; r < 4; r++) {
                int mr = b0 + w * 32 + mi * 16 + quad * 4 + r;
                if (mr < Btot)
                    pri[(size_t)mr * 4800 + nj * 480 + n * 16 + fl] = f2bf(acc[r]);
            }
        }
    }
}

// ---------------- K2 core (fallback path, validated math) ----------------
__device__ __forceinline__ void k2_core(const float* hp, const float* wn, const float* bn,
                                        float* o, float& sc) {
    float h[20];
    #pragma unroll
    for (int d4 = 0; d4 < 20; d4 += 4) {
        float4 v = *(const float4*)(hp + d4);
        h[d4] = v.x; h[d4 + 1] = v.y; h[d4 + 2] = v.z; h[d4 + 3] = v.w;
    }
    float sq = 0.f;
    #pragma unroll
    for (int e = 0; e < 20; e++) {
        float acc = bn[e];
        #pragma unroll
        for (int d = 0; d < 20; d++) acc += h[d] * wn[d * 20 + e];
        acc = fmaxf(acc, 0.f);
        o[e] = acc;
        sq += acc * acc;
    }
    sc = (sq > 0.f) ? sqrtf(sq) / (1.f + sq) : 0.f;
}

// K2s (fallback, validated): u fp32 in place
__global__ __launch_bounds__(256) void k2s(const float* h1, const void* W2, const void* b2,
                                           float* u, const u32* flags, int total) {
    __shared__ float W2s[12000];
    __shared__ float b2s[600];
    const bool wb = flags[3] != 0, bb = flags[4] != 0;
    const int tid = threadIdx.x;
    for (int i = tid; i < 12000; i += 256) W2s[i] = ldf(W2, i, wb);
    for (int i = tid; i < 600; i += 256) b2s[i] = ldf(b2, i, bb);
    __syncthreads();

    int t = blockIdx.x * 256 + tid;
    if (t >= total) return;
    const int b = t / 30, n = t - b * 30;
    float o[20], sc;
    k2_core(h1 + (size_t)b * 600 + n * 20, &W2s[n * 400], &b2s[n * 20], o, sc);
    float* up = u + (size_t)b * 600 + n * 20;
    #pragma unroll
    for (int e4 = 0; e4 < 20; e4 += 4) {
        float4 v;
        v.x = o[e4] * sc; v.y = o[e4 + 1] * sc; v.z = o[e4 + 2] * sc; v.w = o[e4 + 3] * sc;
        *(float4*)(up + e4) = v;
    }
}

// ---------------- K3t2: routing, 2 rows/block (R19; per-lane code == validated k3t) ----------------
__global__ __launch_bounds__(320, 4) void k3t2(const bfu* __restrict__ pri_buf,
                                               float* __restrict__ out, int Btot) {
    __shared__ float L[2][300];
    __shared__ float P[2][300];
    const int tid = threadIdx.x;
    const int g = tid / 160, r = tid - g * 160;
    const int o = r >> 4, j = r & 15;
    const int b0 = blockIdx.x * 2;
    int bb = b0 + g; if (bb >= Btot) bb = Btot - 1;

    const int n0 = 2 * j, n1 = n0 + 1;
    float p0[16], p1[16];
    if (j < 15) {
        const bfu* pb = pri_buf + (size_t)bb * 4800 + (size_t)o * 480 + j * 32;
        uint4 q0 = *(const uint4*)(pb);        // n0 k0..7
        uint4 q1 = *(const uint4*)(pb + 8);    // n0 k8..15
        uint4 q2 = *(const uint4*)(pb + 16);   // n1 k0..7
        uint4 q3 = *(const uint4*)(pb + 24);   // n1 k8..15
        unpack8(q0, p0); unpack8(q1, p0 + 8);
        unpack8(q2, p1); unpack8(q3, p1 + 8);
    } else {
        #pragma unroll
        for (int i = 0; i < 16; i++) { p0[i] = 0.f; p1[i] = 0.f; }
    }

    float L0 = 0.f, L1 = 0.f;
    float v = 0.f;
    #pragma unroll
    for (int it = 0; it < 3; it++) {
        float P0, P1;
        if (it == 0) {
            P0 = 0.1f; P1 = 0.1f;              // softmax(zeros) over 10 outputs
        } else {
            if (r < 30) {                       // dedicated softmax over o for net r
                float l[10];
                #pragma unroll
                for (int oo = 0; oo < 10; oo++) l[oo] = L[g][r * 10 + oo];
                float mx = l[0];
                #pragma unroll
                for (int oo = 1; oo < 10; oo++) mx = fmaxf(mx, l[oo]);
                float den = 0.f;
                #pragma unroll
                for (int oo = 0; oo < 10; oo++) { l[oo] = __expf(l[oo] - mx); den += l[oo]; }
                float inv = 1.f / den;
                #pragma unroll
                for (int oo = 0; oo < 10; oo++) P[g][r * 10 + oo] = l[oo] * inv;
            }
            __syncthreads();
            P0 = (j < 15) ? P[g][n0 * 10 + o] : 0.f;
            P1 = (j < 15) ? P[g][n1 * 10 + o] : 0.f;
        }

        float t[16];
        #pragma unroll
        for (int i = 0; i < 16; i++) t[i] = P0 * p0[i] + P1 * p1[i];

        // 16-lane transpose-reduce: lane j ends with s[k=j] (15 shuffles)
        #pragma unroll
        for (int i = 0; i < 8; i++) {
            float send = (j & 8) ? t[i] : t[i + 8];
            float recv = __shfl_xor(send, 8, 16);
            t[i] = ((j & 8) ? t[i + 8] : t[i]) + recv;
        }
        #pragma unroll
        for (int i = 0; i < 4; i++) {
            float send = (j & 4) ? t[i] : t[i + 4];
            float recv = __shfl_xor(send, 4, 16);
            t[i] = ((j & 4) ? t[i + 4] : t[i]) + recv;
        }
        #pragma unroll
        for (int i = 0; i < 2; i++) {
            float send = (j & 2) ? t[i] : t[i + 2];
            float recv = __shfl_xor(send, 2, 16);
            t[i] = ((j & 2) ? t[i + 2] : t[i]) + recv;
        }
        {
            float send = (j & 1) ? t[0] : t[1];
            float recv = __shfl_xor(send, 1, 16);
            t[0] = ((j & 1) ? t[1] : t[0]) + recv;
        }
        float s = t[0];                         // s[o, k=j]

        if (it < 2) {
            float sf[16];
            #pragma unroll
            for (int k = 0; k < 16; k++) sf[k] = __shfl(s, k, 16);
            float q = 0.f;
            #pragma unroll
            for (int k = 0; k < 16; k++) q += sf[k] * sf[k];
            float scale = sqrtf(q) / (1.f + q);
            v = s * scale;
            float d0 = 0.f, d1 = 0.f;
            #pragma unroll
            for (int k = 0; k < 16; k++) {
                float vk = sf[k] * scale;
                d0 += p0[k] * vk;
                d1 += p1[k] * vk;
            }
            L0 += d0; L1 += d1;
            if (j < 15) {
                L[g][n0 * 10 + o] = L0;
                L[g][n1 * 10 + o] = L1;
            }
            __syncthreads();
        } else {
            float q = s * s;
            q += __shfl_xor(q, 1, 16);
            q += __shfl_xor(q, 2, 16);
            q += __shfl_xor(q, 4, 16);
            q += __shfl_xor(q, 8, 16);
            v = s * sqrtf(q) / (1.f + q);
        }
    }
    if ((b0 + g) < Btot) out[(size_t)(b0 + g) * 160 + r] = v;
}

// ---------------- K3y2 (fallback, validated @202us) ----------------
__global__ __launch_bounds__(640, 2) void k3y2(const float* __restrict__ u,
                                               const bfu* __restrict__ rwb,
                                               float* __restrict__ out, int Btot) {
    __shared__ float US[4][600];
    __shared__ float L[4][300];
    __shared__ float P[4][300];
    const int tid = threadIdx.x;
    const int g = tid / 160, r = tid - g * 160;
    const int o = r >> 4, k = r & 15;
    const int b0 = blockIdx.x * 4;

    {
        const int nf4 = 150;
        for (int i = tid; i < 4 * nf4; i += 640) {
            int gg = i / nf4, j = i - gg * nf4;
            int bb = b0 + gg; if (bb >= Btot) bb = Btot - 1;
            *(float4*)&US[gg][j * 4] = *(const float4*)(u + (size_t)bb * 600 + j * 4);
        }
        for (int i = tid; i < 1200; i += 640) L[i / 300][i % 300] = 0.f;
    }
    __syncthreads();

    float pri[30];
    const bfu* rp = rwb + o * 9600 + k * 20;
    #pragma unroll 2
    for (int n = 0; n < 30; n++) {
        const uint2* rq = (const uint2*)(rp + n * 320);
        float a = 0.f;
        #pragma unroll
        for (int jj = 0; jj < 5; jj++) {
            uint2 w = rq[jj];
            float4 uu = *(const float4*)&US[g][n * 20 + jj * 4];
            a += lo2f(w.x) * uu.x + hi2f(w.x) * uu.y + lo2f(w.y) * uu.z + hi2f(w.y) * uu.w;
        }
        pri[n] = a;
    }

    float v = 0.f;
    for (int it = 0; it < 3; it++) {
        if (r < 30) {
            const int n = r;
            float mx = L[g][n * 10];
            #pragma unroll
            for (int oo = 1; oo < 10; oo++) mx = fmaxf(mx, L[g][n * 10 + oo]);
            float e[10], den = 0.f;
            #pragma unroll
            for (int oo = 0; oo < 10; oo++) { e[oo] = __expf(L[g][n * 10 + oo] - mx); den += e[oo]; }
            float inv = 1.f / den;
            #pragma unroll
            for (int oo = 0; oo < 10; oo++) P[g][n * 10 + oo] = e[oo] * inv;
        }
        __syncthreads();
        float s = 0.f;
        #pragma unroll
        for (int n = 0; n < 30; n++) s += P[g][n * 10 + o] * pri[n];
        float q = s * s;
        q += __shfl_xor(q, 1, 16);
        q += __shfl_xor(q, 2, 16);
        q += __shfl_xor(q, 4, 16);
        q += __shfl_xor(q, 8, 16);
        v = s * sqrtf(q) / (1.f + q);
        if (it < 2) {
            #pragma unroll 5
            for (int n = 0; n < 30; n++) {
                float t = pri[n] * v;
                t += __shfl_xor(t, 1, 16);
                t += __shfl_xor(t, 2, 16);
                t += __shfl_xor(t, 4, 16);
                t += __shfl_xor(t, 8, 16);
                if (k == 0) L[g][n * 10 + o] += t;
            }
            __syncthreads();
        }
    }
    if ((b0 + g) < Btot) out[(size_t)(b0 + g) * 160 + r] = v;
}

extern "C" void kernel_launch(void* const* d_in, const int* in_sizes, int n_in,
                              void* d_out, int out_size, void* d_ws, size_t ws_size,
                              hipStream_t stream) {
    // ---- size-based input matching (validated) ----
    int ix = -1, iw1 = -1, ib1 = -1, iw2 = -1, ib2 = -1, irw = -1;
    for (int i = 0; i < n_in; i++) {
        int s = in_sizes[i];
        if (s == 470400 && iw1 < 0) iw1 = i;
        else if (s == 12000 && iw2 < 0) iw2 = i;
        else if (s == 96000 && irw < 0) irw = i;
        else if (s == 600) { if (ib1 < 0) ib1 = i; else if (ib2 < 0) ib2 = i; }
    }
    long bestsz = -1;
    for (int i = 0; i < n_in; i++) {
        if (i == iw1 || i == iw2 || i == irw || i == ib1 || i == ib2) continue;
        if ((long)in_sizes[i] > bestsz) { bestsz = in_sizes[i]; ix = i; }
    }
    if (ix < 0 || iw1 < 0 || ib1 < 0 || iw2 < 0 || ib2 < 0 || irw < 0) {
        ix = 0; iw1 = 1; ib1 = 2; iw2 = 3; ib2 = 4; irw = 5;
    }
    const void* x  = d_in[ix];
    const void* W1 = d_in[iw1];
    const void* b1 = d_in[ib1];
    const void* W2 = d_in[iw2];
    const void* b2 = d_in[ib2];
    const void* rw = d_in[irw];
    const int B = in_sizes[ix] / 784;
    float* out = (float*)d_out;

    // ---- ws layout (byte offsets, all 16B-aligned) ----
    char* base = (char*)d_ws;
    size_t off = 0;
    float* h1u  = (float*)(base + off); off += (size_t)B * 2400;       // B*600 f32
    float* b1f  = (float*)(base + off); off += 2560;                   // 640 f32
    u32*  flags = (u32*)(base + off);   off += 32;                     // 8 u32
    bfu*   Wt   = (bfu*)(base + off);   off += 1024000;                // 640*800 bf16
    bfu*   xb   = (bfu*)(base + off);   off += (size_t)B * 1600;       // B*800 bf16
    bfu*   rwb  = (bfu*)(base + off);   off += 192000;                 // 96000 bf16
    size_t fb_bytes = off;
    bfu*   rwn  = (bfu*)(base + off);   off += 307200;                 // 30*160*32 bf16
    float* W2t  = (float*)(base + off); off += 48000;                  // 30*20*20 f32
    float* b2f  = (float*)(base + off); off += 2560;                   // 640 f32
    bfu*   pri  = (bfu*)(base + off);   off += (size_t)B * 9600;       // B*4800 bf16
    size_t main_bytes = off;

    const int mode = (ws_size >= main_bytes) ? 0 : 1;   // fixed per-call -> graph-safe
    const int prep_total = B * 800 + 640 * 800 + 96000 + 640
                         + (mode == 0 ? (153600 + 12000 + 640) : 0);

    detect_dtype<<<1, 64, 0, stream>>>((const u32*)x, (const u32*)W1, (const u32*)b1,
                                       (const u32*)W2, (const u32*)b2, (const u32*)rw, flags);
    prep_all<<<(prep_total + 255) / 256, 256, 0, stream>>>(x, W1, b1, W2, b2, rw,
                                                           xb, Wt, b1f, rwb, rwn,
                                                           W2t, b2f, flags, B, mode);
    k1m<<<dim3((B + 127) / 128, 10), 256, 0, stream>>>(xb, Wt, b1f, h1u, B, mode == 0 ? 1 : 0);
    if (mode == 0) {
        k2q<<<dim3((B + 127) / 128, 30), 256, 0, stream>>>(h1u, W2t, b2f, rwn, pri, B);
        k3t2<<<(B + 1) / 2, 320, 0, stream>>>(pri, out, B);
    } else {
        (void)fb_bytes;
        k2s<<<(B * 30 + 255) / 256, 256, 0, stream>>>(h1u, W2, b2, h1u, flags, B * 30);
        k3y2<<<(B + 3) / 4, 640, 0, stream>>>(h1u, rwb, out, B);
    }
}

// Round 6
// 173.506 us; speedup vs baseline: 1.5803x; 1.0367x over previous
//
#include <hip/hip_runtime.h>

// B(derived), IN_DIM=784, NUM_NETS=30, N_NODES=20, NUM_OUT=10, DIM_OUT=16, NUM_ITER=3
// Validated: size-based binding; dtype detect; k1m MFMA BK=64; k2q fused u+priors MFMA;
// k3 routing math (k3t2 @R19). R20: (a) k3v: replace the 16-shfl allgather with LDS
// broadcast -- S[g][o*20+j] write + 4x float4 same-address reads. o-groups are 16-aligned
// within one wave -> same-wave DS ordering, NO extra barrier; stride-20 rows put the 4
// o-rows/wave on disjoint bank quads. Per-lane DS ops 87 -> 65. (b) prep_all xb/Wt
// sections 4-wide (float4 read + ushort4 write), threads 7.15M -> 2.03M.
// Fallback k2s+k3y2 unchanged.

typedef unsigned short bfu;
typedef unsigned int u32;
typedef __attribute__((ext_vector_type(8))) short short8;
typedef __attribute__((ext_vector_type(4))) float floatx4;

__device__ __forceinline__ float bf2f(bfu u) { union { u32 i; float f; } v; v.i = ((u32)u) << 16; return v.f; }
__device__ __forceinline__ float lo2f(u32 w) { union { u32 i; float f; } v; v.i = w << 16; return v.f; }
__device__ __forceinline__ float hi2f(u32 w) { union { u32 i; float f; } v; v.i = w & 0xffff0000u; return v.f; }
__device__ __forceinline__ float ldf(const void* p, int idx, bool b16) {
    return b16 ? bf2f(((const bfu*)p)[idx]) : ((const float*)p)[idx];
}
__device__ __forceinline__ bfu f2bf(float f) {   // RNE
    u32 u = __float_as_uint(f);
    return (bfu)((u + 0x7FFFu + ((u >> 16) & 1u)) >> 16);
}
__device__ __forceinline__ void unpack8(uint4 q, float* dst) {
    dst[0] = lo2f(q.x); dst[1] = hi2f(q.x);
    dst[2] = lo2f(q.y); dst[3] = hi2f(q.y);
    dst[4] = lo2f(q.z); dst[5] = hi2f(q.z);
    dst[6] = lo2f(q.w); dst[7] = hi2f(q.w);
}

// ---- dtype detector (validated) ----
__global__ void detect_dtype(const u32* x, const u32* W1, const u32* b1,
                             const u32* W2, const u32* b2, const u32* rw,
                             u32* flags) {
    int t = threadIdx.x;
    if (t >= 6) return;
    const u32* p = (t == 0) ? x : (t == 1) ? W1 : (t == 2) ? b1
                 : (t == 3) ? W2 : (t == 4) ? b2 : rw;
    int c = 0;
    for (int i = 0; i < 64; i++) {
        u32 e = (p[i] >> 7) & 0xFF;
        c += (e >= 64 && e <= 140) ? 1 : 0;
    }
    flags[t] = (c >= 48) ? 1u : 0u;
}

// ---- prep_all (R20: xb/Wt 4-wide): xb4 | Wt4 | rwb | b1f (+ rwn | W2t | b2f) ----
__global__ void prep_all(const void* x, const void* W1, const void* b1,
                         const void* W2, const void* b2, const void* rw,
                         bfu* __restrict__ xb, bfu* __restrict__ Wt,
                         float* __restrict__ b1f, bfu* __restrict__ rwb,
                         bfu* __restrict__ rwn, float* __restrict__ W2t,
                         float* __restrict__ b2f,
                         const u32* flags, int B, int mode) {
    const int idx = blockIdx.x * 256 + threadIdx.x;
    const int nxb4 = B * 200;
    if (idx < nxb4) {                                  // xb[B][800] bf16, 4/thread
        const bool b16 = flags[0] != 0;
        int b = idx / 200, kk = (idx - b * 200) * 4;
        ushort4 w;
        if (kk < 784) {                                // 784%4==0: chunks never straddle
            int src = b * 784 + kk;
            if (b16) {
                w = *(const ushort4*)((const bfu*)x + src);
            } else {
                float4 f = *(const float4*)((const float*)x + src);
                w.x = f2bf(f.x); w.y = f2bf(f.y); w.z = f2bf(f.z); w.w = f2bf(f.w);
            }
        } else { w.x = 0; w.y = 0; w.z = 0; w.w = 0; }
        *(ushort4*)(xb + b * 800 + kk) = w;
        return;
    }
    int i2 = idx - nxb4;
    if (i2 < 640 * 200) {                              // Wt[c][k] bf16, 4/thread
        const bool wb = flags[1] != 0;
        int c = i2 / 200, k = (i2 - c * 200) * 4;
        ushort4 w; w.x = 0; w.y = 0; w.z = 0; w.w = 0;
        if (c < 600 && k < 784) {
            int nn = c / 20, o = c - nn * 20;
            int src = nn * 15680 + k * 20 + o;         // k-stride 20
            if (wb) {
                const bfu* p = (const bfu*)W1;
                w.x = p[src]; w.y = p[src + 20]; w.z = p[src + 40]; w.w = p[src + 60];
            } else {
                const float* p = (const float*)W1;
                w.x = f2bf(p[src]); w.y = f2bf(p[src + 20]);
                w.z = f2bf(p[src + 40]); w.w = f2bf(p[src + 60]);
            }
        }
        *(ushort4*)(Wt + c * 800 + k) = w;
        return;
    }
    i2 -= 640 * 200;
    if (i2 < 96000) {                                  // rwb[o][n][k][d] bf16 (fallback k3y2)
        const bool rb = flags[5] != 0;
        int d = i2 % 20;
        int k = (i2 / 20) % 16;
        int n = (i2 / 320) % 30;
        int o = i2 / 9600;
        int src = o * 9600 + n * 320 + d * 16 + k;
        rwb[i2] = rb ? ((const bfu*)rw)[src] : f2bf(((const float*)rw)[src]);
        return;
    }
    i2 -= 96000;
    if (i2 < 640) {                                    // b1f fp32
        b1f[i2] = (i2 < 600) ? ldf(b1, i2, flags[2] != 0) : 0.f;
        return;
    }
    i2 -= 640;
    if (mode != 0) return;
    if (i2 < 153600) {                                 // rwn[n][col=o*16+k][dd<32] bf16, K-pad
        const bool rb = flags[5] != 0;
        int dd = i2 % 32;
        int col = (i2 / 32) % 160;
        int n = i2 / 5120;
        bfu v = 0;
        if (dd < 20) {
            int o = col / 16, kk = col % 16;
            int src = o * 9600 + n * 320 + dd * 16 + kk;
            v = rb ? ((const bfu*)rw)[src] : f2bf(((const float*)rw)[src]);
        }
        rwn[i2] = v;
        return;
    }
    i2 -= 153600;
    if (i2 < 12000) {                                  // W2t[n][e][d] fp32 = W2[n][d][e]
        int d = i2 % 20;
        int e = (i2 / 20) % 20;
        int n = i2 / 400;
        W2t[i2] = ldf(W2, n * 400 + d * 20 + e, flags[3] != 0);
        return;
    }
    i2 -= 12000;
    if (i2 < 640) {                                    // b2f fp32
        b2f[i2] = (i2 < 600) ? ldf(b2, i2, flags[4] != 0) : 0.f;
    }
}

// ---------------- K1m: h1 = relu(xb @ Wt^T + b1), bf16 MFMA (validated, BK=64) ----------------
// tr==1 (mode 0): store h1 as [n][b][20] (coalesced reads for k2q). tr==0: [b][600].
__global__ __launch_bounds__(256, 4) void k1m(const bfu* __restrict__ xb, const bfu* __restrict__ Wt,
                                              const float* __restrict__ b1f,
                                              float* __restrict__ h1, int Btot, int tr) {
    __shared__ short As[128 * 72];     // [row][64+8pad]
    __shared__ short Bs[64 * 72];
    const int tid = threadIdx.x;
    const int w = tid >> 6, lane = tid & 63;
    const int quad = lane >> 4, fl = lane & 15;
    const int m0 = blockIdx.x * 128, n0 = blockIdx.y * 64;

    floatx4 acc[2][4];
    #pragma unroll
    for (int mi = 0; mi < 2; mi++)
        #pragma unroll
        for (int ni = 0; ni < 4; ni++) acc[mi][ni] = (floatx4){0.f, 0.f, 0.f, 0.f};

    const int arow = tid >> 1, aseg = tid & 1;    // 2 thr/row, 64B each
    const int brow = tid >> 2, bseg = tid & 3;    // 4 thr/row, 32B each
    int agrow = m0 + arow; if (agrow >= Btot) agrow = Btot - 1;
    const bfu* abase = xb + (size_t)agrow * 800 + aseg * 32;
    const bfu* bbase = Wt + (size_t)(n0 + brow) * 800 + bseg * 16;

    // 12 steps of BK=64
    for (int k0 = 0; k0 < 768; k0 += 64) {
        uint4 qa0 = *(const uint4*)(abase + k0);
        uint4 qa1 = *(const uint4*)(abase + k0 + 8);
        uint4 qa2 = *(const uint4*)(abase + k0 + 16);
        uint4 qa3 = *(const uint4*)(abase + k0 + 24);
        uint4 qb0 = *(const uint4*)(bbase + k0);
        uint4 qb1 = *(const uint4*)(bbase + k0 + 8);

        __syncthreads();
        *(uint4*)&As[arow * 72 + aseg * 32 + 0]  = qa0;
        *(uint4*)&As[arow * 72 + aseg * 32 + 8]  = qa1;
        *(uint4*)&As[arow * 72 + aseg * 32 + 16] = qa2;
        *(uint4*)&As[arow * 72 + aseg * 32 + 24] = qa3;
        *(uint4*)&Bs[brow * 72 + bseg * 16 + 0]  = qb0;
        *(uint4*)&Bs[brow * 72 + bseg * 16 + 8]  = qb1;
        __syncthreads();

        short8 af[2][2], bfr[4][2];
        #pragma unroll
        for (int mi = 0; mi < 2; mi++)
            #pragma unroll
            for (int kk = 0; kk < 2; kk++)
                af[mi][kk] = *(const short8*)&As[(w * 32 + mi * 16 + fl) * 72 + kk * 32 + quad * 8];
        #pragma unroll
        for (int ni = 0; ni < 4; ni++)
            #pragma unroll
            for (int kk = 0; kk < 2; kk++)
                bfr[ni][kk] = *(const short8*)&Bs[(ni * 16 + fl) * 72 + kk * 32 + quad * 8];
        #pragma unroll
        for (int kk = 0; kk < 2; kk++)
            #pragma unroll
            for (int mi = 0; mi < 2; mi++)
                #pragma unroll
                for (int ni = 0; ni < 4; ni++)
                    acc[mi][ni] = __builtin_amdgcn_mfma_f32_16x16x32_bf16(af[mi][kk], bfr[ni][kk], acc[mi][ni], 0, 0, 0);
    }

    // tail step: k0=768, 32 wide
    {
        const bfu* at = xb + (size_t)agrow * 800 + 768 + aseg * 16;
        const bfu* bt = Wt + (size_t)(n0 + brow) * 800 + 768 + bseg * 8;
        uint4 qa0 = *(const uint4*)(at);
        uint4 qa1 = *(const uint4*)(at + 8);
        uint4 qb0 = *(const uint4*)(bt);

        __syncthreads();
        *(uint4*)&As[arow * 72 + aseg * 16 + 0] = qa0;
        *(uint4*)&As[arow * 72 + aseg * 16 + 8] = qa1;
        *(uint4*)&Bs[brow * 72 + bseg * 8] = qb0;
        __syncthreads();

        short8 af[2], bfr[4];
        #pragma unroll
        for (int mi = 0; mi < 2; mi++)
            af[mi] = *(const short8*)&As[(w * 32 + mi * 16 + fl) * 72 + quad * 8];
        #pragma unroll
        for (int ni = 0; ni < 4; ni++)
            bfr[ni] = *(const short8*)&Bs[(ni * 16 + fl) * 72 + quad * 8];
        #pragma unroll
        for (int mi = 0; mi < 2; mi++)
            #pragma unroll
            for (int ni = 0; ni < 4; ni++)
                acc[mi][ni] = __builtin_amdgcn_mfma_f32_16x16x32_bf16(af[mi], bfr[ni], acc[mi][ni], 0, 0, 0);
    }

    #pragma unroll
    for (int mi = 0; mi < 2; mi++) {
        #pragma unroll
        for (int ni = 0; ni < 4; ni++) {
            const int c = n0 + ni * 16 + fl;
            const int cn = c / 20, ce = c - cn * 20;
            #pragma unroll
            for (int r = 0; r < 4; r++) {
                const int m = m0 + w * 32 + mi * 16 + quad * 4 + r;
                if (c < 600 && m < Btot) {
                    size_t di = tr ? (((size_t)cn * Btot + m) * 20 + ce)
                                   : ((size_t)m * 600 + c);
                    h1[di] = fmaxf(acc[mi][ni][r] + b1f[c], 0.f);
                }
            }
        }
    }
}

// ---------------- K2q (main, validated R18): fused u-compute + priors MFMA ----------------
__global__ __launch_bounds__(256) void k2q(const float* __restrict__ h1n,
                                           const float* __restrict__ W2t,
                                           const float* __restrict__ b2f,
                                           const bfu* __restrict__ rwn,
                                           bfu* __restrict__ pri, int Btot) {
    __shared__ short us[128 * 40];
    const int tid = threadIdx.x;
    const int n = blockIdx.y;
    const int b0 = blockIdx.x * 128;

    const int w = tid >> 6, lane = tid & 63;
    const int quad = lane >> 4, fl = lane & 15;
    short8 bfr[10];
    #pragma unroll
    for (int nj = 0; nj < 10; nj++)
        bfr[nj] = *(const short8*)(rwn + ((size_t)n * 160 + nj * 16 + fl) * 32 + quad * 8);

    {
        const int row = tid >> 1, half = tid & 1;
        int br = b0 + row; if (br >= Btot) br = Btot - 1;
        float h[20];
        const float* hp = h1n + ((size_t)n * Btot + br) * 20;
        #pragma unroll
        for (int d4 = 0; d4 < 20; d4 += 4) {
            float4 v = *(const float4*)(hp + d4);
            h[d4] = v.x; h[d4 + 1] = v.y; h[d4 + 2] = v.z; h[d4 + 3] = v.w;
        }
        const float* wn = W2t + n * 400;
        const float* bn = b2f + n * 20;
        float o[10], sq = 0.f;
        #pragma unroll
        for (int i = 0; i < 10; i++) {
            const int e = 2 * i + half;
            float acc = bn[e];
            #pragma unroll
            for (int d = 0; d < 20; d++) acc += h[d] * wn[e * 20 + d];
            acc = fmaxf(acc, 0.f);
            o[i] = acc;
            sq += acc * acc;
        }
        sq += __shfl_xor(sq, 1);
        float sc = (sq > 0.f) ? sqrtf(sq) / (1.f + sq) : 0.f;
        #pragma unroll
        for (int i = 0; i < 10; i++)
            us[row * 40 + 2 * i + half] = (short)f2bf(o[i] * sc);
        #pragma unroll
        for (int i = 10; i < 16; i++)
            us[row * 40 + 2 * i + half] = 0;
    }
    __syncthreads();

    #pragma unroll
    for (int mi = 0; mi < 2; mi++) {
        short8 af = *(const short8*)&us[(w * 32 + mi * 16 + fl) * 40 + quad * 8];
        #pragma unroll
        for (int nj = 0; nj < 10; nj++) {
            floatx4 acc = (floatx4){0.f, 0.f, 0.f, 0.f};
            acc = __builtin_amdgcn_mfma_f32_16x16x32_bf16(af, bfr[nj], acc, 0, 0, 0);
            #pragma unroll
            for (int r = 0; r < 4; r++) {
                int mr = b0 + w * 32 + mi * 16 + quad * 4 + r;
                if (mr < Btot)
                    pri[(size_t)mr * 4800 + nj * 480 + n * 16 + fl] = f2bf(acc[r]);
            }
        }
    }
}

// ---------------- K2 core (fallback path, validated math) ----------------
__device__ __forceinline__ void k2_core(const float* hp, const float* wn, const float* bn,
                                        float* o, float& sc) {
    float h[20];
    #pragma unroll
    for (int d4 = 0; d4 < 20; d4 += 4) {
        float4 v = *(const float4*)(hp + d4);
        h[d4] = v.x; h[d4 + 1] = v.y; h[d4 + 2] = v.z; h[d4 + 3] = v.w;
    }
    float sq = 0.f;
    #pragma unroll
    for (int e = 0; e < 20; e++) {
        float acc = bn[e];
        #pragma unroll
        for (int d = 0; d < 20; d++) acc += h[d] * wn[d * 20 + e];
        acc = fmaxf(acc, 0.f);
        o[e] = acc;
        sq += acc * acc;
    }
    sc = (sq > 0.f) ? sqrtf(sq) / (1.f + sq) : 0.f;
}

// K2s (fallback, validated): u fp32 in place
__global__ __launch_bounds__(256) void k2s(const float* h1, const void* W2, const void* b2,
                                           float* u, const u32* flags, int total) {
    __shared__ float W2s[12000];
    __shared__ float b2s[600];
    const bool wb = flags[3] != 0, bb = flags[4] != 0;
    const int tid = threadIdx.x;
    for (int i = tid; i < 12000; i += 256) W2s[i] = ldf(W2, i, wb);
    for (int i = tid; i < 600; i += 256) b2s[i] = ldf(b2, i, bb);
    __syncthreads();

    int t = blockIdx.x * 256 + tid;
    if (t >= total) return;
    const int b = t / 30, n = t - b * 30;
    float o[20], sc;
    k2_core(h1 + (size_t)b * 600 + n * 20, &W2s[n * 400], &b2s[n * 20], o, sc);
    float* up = u + (size_t)b * 600 + n * 20;
    #pragma unroll
    for (int e4 = 0; e4 < 20; e4 += 4) {
        float4 v;
        v.x = o[e4] * sc; v.y = o[e4 + 1] * sc; v.z = o[e4 + 2] * sc; v.w = o[e4 + 3] * sc;
        *(float4*)(up + e4) = v;
    }
}

// ---------------- K3v: routing, LDS-broadcast allgather (R20) ----------------
// 320 thr = 2 rows/block; per row 160 threads (o=r>>4, j=r&15); per-lane math == k3t2.
// Allgather of s[k] across the 16-lane o-group: 1 ds_write + 4 float4 broadcast reads.
// o-groups are wave-internal (16-aligned) -> same-wave DS ordering, no barrier needed.
// S rows stride 20 floats: 4 o-rows/wave hit disjoint bank quads (conflict-free reads).
__global__ __launch_bounds__(320, 4) void k3v(const bfu* __restrict__ pri_buf,
                                              float* __restrict__ out, int Btot) {
    __shared__ float L[2][300];
    __shared__ float P[2][300];
    __shared__ float S[2][200];   // [g][o*20 + k]
    const int tid = threadIdx.x;
    const int g = tid / 160, r = tid - g * 160;
    const int o = r >> 4, j = r & 15;
    const int b0 = blockIdx.x * 2;
    int bb = b0 + g; if (bb >= Btot) bb = Btot - 1;

    const int n0 = 2 * j, n1 = n0 + 1;
    float p0[16], p1[16];
    if (j < 15) {
        const bfu* pb = pri_buf + (size_t)bb * 4800 + (size_t)o * 480 + j * 32;
        uint4 q0 = *(const uint4*)(pb);        // n0 k0..7
        uint4 q1 = *(const uint4*)(pb + 8);    // n0 k8..15
        uint4 q2 = *(const uint4*)(pb + 16);   // n1 k0..7
        uint4 q3 = *(const uint4*)(pb + 24);   // n1 k8..15
        unpack8(q0, p0); unpack8(q1, p0 + 8);
        unpack8(q2, p1); unpack8(q3, p1 + 8);
    } else {
        #pragma unroll
        for (int i = 0; i < 16; i++) { p0[i] = 0.f; p1[i] = 0.f; }
    }

    float L0 = 0.f, L1 = 0.f;
    float v = 0.f;
    #pragma unroll
    for (int it = 0; it < 3; it++) {
        float P0, P1;
        if (it == 0) {
            P0 = 0.1f; P1 = 0.1f;              // softmax(zeros) over 10 outputs
        } else {
            if (r < 30) {                       // dedicated softmax over o for net r
                float l[10];
                #pragma unroll
                for (int oo = 0; oo < 10; oo++) l[oo] = L[g][r * 10 + oo];
                float mx = l[0];
                #pragma unroll
                for (int oo = 1; oo < 10; oo++) mx = fmaxf(mx, l[oo]);
                float den = 0.f;
                #pragma unroll
                for (int oo = 0; oo < 10; oo++) { l[oo] = __expf(l[oo] - mx); den += l[oo]; }
                float inv = 1.f / den;
                #pragma unroll
                for (int oo = 0; oo < 10; oo++) P[g][r * 10 + oo] = l[oo] * inv;
            }
            __syncthreads();
            P0 = (j < 15) ? P[g][n0 * 10 + o] : 0.f;
            P1 = (j < 15) ? P[g][n1 * 10 + o] : 0.f;
        }

        float t[16];
        #pragma unroll
        for (int i = 0; i < 16; i++) t[i] = P0 * p0[i] + P1 * p1[i];

        // 16-lane transpose-reduce: lane j ends with s[k=j] (15 shuffles)
        #pragma unroll
        for (int i = 0; i < 8; i++) {
            float send = (j & 8) ? t[i] : t[i + 8];
            float recv = __shfl_xor(send, 8, 16);
            t[i] = ((j & 8) ? t[i + 8] : t[i]) + recv;
        }
        #pragma unroll
        for (int i = 0; i < 4; i++) {
            float send = (j & 4) ? t[i] : t[i + 4];
            float recv = __shfl_xor(send, 4, 16);
            t[i] = ((j & 4) ? t[i + 4] : t[i]) + recv;
        }
        #pragma unroll
        for (int i = 0; i < 2; i++) {
            float send = (j & 2) ? t[i] : t[i + 2];
            float recv = __shfl_xor(send, 2, 16);
            t[i] = ((j & 2) ? t[i + 2] : t[i]) + recv;
        }
        {
            float send = (j & 1) ? t[0] : t[1];
            float recv = __shfl_xor(send, 1, 16);
            t[0] = ((j & 1) ? t[1] : t[0]) + recv;
        }
        float s = t[0];                         // s[o, k=j]

        if (it < 2) {
            // wave-internal LDS allgather: write s, read back the o-group's 16 values
            S[g][o * 20 + j] = s;
            float4 s0 = *(const float4*)&S[g][o * 20 + 0];
            float4 s1 = *(const float4*)&S[g][o * 20 + 4];
            float4 s2 = *(const float4*)&S[g][o * 20 + 8];
            float4 s3 = *(const float4*)&S[g][o * 20 + 12];
            float sf[16];
            sf[0] = s0.x;  sf[1] = s0.y;  sf[2] = s0.z;  sf[3] = s0.w;
            sf[4] = s1.x;  sf[5] = s1.y;  sf[6] = s1.z;  sf[7] = s1.w;
            sf[8] = s2.x;  sf[9] = s2.y;  sf[10] = s2.z; sf[11] = s2.w;
            sf[12] = s3.x; sf[13] = s3.y; sf[14] = s3.z; sf[15] = s3.w;
            float q = 0.f;
            #pragma unroll
            for (int k = 0; k < 16; k++) q += sf[k] * sf[k];
            float scale = sqrtf(q) / (1.f + q);
            v = s * scale;
            float d0 = 0.f, d1 = 0.f;
            #pragma unroll
            for (int k = 0; k < 16; k++) {
                float vk = sf[k] * scale;
                d0 += p0[k] * vk;
                d1 += p1[k] * vk;
            }
            L0 += d0; L1 += d1;
            if (j < 15) {
                L[g][n0 * 10 + o] = L0;
                L[g][n1 * 10 + o] = L1;
            }
            __syncthreads();
        } else {
            float q = s * s;
            q += __shfl_xor(q, 1, 16);
            q += __shfl_xor(q, 2, 16);
            q += __shfl_xor(q, 4, 16);
            q += __shfl_xor(q, 8, 16);
            v = s * sqrtf(q) / (1.f + q);
        }
    }
    if ((b0 + g) < Btot) out[(size_t)(b0 + g) * 160 + r] = v;
}

// ---------------- K3y2 (fallback, validated @202us) ----------------
__global__ __launch_bounds__(640, 2) void k3y2(const float* __restrict__ u,
                                               const bfu* __restrict__ rwb,
                                               float* __restrict__ out, int Btot) {
    __shared__ float US[4][600];
    __shared__ float L[4][300];
    __shared__ float P[4][300];
    const int tid = threadIdx.x;
    const int g = tid / 160, r = tid - g * 160;
    const int o = r >> 4, k = r & 15;
    const int b0 = blockIdx.x * 4;

    {
        const int nf4 = 150;
        for (int i = tid; i < 4 * nf4; i += 640) {
            int gg = i / nf4, j = i - gg * nf4;
            int bb = b0 + gg; if (bb >= Btot) bb = Btot - 1;
            *(float4*)&US[gg][j * 4] = *(const float4*)(u + (size_t)bb * 600 + j * 4);
        }
        for (int i = tid; i < 1200; i += 640) L[i / 300][i % 300] = 0.f;
    }
    __syncthreads();

    float pri[30];
    const bfu* rp = rwb + o * 9600 + k * 20;
    #pragma unroll 2
    for (int n = 0; n < 30; n++) {
        const uint2* rq = (const uint2*)(rp + n * 320);
        float a = 0.f;
        #pragma unroll
        for (int jj = 0; jj < 5; jj++) {
            uint2 w = rq[jj];
            float4 uu = *(const float4*)&US[g][n * 20 + jj * 4];
            a += lo2f(w.x) * uu.x + hi2f(w.x) * uu.y + lo2f(w.y) * uu.z + hi2f(w.y) * uu.w;
        }
        pri[n] = a;
    }

    float v = 0.f;
    for (int it = 0; it < 3; it++) {
        if (r < 30) {
            const int n = r;
            float mx = L[g][n * 10];
            #pragma unroll
            for (int oo = 1; oo < 10; oo++) mx = fmaxf(mx, L[g][n * 10 + oo]);
            float e[10], den = 0.f;
            #pragma unroll
            for (int oo = 0; oo < 10; oo++) { e[oo] = __expf(L[g][n * 10 + oo] - mx); den += e[oo]; }
            float inv = 1.f / den;
            #pragma unroll
            for (int oo = 0; oo < 10; oo++) P[g][n * 10 + oo] = e[oo] * inv;
        }
        __syncthreads();
        float s = 0.f;
        #pragma unroll
        for (int n = 0; n < 30; n++) s += P[g][n * 10 + o] * pri[n];
        float q = s * s;
        q += __shfl_xor(q, 1, 16);
        q += __shfl_xor(q, 2, 16);
        q += __shfl_xor(q, 4, 16);
        q += __shfl_xor(q, 8, 16);
        v = s * sqrtf(q) / (1.f + q);
        if (it < 2) {
            #pragma unroll 5
            for (int n = 0; n < 30; n++) {
                float t = pri[n] * v;
                t += __shfl_xor(t, 1, 16);
                t += __shfl_xor(t, 2, 16);
                t += __shfl_xor(t, 4, 16);
                t += __shfl_xor(t, 8, 16);
                if (k == 0) L[g][n * 10 + o] += t;
            }
            __syncthreads();
        }
    }
    if ((b0 + g) < Btot) out[(size_t)(b0 + g) * 160 + r] = v;
}

extern "C" void kernel_launch(void* const* d_in, const int* in_sizes, int n_in,
                              void* d_out, int out_size, void* d_ws, size_t ws_size,
                              hipStream_t stream) {
    // ---- size-based input matching (validated) ----
    int ix = -1, iw1 = -1, ib1 = -1, iw2 = -1, ib2 = -1, irw = -1;
    for (int i = 0; i < n_in; i++) {
        int s = in_sizes[i];
        if (s == 470400 && iw1 < 0) iw1 = i;
        else if (s == 12000 && iw2 < 0) iw2 = i;
        else if (s == 96000 && irw < 0) irw = i;
        else if (s == 600) { if (ib1 < 0) ib1 = i; else if (ib2 < 0) ib2 = i; }
    }
    long bestsz = -1;
    for (int i = 0; i < n_in; i++) {
        if (i == iw1 || i == iw2 || i == irw || i == ib1 || i == ib2) continue;
        if ((long)in_sizes[i] > bestsz) { bestsz = in_sizes[i]; ix = i; }
    }
    if (ix < 0 || iw1 < 0 || ib1 < 0 || iw2 < 0 || ib2 < 0 || irw < 0) {
        ix = 0; iw1 = 1; ib1 = 2; iw2 = 3; ib2 = 4; irw = 5;
    }
    const void* x  = d_in[ix];
    const void* W1 = d_in[iw1];
    const void* b1 = d_in[ib1];
    const void* W2 = d_in[iw2];
    const void* b2 = d_in[ib2];
    const void* rw = d_in[irw];
    const int B = in_sizes[ix] / 784;
    float* out = (float*)d_out;

    // ---- ws layout (byte offsets, all 16B-aligned) ----
    char* base = (char*)d_ws;
    size_t off = 0;
    float* h1u  = (float*)(base + off); off += (size_t)B * 2400;       // B*600 f32
    float* b1f  = (float*)(base + off); off += 2560;                   // 640 f32
    u32*  flags = (u32*)(base + off);   off += 32;                     // 8 u32
    bfu*   Wt   = (bfu*)(base + off);   off += 1024000;                // 640*800 bf16
    bfu*   xb   = (bfu*)(base + off);   off += (size_t)B * 1600;       // B*800 bf16
    bfu*   rwb  = (bfu*)(base + off);   off += 192000;                 // 96000 bf16
    size_t fb_bytes = off;
    bfu*   rwn  = (bfu*)(base + off);   off += 307200;                 // 30*160*32 bf16
    float* W2t  = (float*)(base + off); off += 48000;                  // 30*20*20 f32
    float* b2f  = (float*)(base + off); off += 2560;                   // 640 f32
    bfu*   pri  = (bfu*)(base + off);   off += (size_t)B * 9600;       // B*4800 bf16
    size_t main_bytes = off;

    const int mode = (ws_size >= main_bytes) ? 0 : 1;   // fixed per-call -> graph-safe
    const int prep_total = B * 200 + 640 * 200 + 96000 + 640
                         + (mode == 0 ? (153600 + 12000 + 640) : 0);

    detect_dtype<<<1, 64, 0, stream>>>((const u32*)x, (const u32*)W1, (const u32*)b1,
                                       (const u32*)W2, (const u32*)b2, (const u32*)rw, flags);
    prep_all<<<(prep_total + 255) / 256, 256, 0, stream>>>(x, W1, b1, W2, b2, rw,
                                                           xb, Wt, b1f, rwb, rwn,
                                                           W2t, b2f, flags, B, mode);
    k1m<<<dim3((B + 127) / 128, 10), 256, 0, stream>>>(xb, Wt, b1f, h1u, B, mode == 0 ? 1 : 0);
    if (mode == 0) {
        k2q<<<dim3((B + 127) / 128, 30), 256, 0, stream>>>(h1u, W2t, b2f, rwn, pri, B);
        k3v<<<(B + 1) / 2, 320, 0, stream>>>(pri, out, B);
    } else {
        (void)fb_bytes;
        k2s<<<(B * 30 + 255) / 256, 256, 0, stream>>>(h1u, W2, b2, h1u, flags, B * 30);
        k3y2<<<(B + 3) / 4, 640, 0, stream>>>(h1u, rwb, out, B);
    }
}

// Round 7
// 168.656 us; speedup vs baseline: 1.6258x; 1.0288x over previous
//
#include <hip/hip_runtime.h>

// B(derived), IN_DIM=784, NUM_NETS=30, N_NODES=20, NUM_OUT=10, DIM_OUT=16, NUM_ITER=3
// Validated: size-based binding; dtype detect; k1m MFMA BK=64; k3 routing math; k2 fused
// u+priors MFMA. R21: k2q was 54us with 80 scalar 2B global stores/thread (4x32B scattered
// segments per instr, 2.46M write transactions; HBM 24%, VALU 16% -> store-issue bound).
// -> k2w: pri goes N-MAJOR [b][n*160+o*16+k]; per-mi acc staged to LDS pst[64][168]
// (168-stride: quad rows hit spread banks; fl-pair same-word alias = 2-way = free),
// then cooperative uint4 writes: 10 global stores/thread, fully coalesced 320B runs.
// k3w reads n-major: 2x32B per lane; j-clusters of 4 o's form contiguous 128B spans.
// Fallback k2s+k3y2 unchanged.

typedef unsigned short bfu;
typedef unsigned int u32;
typedef __attribute__((ext_vector_type(8))) short short8;
typedef __attribute__((ext_vector_type(4))) float floatx4;

__device__ __forceinline__ float bf2f(bfu u) { union { u32 i; float f; } v; v.i = ((u32)u) << 16; return v.f; }
__device__ __forceinline__ float lo2f(u32 w) { union { u32 i; float f; } v; v.i = w << 16; return v.f; }
__device__ __forceinline__ float hi2f(u32 w) { union { u32 i; float f; } v; v.i = w & 0xffff0000u; return v.f; }
__device__ __forceinline__ float ldf(const void* p, int idx, bool b16) {
    return b16 ? bf2f(((const bfu*)p)[idx]) : ((const float*)p)[idx];
}
__device__ __forceinline__ bfu f2bf(float f) {   // RNE
    u32 u = __float_as_uint(f);
    return (bfu)((u + 0x7FFFu + ((u >> 16) & 1u)) >> 16);
}
__device__ __forceinline__ void unpack8(uint4 q, float* dst) {
    dst[0] = lo2f(q.x); dst[1] = hi2f(q.x);
    dst[2] = lo2f(q.y); dst[3] = hi2f(q.y);
    dst[4] = lo2f(q.z); dst[5] = hi2f(q.z);
    dst[6] = lo2f(q.w); dst[7] = hi2f(q.w);
}

// ---- dtype detector (validated) ----
__global__ void detect_dtype(const u32* x, const u32* W1, const u32* b1,
                             const u32* W2, const u32* b2, const u32* rw,
                             u32* flags) {
    int t = threadIdx.x;
    if (t >= 6) return;
    const u32* p = (t == 0) ? x : (t == 1) ? W1 : (t == 2) ? b1
                 : (t == 3) ? W2 : (t == 4) ? b2 : rw;
    int c = 0;
    for (int i = 0; i < 64; i++) {
        u32 e = (p[i] >> 7) & 0xFF;
        c += (e >= 64 && e <= 140) ? 1 : 0;
    }
    flags[t] = (c >= 48) ? 1u : 0u;
}

// ---- prep_all (validated R20): xb4 | Wt4 | rwb | b1f (+ rwn | W2t | b2f) ----
__global__ void prep_all(const void* x, const void* W1, const void* b1,
                         const void* W2, const void* b2, const void* rw,
                         bfu* __restrict__ xb, bfu* __restrict__ Wt,
                         float* __restrict__ b1f, bfu* __restrict__ rwb,
                         bfu* __restrict__ rwn, float* __restrict__ W2t,
                         float* __restrict__ b2f,
                         const u32* flags, int B, int mode) {
    const int idx = blockIdx.x * 256 + threadIdx.x;
    const int nxb4 = B * 200;
    if (idx < nxb4) {                                  // xb[B][800] bf16, 4/thread
        const bool b16 = flags[0] != 0;
        int b = idx / 200, kk = (idx - b * 200) * 4;
        ushort4 w;
        if (kk < 784) {                                // 784%4==0: chunks never straddle
            int src = b * 784 + kk;
            if (b16) {
                w = *(const ushort4*)((const bfu*)x + src);
            } else {
                float4 f = *(const float4*)((const float*)x + src);
                w.x = f2bf(f.x); w.y = f2bf(f.y); w.z = f2bf(f.z); w.w = f2bf(f.w);
            }
        } else { w.x = 0; w.y = 0; w.z = 0; w.w = 0; }
        *(ushort4*)(xb + b * 800 + kk) = w;
        return;
    }
    int i2 = idx - nxb4;
    if (i2 < 640 * 200) {                              // Wt[c][k] bf16, 4/thread
        const bool wb = flags[1] != 0;
        int c = i2 / 200, k = (i2 - c * 200) * 4;
        ushort4 w; w.x = 0; w.y = 0; w.z = 0; w.w = 0;
        if (c < 600 && k < 784) {
            int nn = c / 20, o = c - nn * 20;
            int src = nn * 15680 + k * 20 + o;         // k-stride 20
            if (wb) {
                const bfu* p = (const bfu*)W1;
                w.x = p[src]; w.y = p[src + 20]; w.z = p[src + 40]; w.w = p[src + 60];
            } else {
                const float* p = (const float*)W1;
                w.x = f2bf(p[src]); w.y = f2bf(p[src + 20]);
                w.z = f2bf(p[src + 40]); w.w = f2bf(p[src + 60]);
            }
        }
        *(ushort4*)(Wt + c * 800 + k) = w;
        return;
    }
    i2 -= 640 * 200;
    if (i2 < 96000) {                                  // rwb[o][n][k][d] bf16 (fallback k3y2)
        const bool rb = flags[5] != 0;
        int d = i2 % 20;
        int k = (i2 / 20) % 16;
        int n = (i2 / 320) % 30;
        int o = i2 / 9600;
        int src = o * 9600 + n * 320 + d * 16 + k;
        rwb[i2] = rb ? ((const bfu*)rw)[src] : f2bf(((const float*)rw)[src]);
        return;
    }
    i2 -= 96000;
    if (i2 < 640) {                                    // b1f fp32
        b1f[i2] = (i2 < 600) ? ldf(b1, i2, flags[2] != 0) : 0.f;
        return;
    }
    i2 -= 640;
    if (mode != 0) return;
    if (i2 < 153600) {                                 // rwn[n][col=o*16+k][dd<32] bf16, K-pad
        const bool rb = flags[5] != 0;
        int dd = i2 % 32;
        int col = (i2 / 32) % 160;
        int n = i2 / 5120;
        bfu v = 0;
        if (dd < 20) {
            int o = col / 16, kk = col % 16;
            int src = o * 9600 + n * 320 + dd * 16 + kk;
            v = rb ? ((const bfu*)rw)[src] : f2bf(((const float*)rw)[src]);
        }
        rwn[i2] = v;
        return;
    }
    i2 -= 153600;
    if (i2 < 12000) {                                  // W2t[n][e][d] fp32 = W2[n][d][e]
        int d = i2 % 20;
        int e = (i2 / 20) % 20;
        int n = i2 / 400;
        W2t[i2] = ldf(W2, n * 400 + d * 20 + e, flags[3] != 0);
        return;
    }
    i2 -= 12000;
    if (i2 < 640) {                                    // b2f fp32
        b2f[i2] = (i2 < 600) ? ldf(b2, i2, flags[4] != 0) : 0.f;
    }
}

// ---------------- K1m: h1 = relu(xb @ Wt^T + b1), bf16 MFMA (validated, BK=64) ----------------
// tr==1 (mode 0): store h1 as [n][b][20] (coalesced reads for k2w). tr==0: [b][600].
__global__ __launch_bounds__(256, 4) void k1m(const bfu* __restrict__ xb, const bfu* __restrict__ Wt,
                                              const float* __restrict__ b1f,
                                              float* __restrict__ h1, int Btot, int tr) {
    __shared__ short As[128 * 72];     // [row][64+8pad]
    __shared__ short Bs[64 * 72];
    const int tid = threadIdx.x;
    const int w = tid >> 6, lane = tid & 63;
    const int quad = lane >> 4, fl = lane & 15;
    const int m0 = blockIdx.x * 128, n0 = blockIdx.y * 64;

    floatx4 acc[2][4];
    #pragma unroll
    for (int mi = 0; mi < 2; mi++)
        #pragma unroll
        for (int ni = 0; ni < 4; ni++) acc[mi][ni] = (floatx4){0.f, 0.f, 0.f, 0.f};

    const int arow = tid >> 1, aseg = tid & 1;    // 2 thr/row, 64B each
    const int brow = tid >> 2, bseg = tid & 3;    // 4 thr/row, 32B each
    int agrow = m0 + arow; if (agrow >= Btot) agrow = Btot - 1;
    const bfu* abase = xb + (size_t)agrow * 800 + aseg * 32;
    const bfu* bbase = Wt + (size_t)(n0 + brow) * 800 + bseg * 16;

    // 12 steps of BK=64
    for (int k0 = 0; k0 < 768; k0 += 64) {
        uint4 qa0 = *(const uint4*)(abase + k0);
        uint4 qa1 = *(const uint4*)(abase + k0 + 8);
        uint4 qa2 = *(const uint4*)(abase + k0 + 16);
        uint4 qa3 = *(const uint4*)(abase + k0 + 24);
        uint4 qb0 = *(const uint4*)(bbase + k0);
        uint4 qb1 = *(const uint4*)(bbase + k0 + 8);

        __syncthreads();
        *(uint4*)&As[arow * 72 + aseg * 32 + 0]  = qa0;
        *(uint4*)&As[arow * 72 + aseg * 32 + 8]  = qa1;
        *(uint4*)&As[arow * 72 + aseg * 32 + 16] = qa2;
        *(uint4*)&As[arow * 72 + aseg * 32 + 24] = qa3;
        *(uint4*)&Bs[brow * 72 + bseg * 16 + 0]  = qb0;
        *(uint4*)&Bs[brow * 72 + bseg * 16 + 8]  = qb1;
        __syncthreads();

        short8 af[2][2], bfr[4][2];
        #pragma unroll
        for (int mi = 0; mi < 2; mi++)
            #pragma unroll
            for (int kk = 0; kk < 2; kk++)
                af[mi][kk] = *(const short8*)&As[(w * 32 + mi * 16 + fl) * 72 + kk * 32 + quad * 8];
        #pragma unroll
        for (int ni = 0; ni < 4; ni++)
            #pragma unroll
            for (int kk = 0; kk < 2; kk++)
                bfr[ni][kk] = *(const short8*)&Bs[(ni * 16 + fl) * 72 + kk * 32 + quad * 8];
        #pragma unroll
        for (int kk = 0; kk < 2; kk++)
            #pragma unroll
            for (int mi = 0; mi < 2; mi++)
                #pragma unroll
                for (int ni = 0; ni < 4; ni++)
                    acc[mi][ni] = __builtin_amdgcn_mfma_f32_16x16x32_bf16(af[mi][kk], bfr[ni][kk], acc[mi][ni], 0, 0, 0);
    }

    // tail step: k0=768, 32 wide
    {
        const bfu* at = xb + (size_t)agrow * 800 + 768 + aseg * 16;
        const bfu* bt = Wt + (size_t)(n0 + brow) * 800 + 768 + bseg * 8;
        uint4 qa0 = *(const uint4*)(at);
        uint4 qa1 = *(const uint4*)(at + 8);
        uint4 qb0 = *(const uint4*)(bt);

        __syncthreads();
        *(uint4*)&As[arow * 72 + aseg * 16 + 0] = qa0;
        *(uint4*)&As[arow * 72 + aseg * 16 + 8] = qa1;
        *(uint4*)&Bs[brow * 72 + bseg * 8] = qb0;
        __syncthreads();

        short8 af[2], bfr[4];
        #pragma unroll
        for (int mi = 0; mi < 2; mi++)
            af[mi] = *(const short8*)&As[(w * 32 + mi * 16 + fl) * 72 + quad * 8];
        #pragma unroll
        for (int ni = 0; ni < 4; ni++)
            bfr[ni] = *(const short8*)&Bs[(ni * 16 + fl) * 72 + quad * 8];
        #pragma unroll
        for (int mi = 0; mi < 2; mi++)
            #pragma unroll
            for (int ni = 0; ni < 4; ni++)
                acc[mi][ni] = __builtin_amdgcn_mfma_f32_16x16x32_bf16(af[mi], bfr[ni], acc[mi][ni], 0, 0, 0);
    }

    #pragma unroll
    for (int mi = 0; mi < 2; mi++) {
        #pragma unroll
        for (int ni = 0; ni < 4; ni++) {
            const int c = n0 + ni * 16 + fl;
            const int cn = c / 20, ce = c - cn * 20;
            #pragma unroll
            for (int r = 0; r < 4; r++) {
                const int m = m0 + w * 32 + mi * 16 + quad * 4 + r;
                if (c < 600 && m < Btot) {
                    size_t di = tr ? (((size_t)cn * Btot + m) * 20 + ce)
                                   : ((size_t)m * 600 + c);
                    h1[di] = fmaxf(acc[mi][ni][r] + b1f[c], 0.f);
                }
            }
        }
    }
}

// ---------------- K2w (main, R21): fused u-compute + priors MFMA, coalesced store ----------------
// grid (ceil(B/128), 30); block 256. Phase 1: u as before (LDS us[128][40]).
// Phase 2: per mi, MFMA accs -> LDS pst[64][168] (bf16), barrier, cooperative uint4
// write-out of 320B-contiguous rows to n-major pri[b][n*160 + o*16 + k].
__global__ __launch_bounds__(256) void k2w(const float* __restrict__ h1n,
                                           const float* __restrict__ W2t,
                                           const float* __restrict__ b2f,
                                           const bfu* __restrict__ rwn,
                                           bfu* __restrict__ pri, int Btot) {
    __shared__ short us[128 * 40];
    __shared__ short pst[64 * 168];   // [row_local][160 + 8 pad]
    const int tid = threadIdx.x;
    const int n = blockIdx.y;
    const int b0 = blockIdx.x * 128;

    const int w = tid >> 6, lane = tid & 63;
    const int quad = lane >> 4, fl = lane & 15;
    short8 bfr[10];
    #pragma unroll
    for (int nj = 0; nj < 10; nj++)
        bfr[nj] = *(const short8*)(rwn + ((size_t)n * 160 + nj * 16 + fl) * 32 + quad * 8);

    {   // ---- phase 1: u for rows b0..b0+127 ----
        const int row = tid >> 1, half = tid & 1;
        int br = b0 + row; if (br >= Btot) br = Btot - 1;
        float h[20];
        const float* hp = h1n + ((size_t)n * Btot + br) * 20;
        #pragma unroll
        for (int d4 = 0; d4 < 20; d4 += 4) {
            float4 v = *(const float4*)(hp + d4);
            h[d4] = v.x; h[d4 + 1] = v.y; h[d4 + 2] = v.z; h[d4 + 3] = v.w;
        }
        const float* wn = W2t + n * 400;
        const float* bn = b2f + n * 20;
        float o[10], sq = 0.f;
        #pragma unroll
        for (int i = 0; i < 10; i++) {
            const int e = 2 * i + half;
            float acc = bn[e];
            #pragma unroll
            for (int d = 0; d < 20; d++) acc += h[d] * wn[e * 20 + d];
            acc = fmaxf(acc, 0.f);
            o[i] = acc;
            sq += acc * acc;
        }
        sq += __shfl_xor(sq, 1);
        float sc = (sq > 0.f) ? sqrtf(sq) / (1.f + sq) : 0.f;
        #pragma unroll
        for (int i = 0; i < 10; i++)
            us[row * 40 + 2 * i + half] = (short)f2bf(o[i] * sc);
        #pragma unroll
        for (int i = 10; i < 16; i++)
            us[row * 40 + 2 * i + half] = 0;
    }
    __syncthreads();

    // ---- phase 2: per-mi MFMA -> LDS stage -> coalesced write ----
    #pragma unroll
    for (int mi = 0; mi < 2; mi++) {
        short8 af = *(const short8*)&us[(w * 32 + mi * 16 + fl) * 40 + quad * 8];
        #pragma unroll
        for (int nj = 0; nj < 10; nj++) {
            floatx4 acc = (floatx4){0.f, 0.f, 0.f, 0.f};
            acc = __builtin_amdgcn_mfma_f32_16x16x32_bf16(af, bfr[nj], acc, 0, 0, 0);
            // row_local = w*16 + quad*4 + r  (0..63); col = nj*16 + fl
            #pragma unroll
            for (int r = 0; r < 4; r++)
                pst[(w * 16 + quad * 4 + r) * 168 + nj * 16 + fl] = (short)f2bf(acc[r]);
        }
        __syncthreads();
        // cooperative write: 64 rows x 320B contiguous; 1280 uint4 = 256 thr x 5
        #pragma unroll
        for (int s = 0; s < 5; s++) {
            int i = s * 256 + tid;
            int rl = i / 20, seg = i - rl * 20;
            int row = b0 + (rl >> 4) * 32 + mi * 16 + (rl & 15);
            if (row < Btot)
                *(uint4*)(pri + (size_t)row * 4800 + n * 160 + seg * 8)
                    = *(const uint4*)&pst[rl * 168 + seg * 8];
        }
        __syncthreads();
    }
}

// ---------------- K2 core (fallback path, validated math) ----------------
__device__ __forceinline__ void k2_core(const float* hp, const float* wn, const float* bn,
                                        float* o, float& sc) {
    float h[20];
    #pragma unroll
    for (int d4 = 0; d4 < 20; d4 += 4) {
        float4 v = *(const float4*)(hp + d4);
        h[d4] = v.x; h[d4 + 1] = v.y; h[d4 + 2] = v.z; h[d4 + 3] = v.w;
    }
    float sq = 0.f;
    #pragma unroll
    for (int e = 0; e < 20; e++) {
        float acc = bn[e];
        #pragma unroll
        for (int d = 0; d < 20; d++) acc += h[d] * wn[d * 20 + e];
        acc = fmaxf(acc, 0.f);
        o[e] = acc;
        sq += acc * acc;
    }
    sc = (sq > 0.f) ? sqrtf(sq) / (1.f + sq) : 0.f;
}

// K2s (fallback, validated): u fp32 in place
__global__ __launch_bounds__(256) void k2s(const float* h1, const void* W2, const void* b2,
                                           float* u, const u32* flags, int total) {
    __shared__ float W2s[12000];
    __shared__ float b2s[600];
    const bool wb = flags[3] != 0, bb = flags[4] != 0;
    const int tid = threadIdx.x;
    for (int i = tid; i < 12000; i += 256) W2s[i] = ldf(W2, i, wb);
    for (int i = tid; i < 600; i += 256) b2s[i] = ldf(b2, i, bb);
    __syncthreads();

    int t = blockIdx.x * 256 + tid;
    if (t >= total) return;
    const int b = t / 30, n = t - b * 30;
    float o[20], sc;
    k2_core(h1 + (size_t)b * 600 + n * 20, &W2s[n * 400], &b2s[n * 20], o, sc);
    float* up = u + (size_t)b * 600 + n * 20;
    #pragma unroll
    for (int e4 = 0; e4 < 20; e4 += 4) {
        float4 v;
        v.x = o[e4] * sc; v.y = o[e4 + 1] * sc; v.z = o[e4 + 2] * sc; v.w = o[e4 + 3] * sc;
        *(float4*)(up + e4) = v;
    }
}

// ---------------- K3w: routing, LDS-broadcast allgather, n-major pri (R21) ----------------
// 320 thr = 2 rows/block; per row 160 threads (o=r>>4, j=r&15); per-lane math == k3v.
__global__ __launch_bounds__(320, 4) void k3w(const bfu* __restrict__ pri_buf,
                                              float* __restrict__ out, int Btot) {
    __shared__ float L[2][300];
    __shared__ float P[2][300];
    __shared__ float S[2][200];   // [g][o*20 + k]
    const int tid = threadIdx.x;
    const int g = tid / 160, r = tid - g * 160;
    const int o = r >> 4, j = r & 15;
    const int b0 = blockIdx.x * 2;
    int bb = b0 + g; if (bb >= Btot) bb = Btot - 1;

    const int n0 = 2 * j, n1 = n0 + 1;
    float p0[16], p1[16];
    if (j < 15) {
        const bfu* pb = pri_buf + (size_t)bb * 4800 + n0 * 160 + o * 16;
        uint4 q0 = *(const uint4*)(pb);          // n0 k0..7
        uint4 q1 = *(const uint4*)(pb + 8);      // n0 k8..15
        uint4 q2 = *(const uint4*)(pb + 160);    // n1 k0..7
        uint4 q3 = *(const uint4*)(pb + 168);    // n1 k8..15
        unpack8(q0, p0); unpack8(q1, p0 + 8);
        unpack8(q2, p1); unpack8(q3, p1 + 8);
    } else {
        #pragma unroll
        for (int i = 0; i < 16; i++) { p0[i] = 0.f; p1[i] = 0.f; }
    }

    float L0 = 0.f, L1 = 0.f;
    float v = 0.f;
    #pragma unroll
    for (int it = 0; it < 3; it++) {
        float P0, P1;
        if (it == 0) {
            P0 = 0.1f; P1 = 0.1f;              // softmax(zeros) over 10 outputs
        } else {
            if (r < 30) {                       // dedicated softmax over o for net r
                float l[10];
                #pragma unroll
                for (int oo = 0; oo < 10; oo++) l[oo] = L[g][r * 10 + oo];
                float mx = l[0];
                #pragma unroll
                for (int oo = 1; oo < 10; oo++) mx = fmaxf(mx, l[oo]);
                float den = 0.f;
                #pragma unroll
                for (int oo = 0; oo < 10; oo++) { l[oo] = __expf(l[oo] - mx); den += l[oo]; }
                float inv = 1.f / den;
                #pragma unroll
                for (int oo = 0; oo < 10; oo++) P[g][r * 10 + oo] = l[oo] * inv;
            }
            __syncthreads();
            P0 = (j < 15) ? P[g][n0 * 10 + o] : 0.f;
            P1 = (j < 15) ? P[g][n1 * 10 + o] : 0.f;
        }

        float t[16];
        #pragma unroll
        for (int i = 0; i < 16; i++) t[i] = P0 * p0[i] + P1 * p1[i];

        // 16-lane transpose-reduce: lane j ends with s[k=j] (15 shuffles)
        #pragma unroll
        for (int i = 0; i < 8; i++) {
            float send = (j & 8) ? t[i] : t[i + 8];
            float recv = __shfl_xor(send, 8, 16);
            t[i] = ((j & 8) ? t[i + 8] : t[i]) + recv;
        }
        #pragma unroll
        for (int i = 0; i < 4; i++) {
            float send = (j & 4) ? t[i] : t[i + 4];
            float recv = __shfl_xor(send, 4, 16);
            t[i] = ((j & 4) ? t[i + 4] : t[i]) + recv;
        }
        #pragma unroll
        for (int i = 0; i < 2; i++) {
            float send = (j & 2) ? t[i] : t[i + 2];
            float recv = __shfl_xor(send, 2, 16);
            t[i] = ((j & 2) ? t[i + 2] : t[i]) + recv;
        }
        {
            float send = (j & 1) ? t[0] : t[1];
            float recv = __shfl_xor(send, 1, 16);
            t[0] = ((j & 1) ? t[1] : t[0]) + recv;
        }
        float s = t[0];                         // s[o, k=j]

        if (it < 2) {
            // wave-internal LDS allgather: write s, read back the o-group's 16 values
            S[g][o * 20 + j] = s;
            float4 s0 = *(const float4*)&S[g][o * 20 + 0];
            float4 s1 = *(const float4*)&S[g][o * 20 + 4];
            float4 s2 = *(const float4*)&S[g][o * 20 + 8];
            float4 s3 = *(const float4*)&S[g][o * 20 + 12];
            float sf[16];
            sf[0] = s0.x;  sf[1] = s0.y;  sf[2] = s0.z;  sf[3] = s0.w;
            sf[4] = s1.x;  sf[5] = s1.y;  sf[6] = s1.z;  sf[7] = s1.w;
            sf[8] = s2.x;  sf[9] = s2.y;  sf[10] = s2.z; sf[11] = s2.w;
            sf[12] = s3.x; sf[13] = s3.y; sf[14] = s3.z; sf[15] = s3.w;
            float q = 0.f;
            #pragma unroll
            for (int k = 0; k < 16; k++) q += sf[k] * sf[k];
            float scale = sqrtf(q) / (1.f + q);
            v = s * scale;
            float d0 = 0.f, d1 = 0.f;
            #pragma unroll
            for (int k = 0; k < 16; k++) {
                float vk = sf[k] * scale;
                d0 += p0[k] * vk;
                d1 += p1[k] * vk;
            }
            L0 += d0; L1 += d1;
            if (j < 15) {
                L[g][n0 * 10 + o] = L0;
                L[g][n1 * 10 + o] = L1;
            }
            __syncthreads();
        } else {
            float q = s * s;
            q += __shfl_xor(q, 1, 16);
            q += __shfl_xor(q, 2, 16);
            q += __shfl_xor(q, 4, 16);
            q += __shfl_xor(q, 8, 16);
            v = s * sqrtf(q) / (1.f + q);
        }
    }
    if ((b0 + g) < Btot) out[(size_t)(b0 + g) * 160 + r] = v;
}

// ---------------- K3y2 (fallback, validated @202us) ----------------
__global__ __launch_bounds__(640, 2) void k3y2(const float* __restrict__ u,
                                               const bfu* __restrict__ rwb,
                                               float* __restrict__ out, int Btot) {
    __shared__ float US[4][600];
    __shared__ float L[4][300];
    __shared__ float P[4][300];
    const int tid = threadIdx.x;
    const int g = tid / 160, r = tid - g * 160;
    const int o = r >> 4, k = r & 15;
    const int b0 = blockIdx.x * 4;

    {
        const int nf4 = 150;
        for (int i = tid; i < 4 * nf4; i += 640) {
            int gg = i / nf4, j = i - gg * nf4;
            int bb = b0 + gg; if (bb >= Btot) bb = Btot - 1;
            *(float4*)&US[gg][j * 4] = *(const float4*)(u + (size_t)bb * 600 + j * 4);
        }
        for (int i = tid; i < 1200; i += 640) L[i / 300][i % 300] = 0.f;
    }
    __syncthreads();

    float pri[30];
    const bfu* rp = rwb + o * 9600 + k * 20;
    #pragma unroll 2
    for (int n = 0; n < 30; n++) {
        const uint2* rq = (const uint2*)(rp + n * 320);
        float a = 0.f;
        #pragma unroll
        for (int jj = 0; jj < 5; jj++) {
            uint2 w = rq[jj];
            float4 uu = *(const float4*)&US[g][n * 20 + jj * 4];
            a += lo2f(w.x) * uu.x + hi2f(w.x) * uu.y + lo2f(w.y) * uu.z + hi2f(w.y) * uu.w;
        }
        pri[n] = a;
    }

    float v = 0.f;
    for (int it = 0; it < 3; it++) {
        if (r < 30) {
            const int n = r;
            float mx = L[g][n * 10];
            #pragma unroll
            for (int oo = 1; oo < 10; oo++) mx = fmaxf(mx, L[g][n * 10 + oo]);
            float e[10], den = 0.f;
            #pragma unroll
            for (int oo = 0; oo < 10; oo++) { e[oo] = __expf(L[g][n * 10 + oo] - mx); den += e[oo]; }
            float inv = 1.f / den;
            #pragma unroll
            for (int oo = 0; oo < 10; oo++) P[g][n * 10 + oo] = e[oo] * inv;
        }
        __syncthreads();
        float s = 0.f;
        #pragma unroll
        for (int n = 0; n < 30; n++) s += P[g][n * 10 + o] * pri[n];
        float q = s * s;
        q += __shfl_xor(q, 1, 16);
        q += __shfl_xor(q, 2, 16);
        q += __shfl_xor(q, 4, 16);
        q += __shfl_xor(q, 8, 16);
        v = s * sqrtf(q) / (1.f + q);
        if (it < 2) {
            #pragma unroll 5
            for (int n = 0; n < 30; n++) {
                float t = pri[n] * v;
                t += __shfl_xor(t, 1, 16);
                t += __shfl_xor(t, 2, 16);
                t += __shfl_xor(t, 4, 16);
                t += __shfl_xor(t, 8, 16);
                if (k == 0) L[g][n * 10 + o] += t;
            }
            __syncthreads();
        }
    }
    if ((b0 + g) < Btot) out[(size_t)(b0 + g) * 160 + r] = v;
}

extern "C" void kernel_launch(void* const* d_in, const int* in_sizes, int n_in,
                              void* d_out, int out_size, void* d_ws, size_t ws_size,
                              hipStream_t stream) {
    // ---- size-based input matching (validated) ----
    int ix = -1, iw1 = -1, ib1 = -1, iw2 = -1, ib2 = -1, irw = -1;
    for (int i = 0; i < n_in; i++) {
        int s = in_sizes[i];
        if (s == 470400 && iw1 < 0) iw1 = i;
        else if (s == 12000 && iw2 < 0) iw2 = i;
        else if (s == 96000 && irw < 0) irw = i;
        else if (s == 600) { if (ib1 < 0) ib1 = i; else if (ib2 < 0) ib2 = i; }
    }
    long bestsz = -1;
    for (int i = 0; i < n_in; i++) {
        if (i == iw1 || i == iw2 || i == irw || i == ib1 || i == ib2) continue;
        if ((long)in_sizes[i] > bestsz) { bestsz = in_sizes[i]; ix = i; }
    }
    if (ix < 0 || iw1 < 0 || ib1 < 0 || iw2 < 0 || ib2 < 0 || irw < 0) {
        ix = 0; iw1 = 1; ib1 = 2; iw2 = 3; ib2 = 4; irw = 5;
    }
    const void* x  = d_in[ix];
    const void* W1 = d_in[iw1];
    const void* b1 = d_in[ib1];
    const void* W2 = d_in[iw2];
    const void* b2 = d_in[ib2];
    const void* rw = d_in[irw];
    const int B = in_sizes[ix] / 784;
    float* out = (float*)d_out;

    // ---- ws layout (byte offsets, all 16B-aligned) ----
    char* base = (char*)d_ws;
    size_t off = 0;
    float* h1u  = (float*)(base + off); off += (size_t)B * 2400;       // B*600 f32
    float* b1f  = (float*)(base + off); off += 2560;                   // 640 f32
    u32*  flags = (u32*)(base + off);   off += 32;                     // 8 u32
    bfu*   Wt   = (bfu*)(base + off);   off += 1024000;                // 640*800 bf16
    bfu*   xb   = (bfu*)(base + off);   off += (size_t)B * 1600;       // B*800 bf16
    bfu*   rwb  = (bfu*)(base + off);   off += 192000;                 // 96000 bf16
    size_t fb_bytes = off;
    bfu*   rwn  = (bfu*)(base + off);   off += 307200;                 // 30*160*32 bf16
    float* W2t  = (float*)(base + off); off += 48000;                  // 30*20*20 f32
    float* b2f  = (float*)(base + off); off += 2560;                   // 640 f32
    bfu*   pri  = (bfu*)(base + off);   off += (size_t)B * 9600;       // B*4800 bf16
    size_t main_bytes = off;

    const int mode = (ws_size >= main_bytes) ? 0 : 1;   // fixed per-call -> graph-safe
    const int prep_total = B * 200 + 640 * 200 + 96000 + 640
                         + (mode == 0 ? (153600 + 12000 + 640) : 0);

    detect_dtype<<<1, 64, 0, stream>>>((const u32*)x, (const u32*)W1, (const u32*)b1,
                                       (const u32*)W2, (const u32*)b2, (const u32*)rw, flags);
    prep_all<<<(prep_total + 255) / 256, 256, 0, stream>>>(x, W1, b1, W2, b2, rw,
                                                           xb, Wt, b1f, rwb, rwn,
                                                           W2t, b2f, flags, B, mode);
    k1m<<<dim3((B + 127) / 128, 10), 256, 0, stream>>>(xb, Wt, b1f, h1u, B, mode == 0 ? 1 : 0);
    if (mode == 0) {
        k2w<<<dim3((B + 127) / 128, 30), 256, 0, stream>>>(h1u, W2t, b2f, rwn, pri, B);
        k3w<<<(B + 1) / 2, 320, 0, stream>>>(pri, out, B);
    } else {
        (void)fb_bytes;
        k2s<<<(B * 30 + 255) / 256, 256, 0, stream>>>(h1u, W2, b2, h1u, flags, B * 30);
        k3y2<<<(B + 3) / 4, 640, 0, stream>>>(h1u, rwb, out, B);
    }
}

// Round 8
// 163.494 us; speedup vs baseline: 1.6771x; 1.0316x over previous
//
#include <hip/hip_runtime.h>

// B(derived), IN_DIM=784, NUM_NETS=30, N_NODES=20, NUM_OUT=10, DIM_OUT=16, NUM_ITER=3
// Validated: size-based binding; k1m MFMA BK=64; k2w fused u+priors MFMA w/ LDS-staged
// coalesced pri store (n-major); k3w routing w/ LDS-broadcast allgather.
// R22: (a) detect_dtype folded INTO prep_all (per-block LDS flags, 6x64 L2-hot loads +
// 1 barrier) -- kills a serial 1-block launch on the critical path; standalone detect
// kept for the fallback path only (k2s reads global flags). (b) k1m tr=1 epilogue was
// 32 scalar f32 stores/thread scattered at ((c/20)*B+m)*20+ce (same pathology as R21's
// k2q): now staged to LDS ep[128][68] f32 (unioned over As/Bs, barrier-guarded), then
// 8 cooperative float4 stores/thread; 20%4==0 so every 16B chunk is within one net row
// (80B contiguous runs). Fallback k2s+k3y2 unchanged.

typedef unsigned short bfu;
typedef unsigned int u32;
typedef __attribute__((ext_vector_type(8))) short short8;
typedef __attribute__((ext_vector_type(4))) float floatx4;

__device__ __forceinline__ float bf2f(bfu u) { union { u32 i; float f; } v; v.i = ((u32)u) << 16; return v.f; }
__device__ __forceinline__ float lo2f(u32 w) { union { u32 i; float f; } v; v.i = w << 16; return v.f; }
__device__ __forceinline__ float hi2f(u32 w) { union { u32 i; float f; } v; v.i = w & 0xffff0000u; return v.f; }
__device__ __forceinline__ float ldf(const void* p, int idx, bool b16) {
    return b16 ? bf2f(((const bfu*)p)[idx]) : ((const float*)p)[idx];
}
__device__ __forceinline__ bfu f2bf(float f) {   // RNE
    u32 u = __float_as_uint(f);
    return (bfu)((u + 0x7FFFu + ((u >> 16) & 1u)) >> 16);
}
__device__ __forceinline__ void unpack8(uint4 q, float* dst) {
    dst[0] = lo2f(q.x); dst[1] = hi2f(q.x);
    dst[2] = lo2f(q.y); dst[3] = hi2f(q.y);
    dst[4] = lo2f(q.z); dst[5] = hi2f(q.z);
    dst[6] = lo2f(q.w); dst[7] = hi2f(q.w);
}
__device__ __forceinline__ u32 detect_one(const u32* p) {
    int c = 0;
    for (int i = 0; i < 64; i++) {
        u32 e = (p[i] >> 7) & 0xFF;
        c += (e >= 64 && e <= 140) ? 1 : 0;
    }
    return (c >= 48) ? 1u : 0u;
}

// ---- dtype detector (fallback path only; k2s reads global flags) ----
__global__ void detect_dtype(const u32* x, const u32* W1, const u32* b1,
                             const u32* W2, const u32* b2, const u32* rw,
                             u32* flags) {
    int t = threadIdx.x;
    if (t >= 6) return;
    const u32* p = (t == 0) ? x : (t == 1) ? W1 : (t == 2) ? b1
                 : (t == 3) ? W2 : (t == 4) ? b2 : rw;
    flags[t] = detect_one(p);
}

// ---- prep_all (R22: self-detecting): xb4 | Wt4 | rwb | b1f (+ rwn | W2t | b2f) ----
__global__ void prep_all(const void* x, const void* W1, const void* b1,
                         const void* W2, const void* b2, const void* rw,
                         bfu* __restrict__ xb, bfu* __restrict__ Wt,
                         float* __restrict__ b1f, bfu* __restrict__ rwb,
                         bfu* __restrict__ rwn, float* __restrict__ W2t,
                         float* __restrict__ b2f,
                         int B, int mode) {
    __shared__ u32 flg[6];
    {
        const int t = threadIdx.x;
        if (t < 6) {
            const u32* p = (t == 0) ? (const u32*)x : (t == 1) ? (const u32*)W1
                         : (t == 2) ? (const u32*)b1 : (t == 3) ? (const u32*)W2
                         : (t == 4) ? (const u32*)b2 : (const u32*)rw;
            flg[t] = detect_one(p);
        }
    }
    __syncthreads();

    const int idx = blockIdx.x * 256 + threadIdx.x;
    const int nxb4 = B * 200;
    if (idx < nxb4) {                                  // xb[B][800] bf16, 4/thread
        const bool b16 = flg[0] != 0;
        int b = idx / 200, kk = (idx - b * 200) * 4;
        ushort4 w;
        if (kk < 784) {                                // 784%4==0: chunks never straddle
            int src = b * 784 + kk;
            if (b16) {
                w = *(const ushort4*)((const bfu*)x + src);
            } else {
                float4 f = *(const float4*)((const float*)x + src);
                w.x = f2bf(f.x); w.y = f2bf(f.y); w.z = f2bf(f.z); w.w = f2bf(f.w);
            }
        } else { w.x = 0; w.y = 0; w.z = 0; w.w = 0; }
        *(ushort4*)(xb + b * 800 + kk) = w;
        return;
    }
    int i2 = idx - nxb4;
    if (i2 < 640 * 200) {                              // Wt[c][k] bf16, 4/thread
        const bool wb = flg[1] != 0;
        int c = i2 / 200, k = (i2 - c * 200) * 4;
        ushort4 w; w.x = 0; w.y = 0; w.z = 0; w.w = 0;
        if (c < 600 && k < 784) {
            int nn = c / 20, o = c - nn * 20;
            int src = nn * 15680 + k * 20 + o;         // k-stride 20
            if (wb) {
                const bfu* p = (const bfu*)W1;
                w.x = p[src]; w.y = p[src + 20]; w.z = p[src + 40]; w.w = p[src + 60];
            } else {
                const float* p = (const float*)W1;
                w.x = f2bf(p[src]); w.y = f2bf(p[src + 20]);
                w.z = f2bf(p[src + 40]); w.w = f2bf(p[src + 60]);
            }
        }
        *(ushort4*)(Wt + c * 800 + k) = w;
        return;
    }
    i2 -= 640 * 200;
    if (i2 < 96000) {                                  // rwb[o][n][k][d] bf16 (fallback k3y2)
        const bool rb = flg[5] != 0;
        int d = i2 % 20;
        int k = (i2 / 20) % 16;
        int n = (i2 / 320) % 30;
        int o = i2 / 9600;
        int src = o * 9600 + n * 320 + d * 16 + k;
        rwb[i2] = rb ? ((const bfu*)rw)[src] : f2bf(((const float*)rw)[src]);
        return;
    }
    i2 -= 96000;
    if (i2 < 640) {                                    // b1f fp32
        b1f[i2] = (i2 < 600) ? ldf(b1, i2, flg[2] != 0) : 0.f;
        return;
    }
    i2 -= 640;
    if (mode != 0) return;
    if (i2 < 153600) {                                 // rwn[n][col=o*16+k][dd<32] bf16, K-pad
        const bool rb = flg[5] != 0;
        int dd = i2 % 32;
        int col = (i2 / 32) % 160;
        int n = i2 / 5120;
        bfu v = 0;
        if (dd < 20) {
            int o = col / 16, kk = col % 16;
            int src = o * 9600 + n * 320 + dd * 16 + kk;
            v = rb ? ((const bfu*)rw)[src] : f2bf(((const float*)rw)[src]);
        }
        rwn[i2] = v;
        return;
    }
    i2 -= 153600;
    if (i2 < 12000) {                                  // W2t[n][e][d] fp32 = W2[n][d][e]
        int d = i2 % 20;
        int e = (i2 / 20) % 20;
        int n = i2 / 400;
        W2t[i2] = ldf(W2, n * 400 + d * 20 + e, flg[3] != 0);
        return;
    }
    i2 -= 12000;
    if (i2 < 640) {                                    // b2f fp32
        b2f[i2] = (i2 < 600) ? ldf(b2, i2, flg[4] != 0) : 0.f;
    }
}

// ---------------- K1m: h1 = relu(xb @ Wt^T + b1), bf16 MFMA (BK=64; R22 epilogue) ----------------
// tr==1 (mode 0): h1 [n][b][20], LDS-staged coalesced float4 stores. tr==0: [b][600] direct.
__global__ __launch_bounds__(256, 4) void k1m(const bfu* __restrict__ xb, const bfu* __restrict__ Wt,
                                              const float* __restrict__ b1f,
                                              float* __restrict__ h1, int Btot, int tr) {
    __shared__ __align__(16) char smem[128 * 68 * 4];   // max(As+Bs=27648, ep=34816)
    short* As = (short*)smem;                // [128][72]
    short* Bs = (short*)(smem + 128 * 72 * 2);  // [64][72]
    const int tid = threadIdx.x;
    const int w = tid >> 6, lane = tid & 63;
    const int quad = lane >> 4, fl = lane & 15;
    const int m0 = blockIdx.x * 128, n0 = blockIdx.y * 64;

    floatx4 acc[2][4];
    #pragma unroll
    for (int mi = 0; mi < 2; mi++)
        #pragma unroll
        for (int ni = 0; ni < 4; ni++) acc[mi][ni] = (floatx4){0.f, 0.f, 0.f, 0.f};

    const int arow = tid >> 1, aseg = tid & 1;    // 2 thr/row, 64B each
    const int brow = tid >> 2, bseg = tid & 3;    // 4 thr/row, 32B each
    int agrow = m0 + arow; if (agrow >= Btot) agrow = Btot - 1;
    const bfu* abase = xb + (size_t)agrow * 800 + aseg * 32;
    const bfu* bbase = Wt + (size_t)(n0 + brow) * 800 + bseg * 16;

    // 12 steps of BK=64
    for (int k0 = 0; k0 < 768; k0 += 64) {
        uint4 qa0 = *(const uint4*)(abase + k0);
        uint4 qa1 = *(const uint4*)(abase + k0 + 8);
        uint4 qa2 = *(const uint4*)(abase + k0 + 16);
        uint4 qa3 = *(const uint4*)(abase + k0 + 24);
        uint4 qb0 = *(const uint4*)(bbase + k0);
        uint4 qb1 = *(const uint4*)(bbase + k0 + 8);

        __syncthreads();
        *(uint4*)&As[arow * 72 + aseg * 32 + 0]  = qa0;
        *(uint4*)&As[arow * 72 + aseg * 32 + 8]  = qa1;
        *(uint4*)&As[arow * 72 + aseg * 32 + 16] = qa2;
        *(uint4*)&As[arow * 72 + aseg * 32 + 24] = qa3;
        *(uint4*)&Bs[brow * 72 + bseg * 16 + 0]  = qb0;
        *(uint4*)&Bs[brow * 72 + bseg * 16 + 8]  = qb1;
        __syncthreads();

        short8 af[2][2], bfr[4][2];
        #pragma unroll
        for (int mi = 0; mi < 2; mi++)
            #pragma unroll
            for (int kk = 0; kk < 2; kk++)
                af[mi][kk] = *(const short8*)&As[(w * 32 + mi * 16 + fl) * 72 + kk * 32 + quad * 8];
        #pragma unroll
        for (int ni = 0; ni < 4; ni++)
            #pragma unroll
            for (int kk = 0; kk < 2; kk++)
                bfr[ni][kk] = *(const short8*)&Bs[(ni * 16 + fl) * 72 + kk * 32 + quad * 8];
        #pragma unroll
        for (int kk = 0; kk < 2; kk++)
            #pragma unroll
            for (int mi = 0; mi < 2; mi++)
                #pragma unroll
                for (int ni = 0; ni < 4; ni++)
                    acc[mi][ni] = __builtin_amdgcn_mfma_f32_16x16x32_bf16(af[mi][kk], bfr[ni][kk], acc[mi][ni], 0, 0, 0);
    }

    // tail step: k0=768, 32 wide
    {
        const bfu* at = xb + (size_t)agrow * 800 + 768 + aseg * 16;
        const bfu* bt = Wt + (size_t)(n0 + brow) * 800 + 768 + bseg * 8;
        uint4 qa0 = *(const uint4*)(at);
        uint4 qa1 = *(const uint4*)(at + 8);
        uint4 qb0 = *(const uint4*)(bt);

        __syncthreads();
        *(uint4*)&As[arow * 72 + aseg * 16 + 0] = qa0;
        *(uint4*)&As[arow * 72 + aseg * 16 + 8] = qa1;
        *(uint4*)&Bs[brow * 72 + bseg * 8] = qb0;
        __syncthreads();

        short8 af[2], bfr[4];
        #pragma unroll
        for (int mi = 0; mi < 2; mi++)
            af[mi] = *(const short8*)&As[(w * 32 + mi * 16 + fl) * 72 + quad * 8];
        #pragma unroll
        for (int ni = 0; ni < 4; ni++)
            bfr[ni] = *(const short8*)&Bs[(ni * 16 + fl) * 72 + quad * 8];
        #pragma unroll
        for (int mi = 0; mi < 2; mi++)
            #pragma unroll
            for (int ni = 0; ni < 4; ni++)
                acc[mi][ni] = __builtin_amdgcn_mfma_f32_16x16x32_bf16(af[mi], bfr[ni], acc[mi][ni], 0, 0, 0);
    }

    if (tr) {
        // R22 epilogue: stage bias+relu result to LDS (reuses As/Bs region), then
        // cooperative float4 writes: 8/thread, 80B-contiguous runs in h1n[n][b][20].
        __syncthreads();                       // all waves done reading As/Bs
        float* ep = (float*)smem;              // [128][68]
        #pragma unroll
        for (int mi = 0; mi < 2; mi++) {
            #pragma unroll
            for (int ni = 0; ni < 4; ni++) {
                const int c = n0 + ni * 16 + fl;
                const float bias = b1f[c];     // b1f padded to 640
                #pragma unroll
                for (int r = 0; r < 4; r++)
                    ep[(w * 32 + mi * 16 + quad * 4 + r) * 68 + ni * 16 + fl]
                        = fmaxf(acc[mi][ni][r] + bias, 0.f);
            }
        }
        __syncthreads();
        #pragma unroll
        for (int s = 0; s < 8; s++) {
            const int i = s * 256 + tid;
            const int ml = i >> 4, cq = i & 15;
            const int c = n0 + cq * 4;
            const int m = m0 + ml;
            if (c < 600 && m < Btot) {
                const int cn = c / 20, ce = c - cn * 20;   // 20%4==0: chunk within net
                *(float4*)(h1 + ((size_t)cn * Btot + m) * 20 + ce)
                    = *(const float4*)&ep[ml * 68 + cq * 4];
            }
        }
    } else {
        #pragma unroll
        for (int mi = 0; mi < 2; mi++) {
            #pragma unroll
            for (int ni = 0; ni < 4; ni++) {
                const int c = n0 + ni * 16 + fl;
                #pragma unroll
                for (int r = 0; r < 4; r++) {
                    const int m = m0 + w * 32 + mi * 16 + quad * 4 + r;
                    if (c < 600 && m < Btot)
                        h1[(size_t)m * 600 + c] = fmaxf(acc[mi][ni][r] + b1f[c], 0.f);
                }
            }
        }
    }
}

// ---------------- K2w (main, validated R21): fused u-compute + priors MFMA, coalesced store ----------------
__global__ __launch_bounds__(256) void k2w(const float* __restrict__ h1n,
                                           const float* __restrict__ W2t,
                                           const float* __restrict__ b2f,
                                           const bfu* __restrict__ rwn,
                                           bfu* __restrict__ pri, int Btot) {
    __shared__ short us[128 * 40];
    __shared__ short pst[64 * 168];   // [row_local][160 + 8 pad]
    const int tid = threadIdx.x;
    const int n = blockIdx.y;
    const int b0 = blockIdx.x * 128;

    const int w = tid >> 6, lane = tid & 63;
    const int quad = lane >> 4, fl = lane & 15;
    short8 bfr[10];
    #pragma unroll
    for (int nj = 0; nj < 10; nj++)
        bfr[nj] = *(const short8*)(rwn + ((size_t)n * 160 + nj * 16 + fl) * 32 + quad * 8);

    {   // ---- phase 1: u for rows b0..b0+127 ----
        const int row = tid >> 1, half = tid & 1;
        int br = b0 + row; if (br >= Btot) br = Btot - 1;
        float h[20];
        const float* hp = h1n + ((size_t)n * Btot + br) * 20;
        #pragma unroll
        for (int d4 = 0; d4 < 20; d4 += 4) {
            float4 v = *(const float4*)(hp + d4);
            h[d4] = v.x; h[d4 + 1] = v.y; h[d4 + 2] = v.z; h[d4 + 3] = v.w;
        }
        const float* wn = W2t + n * 400;
        const float* bn = b2f + n * 20;
        float o[10], sq = 0.f;
        #pragma unroll
        for (int i = 0; i < 10; i++) {
            const int e = 2 * i + half;
            float acc = bn[e];
            #pragma unroll
            for (int d = 0; d < 20; d++) acc += h[d] * wn[e * 20 + d];
            acc = fmaxf(acc, 0.f);
            o[i] = acc;
            sq += acc * acc;
        }
        sq += __shfl_xor(sq, 1);
        float sc = (sq > 0.f) ? sqrtf(sq) / (1.f + sq) : 0.f;
        #pragma unroll
        for (int i = 0; i < 10; i++)
            us[row * 40 + 2 * i + half] = (short)f2bf(o[i] * sc);
        #pragma unroll
        for (int i = 10; i < 16; i++)
            us[row * 40 + 2 * i + half] = 0;
    }
    __syncthreads();

    // ---- phase 2: per-mi MFMA -> LDS stage -> coalesced write ----
    #pragma unroll
    for (int mi = 0; mi < 2; mi++) {
        short8 af = *(const short8*)&us[(w * 32 + mi * 16 + fl) * 40 + quad * 8];
        #pragma unroll
        for (int nj = 0; nj < 10; nj++) {
            floatx4 acc = (floatx4){0.f, 0.f, 0.f, 0.f};
            acc = __builtin_amdgcn_mfma_f32_16x16x32_bf16(af, bfr[nj], acc, 0, 0, 0);
            #pragma unroll
            for (int r = 0; r < 4; r++)
                pst[(w * 16 + quad * 4 + r) * 168 + nj * 16 + fl] = (short)f2bf(acc[r]);
        }
        __syncthreads();
        #pragma unroll
        for (int s = 0; s < 5; s++) {
            int i = s * 256 + tid;
            int rl = i / 20, seg = i - rl * 20;
            int row = b0 + (rl >> 4) * 32 + mi * 16 + (rl & 15);
            if (row < Btot)
                *(uint4*)(pri + (size_t)row * 4800 + n * 160 + seg * 8)
                    = *(const uint4*)&pst[rl * 168 + seg * 8];
        }
        __syncthreads();
    }
}

// ---------------- K2 core (fallback path, validated math) ----------------
__device__ __forceinline__ void k2_core(const float* hp, const float* wn, const float* bn,
                                        float* o, float& sc) {
    float h[20];
    #pragma unroll
    for (int d4 = 0; d4 < 20; d4 += 4) {
        float4 v = *(const float4*)(hp + d4);
        h[d4] = v.x; h[d4 + 1] = v.y; h[d4 + 2] = v.z; h[d4 + 3] = v.w;
    }
    float sq = 0.f;
    #pragma unroll
    for (int e = 0; e < 20; e++) {
        float acc = bn[e];
        #pragma unroll
        for (int d = 0; d < 20; d++) acc += h[d] * wn[d * 20 + e];
        acc = fmaxf(acc, 0.f);
        o[e] = acc;
        sq += acc * acc;
    }
    sc = (sq > 0.f) ? sqrtf(sq) / (1.f + sq) : 0.f;
}

// K2s (fallback, validated): u fp32 in place
__global__ __launch_bounds__(256) void k2s(const float* h1, const void* W2, const void* b2,
                                           float* u, const u32* flags, int total) {
    __shared__ float W2s[12000];
    __shared__ float b2s[600];
    const bool wb = flags[3] != 0, bb = flags[4] != 0;
    const int tid = threadIdx.x;
    for (int i = tid; i < 12000; i += 256) W2s[i] = ldf(W2, i, wb);
    for (int i = tid; i < 600; i += 256) b2s[i] = ldf(b2, i, bb);
    __syncthreads();

    int t = blockIdx.x * 256 + tid;
    if (t >= total) return;
    const int b = t / 30, n = t - b * 30;
    float o[20], sc;
    k2_core(h1 + (size_t)b * 600 + n * 20, &W2s[n * 400], &b2s[n * 20], o, sc);
    float* up = u + (size_t)b * 600 + n * 20;
    #pragma unroll
    for (int e4 = 0; e4 < 20; e4 += 4) {
        float4 v;
        v.x = o[e4] * sc; v.y = o[e4 + 1] * sc; v.z = o[e4 + 2] * sc; v.w = o[e4 + 3] * sc;
        *(float4*)(up + e4) = v;
    }
}

// ---------------- K3w: routing, LDS-broadcast allgather, n-major pri (validated R21) ----------------
__global__ __launch_bounds__(320, 4) void k3w(const bfu* __restrict__ pri_buf,
                                              float* __restrict__ out, int Btot) {
    __shared__ float L[2][300];
    __shared__ float P[2][300];
    __shared__ float S[2][200];   // [g][o*20 + k]
    const int tid = threadIdx.x;
    const int g = tid / 160, r = tid - g * 160;
    const int o = r >> 4, j = r & 15;
    const int b0 = blockIdx.x * 2;
    int bb = b0 + g; if (bb >= Btot) bb = Btot - 1;

    const int n0 = 2 * j, n1 = n0 + 1;
    float p0[16], p1[16];
    if (j < 15) {
        const bfu* pb = pri_buf + (size_t)bb * 4800 + n0 * 160 + o * 16;
        uint4 q0 = *(const uint4*)(pb);          // n0 k0..7
        uint4 q1 = *(const uint4*)(pb + 8);      // n0 k8..15
        uint4 q2 = *(const uint4*)(pb + 160);    // n1 k0..7
        uint4 q3 = *(const uint4*)(pb + 168);    // n1 k8..15
        unpack8(q0, p0); unpack8(q1, p0 + 8);
        unpack8(q2, p1); unpack8(q3, p1 + 8);
    } else {
        #pragma unroll
        for (int i = 0; i < 16; i++) { p0[i] = 0.f; p1[i] = 0.f; }
    }

    float L0 = 0.f, L1 = 0.f;
    float v = 0.f;
    #pragma unroll
    for (int it = 0; it < 3; it++) {
        float P0, P1;
        if (it == 0) {
            P0 = 0.1f; P1 = 0.1f;              // softmax(zeros) over 10 outputs
        } else {
            if (r < 30) {                       // dedicated softmax over o for net r
                float l[10];
                #pragma unroll
                for (int oo = 0; oo < 10; oo++) l[oo] = L[g][r * 10 + oo];
                float mx = l[0];
                #pragma unroll
                for (int oo = 1; oo < 10; oo++) mx = fmaxf(mx, l[oo]);
                float den = 0.f;
                #pragma unroll
                for (int oo = 0; oo < 10; oo++) { l[oo] = __expf(l[oo] - mx); den += l[oo]; }
                float inv = 1.f / den;
                #pragma unroll
                for (int oo = 0; oo < 10; oo++) P[g][r * 10 + oo] = l[oo] * inv;
            }
            __syncthreads();
            P0 = (j < 15) ? P[g][n0 * 10 + o] : 0.f;
            P1 = (j < 15) ? P[g][n1 * 10 + o] : 0.f;
        }

        float t[16];
        #pragma unroll
        for (int i = 0; i < 16; i++) t[i] = P0 * p0[i] + P1 * p1[i];

        // 16-lane transpose-reduce: lane j ends with s[k=j] (15 shuffles)
        #pragma unroll
        for (int i = 0; i < 8; i++) {
            float send = (j & 8) ? t[i] : t[i + 8];
            float recv = __shfl_xor(send, 8, 16);
            t[i] = ((j & 8) ? t[i + 8] : t[i]) + recv;
        }
        #pragma unroll
        for (int i = 0; i < 4; i++) {
            float send = (j & 4) ? t[i] : t[i + 4];
            float recv = __shfl_xor(send, 4, 16);
            t[i] = ((j & 4) ? t[i + 4] : t[i]) + recv;
        }
        #pragma unroll
        for (int i = 0; i < 2; i++) {
            float send = (j & 2) ? t[i] : t[i + 2];
            float recv = __shfl_xor(send, 2, 16);
            t[i] = ((j & 2) ? t[i + 2] : t[i]) + recv;
        }
        {
            float send = (j & 1) ? t[0] : t[1];
            float recv = __shfl_xor(send, 1, 16);
            t[0] = ((j & 1) ? t[1] : t[0]) + recv;
        }
        float s = t[0];                         // s[o, k=j]

        if (it < 2) {
            // wave-internal LDS allgather: write s, read back the o-group's 16 values
            S[g][o * 20 + j] = s;
            float4 s0 = *(const float4*)&S[g][o * 20 + 0];
            float4 s1 = *(const float4*)&S[g][o * 20 + 4];
            float4 s2 = *(const float4*)&S[g][o * 20 + 8];
            float4 s3 = *(const float4*)&S[g][o * 20 + 12];
            float sf[16];
            sf[0] = s0.x;  sf[1] = s0.y;  sf[2] = s0.z;  sf[3] = s0.w;
            sf[4] = s1.x;  sf[5] = s1.y;  sf[6] = s1.z;  sf[7] = s1.w;
            sf[8] = s2.x;  sf[9] = s2.y;  sf[10] = s2.z; sf[11] = s2.w;
            sf[12] = s3.x; sf[13] = s3.y; sf[14] = s3.z; sf[15] = s3.w;
            float q = 0.f;
            #pragma unroll
            for (int k = 0; k < 16; k++) q += sf[k] * sf[k];
            float scale = sqrtf(q) / (1.f + q);
            v = s * scale;
            float d0 = 0.f, d1 = 0.f;
            #pragma unroll
            for (int k = 0; k < 16; k++) {
                float vk = sf[k] * scale;
                d0 += p0[k] * vk;
                d1 += p1[k] * vk;
            }
            L0 += d0; L1 += d1;
            if (j < 15) {
                L[g][n0 * 10 + o] = L0;
                L[g][n1 * 10 + o] = L1;
            }
            __syncthreads();
        } else {
            float q = s * s;
            q += __shfl_xor(q, 1, 16);
            q += __shfl_xor(q, 2, 16);
            q += __shfl_xor(q, 4, 16);
            q += __shfl_xor(q, 8, 16);
            v = s * sqrtf(q) / (1.f + q);
        }
    }
    if ((b0 + g) < Btot) out[(size_t)(b0 + g) * 160 + r] = v;
}

// ---------------- K3y2 (fallback, validated @202us) ----------------
__global__ __launch_bounds__(640, 2) void k3y2(const float* __restrict__ u,
                                               const bfu* __restrict__ rwb,
                                               float* __restrict__ out, int Btot) {
    __shared__ float US[4][600];
    __shared__ float L[4][300];
    __shared__ float P[4][300];
    const int tid = threadIdx.x;
    const int g = tid / 160, r = tid - g * 160;
    const int o = r >> 4, k = r & 15;
    const int b0 = blockIdx.x * 4;

    {
        const int nf4 = 150;
        for (int i = tid; i < 4 * nf4; i += 640) {
            int gg = i / nf4, j = i - gg * nf4;
            int bb = b0 + gg; if (bb >= Btot) bb = Btot - 1;
            *(float4*)&US[gg][j * 4] = *(const float4*)(u + (size_t)bb * 600 + j * 4);
        }
        for (int i = tid; i < 1200; i += 640) L[i / 300][i % 300] = 0.f;
    }
    __syncthreads();

    float pri[30];
    const bfu* rp = rwb + o * 9600 + k * 20;
    #pragma unroll 2
    for (int n = 0; n < 30; n++) {
        const uint2* rq = (const uint2*)(rp + n * 320);
        float a = 0.f;
        #pragma unroll
        for (int jj = 0; jj < 5; jj++) {
            uint2 w = rq[jj];
            float4 uu = *(const float4*)&US[g][n * 20 + jj * 4];
            a += lo2f(w.x) * uu.x + hi2f(w.x) * uu.y + lo2f(w.y) * uu.z + hi2f(w.y) * uu.w;
        }
        pri[n] = a;
    }

    float v = 0.f;
    for (int it = 0; it < 3; it++) {
        if (r < 30) {
            const int n = r;
            float mx = L[g][n * 10];
            #pragma unroll
            for (int oo = 1; oo < 10; oo++) mx = fmaxf(mx, L[g][n * 10 + oo]);
            float e[10], den = 0.f;
            #pragma unroll
            for (int oo = 0; oo < 10; oo++) { e[oo] = __expf(L[g][n * 10 + oo] - mx); den += e[oo]; }
            float inv = 1.f / den;
            #pragma unroll
            for (int oo = 0; oo < 10; oo++) P[g][n * 10 + oo] = e[oo] * inv;
        }
        __syncthreads();
        float s = 0.f;
        #pragma unroll
        for (int n = 0; n < 30; n++) s += P[g][n * 10 + o] * pri[n];
        float q = s * s;
        q += __shfl_xor(q, 1, 16);
        q += __shfl_xor(q, 2, 16);
        q += __shfl_xor(q, 4, 16);
        q += __shfl_xor(q, 8, 16);
        v = s * sqrtf(q) / (1.f + q);
        if (it < 2) {
            #pragma unroll 5
            for (int n = 0; n < 30; n++) {
                float t = pri[n] * v;
                t += __shfl_xor(t, 1, 16);
                t += __shfl_xor(t, 2, 16);
                t += __shfl_xor(t, 4, 16);
                t += __shfl_xor(t, 8, 16);
                if (k == 0) L[g][n * 10 + o] += t;
            }
            __syncthreads();
        }
    }
    if ((b0 + g) < Btot) out[(size_t)(b0 + g) * 160 + r] = v;
}

extern "C" void kernel_launch(void* const* d_in, const int* in_sizes, int n_in,
                              void* d_out, int out_size, void* d_ws, size_t ws_size,
                              hipStream_t stream) {
    // ---- size-based input matching (validated) ----
    int ix = -1, iw1 = -1, ib1 = -1, iw2 = -1, ib2 = -1, irw = -1;
    for (int i = 0; i < n_in; i++) {
        int s = in_sizes[i];
        if (s == 470400 && iw1 < 0) iw1 = i;
        else if (s == 12000 && iw2 < 0) iw2 = i;
        else if (s == 96000 && irw < 0) irw = i;
        else if (s == 600) { if (ib1 < 0) ib1 = i; else if (ib2 < 0) ib2 = i; }
    }
    long bestsz = -1;
    for (int i = 0; i < n_in; i++) {
        if (i == iw1 || i == iw2 || i == irw || i == ib1 || i == ib2) continue;
        if ((long)in_sizes[i] > bestsz) { bestsz = in_sizes[i]; ix = i; }
    }
    if (ix < 0 || iw1 < 0 || ib1 < 0 || iw2 < 0 || ib2 < 0 || irw < 0) {
        ix = 0; iw1 = 1; ib1 = 2; iw2 = 3; ib2 = 4; irw = 5;
    }
    const void* x  = d_in[ix];
    const void* W1 = d_in[iw1];
    const void* b1 = d_in[ib1];
    const void* W2 = d_in[iw2];
    const void* b2 = d_in[ib2];
    const void* rw = d_in[irw];
    const int B = in_sizes[ix] / 784;
    float* out = (float*)d_out;

    // ---- ws layout (byte offsets, all 16B-aligned) ----
    char* base = (char*)d_ws;
    size_t off = 0;
    float* h1u  = (float*)(base + off); off += (size_t)B * 2400;       // B*600 f32
    float* b1f  = (float*)(base + off); off += 2560;                   // 640 f32
    u32*  flags = (u32*)(base + off);   off += 32;                     // 8 u32 (fallback only)
    bfu*   Wt   = (bfu*)(base + off);   off += 1024000;                // 640*800 bf16
    bfu*   xb   = (bfu*)(base + off);   off += (size_t)B * 1600;       // B*800 bf16
    bfu*   rwb  = (bfu*)(base + off);   off += 192000;                 // 96000 bf16
    size_t fb_bytes = off;
    bfu*   rwn  = (bfu*)(base + off);   off += 307200;                 // 30*160*32 bf16
    float* W2t  = (float*)(base + off); off += 48000;                  // 30*20*20 f32
    float* b2f  = (float*)(base + off); off += 2560;                   // 640 f32
    bfu*   pri  = (bfu*)(base + off);   off += (size_t)B * 9600;       // B*4800 bf16
    size_t main_bytes = off;

    const int mode = (ws_size >= main_bytes) ? 0 : 1;   // fixed per-call -> graph-safe
    const int prep_total = B * 200 + 640 * 200 + 96000 + 640
                         + (mode == 0 ? (153600 + 12000 + 640) : 0);

    if (mode != 0)   // fallback path needs global flags for k2s
        detect_dtype<<<1, 64, 0, stream>>>((const u32*)x, (const u32*)W1, (const u32*)b1,
                                           (const u32*)W2, (const u32*)b2, (const u32*)rw, flags);
    prep_all<<<(prep_total + 255) / 256, 256, 0, stream>>>(x, W1, b1, W2, b2, rw,
                                                           xb, Wt, b1f, rwb, rwn,
                                                           W2t, b2f, B, mode);
    k1m<<<dim3((B + 127) / 128, 10), 256, 0, stream>>>(xb, Wt, b1f, h1u, B, mode == 0 ? 1 : 0);
    if (mode == 0) {
        k2w<<<dim3((B + 127) / 128, 30), 256, 0, stream>>>(h1u, W2t, b2f, rwn, pri, B);
        k3w<<<(B + 1) / 2, 320, 0, stream>>>(pri, out, B);
    } else {
        (void)fb_bytes;
        k2s<<<(B * 30 + 255) / 256, 256, 0, stream>>>(h1u, W2, b2, h1u, flags, B * 30);
        k3y2<<<(B + 3) / 4, 640, 0, stream>>>(h1u, rwb, out, B);
    }
}